// Round 4
// baseline (12245.081 us; speedup 1.0000x reference)
//
#include <hip/hip_runtime.h>
#include <hip/hip_bf16.h>

typedef __hip_bfloat16 bf16;
#define DEV static __device__ __forceinline__

DEV float b2f(bf16 v) { return __bfloat162float(v); }
DEV bf16  f2b(float v) { return __float2bfloat16(v); }
DEV float sigf(float x) { return 1.0f / (1.0f + __expf(-x)); }
DEV float tanhfast(float x) { return 2.0f / (1.0f + __expf(-2.0f * x)) - 1.0f; }

// ---------------------------------------------------------------------------
// B=8, T=16 -> 128 frames. Encoder 3->64@84 pool, 64->128@42 pool, 128->256@21.
// ConvLSTM @21x21 (dw 3x3 on 512ch, pw 512->1024 gates). Decoder up2+conv
// 256->128@42, up2+conv 128->64@84, 1x1 64->1.
//
// Round-4 changes: (a) runtime input-dtype detection (f32 vs bf16) — the
// reference declares float32; prior rounds' NaN is consistent with reading
// f32 as bf16 (uniform low-half bits -> exp 0xFF with p~0.8%). (b) weights
// canonicalized to bf16 in ws; x read dual-dtype; outputs written dual-dtype.
// (c) ws_size-aware layout: BIG (no aliasing, 64 MB) or SMALL per-batch (15 MB).
// ---------------------------------------------------------------------------

// detect: scan x as u16; bf16 N(0,1) never has exp-field >= 0xC0, f32-as-u16
// low halves are ~uniform -> ~25% hit. One block.
__global__ void k_detect(const unsigned short* __restrict__ xb, int nscan, int* flag)
{
    __shared__ int cnt_s[256];
    int tid = threadIdx.x;
    int c = 0;
    for (int i = tid; i < nscan; i += 256) {
        unsigned int e = (xb[i] >> 7) & 0xFF;
        c += (e >= 0xC0);
    }
    cnt_s[tid] = c;
    __syncthreads();
    for (int off = 128; off > 0; off >>= 1) {
        if (tid < off) cnt_s[tid] += cnt_s[tid + off];
        __syncthreads();
    }
    if (tid == 0) *flag = (cnt_s[0] > 1000) ? 1 : 0;
}

// canon: copy one tensor into bf16, reading per detected dtype
__global__ __launch_bounds__(256) void k_canon(
    const void* __restrict__ src, bf16* __restrict__ dst, int n,
    const int* __restrict__ flag)
{
    int i = blockIdx.x * 256 + threadIdx.x;
    if (i >= n) return;
    if (*flag) dst[i] = f2b(((const float*)src)[i]);
    else       dst[i] = ((const bf16*)src)[i];
}

// K1: conv 3->64 (3x3 pad1) + relu + maxpool2 : x[fbase+z] -> p1c[z,64,42,42]
__global__ __launch_bounds__(256) void k_conv1_pool(
    const void* __restrict__ xv, const bf16* __restrict__ w,
    const bf16* __restrict__ bias, bf16* __restrict__ p1c, int fbase,
    const int* __restrict__ flag)
{
    __shared__ __align__(16) float in_s[3][16][16];
    __shared__ __align__(16) float w_s[1728];
    __shared__ __align__(16) float b_s[64];
    const int z = blockIdx.y;
    const int n = fbase + z;
    const int ty = blockIdx.x / 6, tx = blockIdx.x % 6;
    const int tid = threadIdx.x;
    const int isf32 = *flag;
    for (int i = tid; i < 1728; i += 256) w_s[i] = b2f(w[i]);
    if (tid < 64) b_s[tid] = b2f(bias[tid]);
    const int iy0 = ty * 14 - 1, ix0 = tx * 14 - 1;
    for (int i = tid; i < 768; i += 256) {
        int ci = i >> 8, r = (i >> 4) & 15, col = i & 15;
        int gy = iy0 + r, gx = ix0 + col;
        float v = 0.f;
        if (gy >= 0 && gy < 84 && gx >= 0 && gx < 84) {
            int idx = (n * 3 + ci) * 7056 + gy * 84 + gx;
            v = isf32 ? ((const float*)xv)[idx] : b2f(((const bf16*)xv)[idx]);
        }
        in_s[ci][r][col] = v;
    }
    __syncthreads();
    for (int idx = tid; idx < 3136; idx += 256) {
        int oc = idx / 49, p = idx % 49;
        int py = p / 7, px = p % 7;
        float m = 0.f;  // relu floor
        #pragma unroll
        for (int pp = 0; pp < 4; ++pp) {
            int a = pp >> 1, bb = pp & 1;
            float sacc = b_s[oc];
            for (int ci = 0; ci < 3; ++ci)
                #pragma unroll
                for (int ky = 0; ky < 3; ++ky)
                    #pragma unroll
                    for (int kx = 0; kx < 3; ++kx)
                        sacc += w_s[(oc * 3 + ci) * 9 + ky * 3 + kx] *
                                in_s[ci][2 * py + a + ky][2 * px + bb + kx];
            m = fmaxf(m, sacc);
        }
        p1c[((z * 64 + oc) * 42 + ty * 7 + py) * 42 + tx * 7 + px] = f2b(m);
    }
}

// K2: conv 64->128 (3x3 pad1) + relu + maxpool2 : p1c[z] -> p2c[z,128,21,21]
__global__ __launch_bounds__(256) void k_conv2_pool(
    const bf16* __restrict__ p1c, const bf16* __restrict__ w,
    const bf16* __restrict__ bias, bf16* __restrict__ p2c)
{
    __shared__ __align__(16) float in_s[16][8][44];
    __shared__ __align__(16) float w_s[16][9][32];
    const int z = blockIdx.z, rt = blockIdx.x, oq = blockIdx.y;
    const int tid = threadIdx.x;
    const int s = tid & 63, og = tid >> 6;
    const int pr = (s < 63) ? (s / 21) : 2, pc = s % 21;
    const bool act = (s < 63);
    const int r0 = rt * 3;
    const int iy0 = r0 * 2 - 1;
    float acc[32];
    #pragma unroll
    for (int i = 0; i < 32; ++i) acc[i] = 0.f;
    for (int cc = 0; cc < 4; ++cc) {
        const int c0 = cc * 16;
        __syncthreads();
        for (int i = tid; i < 5632; i += 256) {
            int ci = i / 352, rem = i % 352, r = rem / 44, col = rem % 44;
            int gy = iy0 + r, gx = col - 1;
            float v = 0.f;
            if (gy >= 0 && gy < 42 && gx >= 0 && gx < 42)
                v = b2f(p1c[((z * 64 + c0 + ci) * 42 + gy) * 42 + gx]);
            in_s[ci][r][col] = v;
        }
        for (int i = tid; i < 4608; i += 256) {
            int ci = i / 288, rem = i % 288, tap = rem / 32, ol = rem & 31;
            w_s[ci][tap][ol] = b2f(w[((oq * 32 + ol) * 64 + c0 + ci) * 9 + tap]);
        }
        __syncthreads();
        if (act) {
            #pragma unroll 1
            for (int ci = 0; ci < 16; ++ci) {
                float iv[4][4];
                #pragma unroll
                for (int r = 0; r < 4; ++r)
                    #pragma unroll
                    for (int col = 0; col < 4; ++col)
                        iv[r][col] = in_s[ci][2 * pr + r][2 * pc + col];
                #pragma unroll
                for (int tap = 0; tap < 9; ++tap) {
                    const int ky = tap / 3, kx = tap % 3;
                    const float4 w0 = *(const float4*)&w_s[ci][tap][og * 8];
                    const float4 w1 = *(const float4*)&w_s[ci][tap][og * 8 + 4];
                    const float wv[8] = {w0.x, w0.y, w0.z, w0.w, w1.x, w1.y, w1.z, w1.w};
                    #pragma unroll
                    for (int j = 0; j < 8; ++j)
                        #pragma unroll
                        for (int pp = 0; pp < 4; ++pp)
                            acc[j * 4 + pp] += wv[j] * iv[(pp >> 1) + ky][(pp & 1) + kx];
                }
            }
        }
    }
    if (act) {
        #pragma unroll
        for (int j = 0; j < 8; ++j) {
            const int oc = oq * 32 + og * 8 + j;
            const float bv = b2f(bias[oc]);
            float m = 0.f;
            #pragma unroll
            for (int pp = 0; pp < 4; ++pp) m = fmaxf(m, acc[j * 4 + pp] + bv);
            p2c[((z * 128 + oc) * 21 + r0 + pr) * 21 + pc] = f2b(m);
        }
    }
}

// K3: conv 128->256 (3x3 pad1) + relu : p2c[z] -> feats[(zbase+z),256,21,21]
__global__ __launch_bounds__(256) void k_conv3(
    const bf16* __restrict__ p2c, const bf16* __restrict__ w,
    const bf16* __restrict__ bias, bf16* __restrict__ feats, int zbase)
{
    __shared__ __align__(16) float in_s[16][8][23];
    __shared__ __align__(16) float w_s[16][9][32];
    const int z = blockIdx.z, rt = blockIdx.x, oq = blockIdx.y;
    const int n = zbase + z;
    const int tid = threadIdx.x;
    const int s = tid & 63, og = tid >> 6;
    const bool act = (s < 63);
    const int lr = (s < 63) ? (s / 21) : 2, col = s % 21;
    const int r0 = rt * 6;
    float acc[16];
    #pragma unroll
    for (int i = 0; i < 16; ++i) acc[i] = 0.f;
    for (int cc = 0; cc < 8; ++cc) {
        const int c0 = cc * 16;
        __syncthreads();
        for (int i = tid; i < 2944; i += 256) {
            int ci = i / 184, rem = i % 184, r = rem / 23, gcol = rem % 23;
            int gy = r0 - 1 + r, gx = gcol - 1;
            float v = 0.f;
            if (gy >= 0 && gy < 21 && gx >= 0 && gx < 21)
                v = b2f(p2c[((z * 128 + c0 + ci) * 21 + gy) * 21 + gx]);
            in_s[ci][r][gcol] = v;
        }
        for (int i = tid; i < 4608; i += 256) {
            int ci = i / 288, rem = i % 288, tap = rem / 32, ol = rem & 31;
            w_s[ci][tap][ol] = b2f(w[((oq * 32 + ol) * 128 + c0 + ci) * 9 + tap]);
        }
        __syncthreads();
        if (act) {
            #pragma unroll 1
            for (int ci = 0; ci < 16; ++ci) {
                float iv0[3][3], iv1[3][3];
                #pragma unroll
                for (int r = 0; r < 3; ++r)
                    #pragma unroll
                    for (int q = 0; q < 3; ++q) {
                        iv0[r][q] = in_s[ci][lr + r][col + q];
                        iv1[r][q] = in_s[ci][lr + 3 + r][col + q];
                    }
                #pragma unroll
                for (int tap = 0; tap < 9; ++tap) {
                    const int ky = tap / 3, kx = tap % 3;
                    const float4 w0 = *(const float4*)&w_s[ci][tap][og * 8];
                    const float4 w1 = *(const float4*)&w_s[ci][tap][og * 8 + 4];
                    const float wv[8] = {w0.x, w0.y, w0.z, w0.w, w1.x, w1.y, w1.z, w1.w};
                    #pragma unroll
                    for (int j = 0; j < 8; ++j) {
                        acc[j]     += wv[j] * iv0[ky][kx];
                        acc[j + 8] += wv[j] * iv1[ky][kx];
                    }
                }
            }
        }
    }
    if (act) {
        const int oy0 = r0 + lr, oy1 = oy0 + 3;
        #pragma unroll
        for (int j = 0; j < 8; ++j) {
            const int oc = oq * 32 + og * 8 + j;
            const float bv = b2f(bias[oc]);
            if (oy0 < 21)
                feats[((n * 256 + oc) * 21 + oy0) * 21 + col] = f2b(fmaxf(acc[j] + bv, 0.f));
            if (oy1 < 21)
                feats[((n * 256 + oc) * 21 + oy1) * 21 + col] = f2b(fmaxf(acc[j + 8] + bv, 0.f));
        }
    }
}

// K4: depthwise 3x3 on comb=[feats_t(256) | h(256)] -> dwout f32 [nb,512,441]
__global__ __launch_bounds__(256) void k_dw(
    const bf16* __restrict__ feats, const float* __restrict__ h,
    const bf16* __restrict__ dww, float* __restrict__ dwout, int t, int ntot)
{
    int idx = blockIdx.x * 256 + threadIdx.x;
    if (idx >= ntot) return;
    const int p = idx % 441;
    const int ch = (idx / 441) & 511;
    const int b = idx / (441 * 512);
    const int y = p / 21, x = p % 21;
    float wv[9];
    #pragma unroll
    for (int k = 0; k < 9; ++k) wv[k] = b2f(dww[ch * 9 + k]);
    float s = 0.f;
    #pragma unroll
    for (int ky = 0; ky < 3; ++ky) {
        int iy = y + ky - 1;
        if (iy < 0 || iy >= 21) continue;
        #pragma unroll
        for (int kx = 0; kx < 3; ++kx) {
            int ix = x + kx - 1;
            if (ix < 0 || ix >= 21) continue;
            float v;
            if (ch < 256) v = b2f(feats[((b * 16 + t) * 256 + ch) * 441 + iy * 21 + ix]);
            else          v = h[(b * 256 + (ch - 256)) * 441 + iy * 21 + ix];
            s += wv[ky * 3 + kx] * v;
        }
    }
    dwout[idx] = s;
}

// K5: pointwise 512->1024 + bias + gates; updates h,c (f32), writes hs_t[nb,256,441]
__global__ __launch_bounds__(256) void k_pw_gate(
    const float* __restrict__ dwout, const bf16* __restrict__ pww,
    const bf16* __restrict__ pwb, float* __restrict__ h, float* __restrict__ c,
    bf16* __restrict__ hs_t)
{
    __shared__ __align__(16) float a_s[32][64];
    __shared__ __align__(16) float w_s[32][128];
    const int b = blockIdx.z, cq = blockIdx.y, pt = blockIdx.x;
    const int tid = threadIdx.x;
    const int s = tid & 31, cg = tid >> 5;
    const int p0 = pt * 64 + s, p1 = p0 + 32;
    float acc0[16], acc1[16];
    #pragma unroll
    for (int i = 0; i < 16; ++i) { acc0[i] = 0.f; acc1[i] = 0.f; }
    for (int kk = 0; kk < 512; kk += 32) {
        __syncthreads();
        for (int i = tid; i < 2048; i += 256) {
            int k = i >> 6, pix = i & 63;
            int gp = pt * 64 + pix;
            a_s[k][pix] = (gp < 441) ? dwout[(b * 512 + kk + k) * 441 + gp] : 0.f;
        }
        for (int i = tid; i < 4096; i += 256) {
            int k = i >> 7, j = i & 127;
            int cgl = j >> 4, ccl = (j >> 2) & 3, gate = j & 3;
            int oc = gate * 256 + cq * 32 + cgl * 4 + ccl;
            w_s[k][j] = b2f(pww[oc * 512 + kk + k]);
        }
        __syncthreads();
        #pragma unroll 4
        for (int k = 0; k < 32; ++k) {
            const float a0 = a_s[k][s], a1 = a_s[k][s + 32];
            const float4 q0 = *(const float4*)&w_s[k][cg * 16];
            const float4 q1 = *(const float4*)&w_s[k][cg * 16 + 4];
            const float4 q2 = *(const float4*)&w_s[k][cg * 16 + 8];
            const float4 q3 = *(const float4*)&w_s[k][cg * 16 + 12];
            const float wv[16] = {q0.x, q0.y, q0.z, q0.w, q1.x, q1.y, q1.z, q1.w,
                                  q2.x, q2.y, q2.z, q2.w, q3.x, q3.y, q3.z, q3.w};
            #pragma unroll
            for (int j = 0; j < 16; ++j) { acc0[j] += wv[j] * a0; acc1[j] += wv[j] * a1; }
        }
    }
    #pragma unroll
    for (int ccl = 0; ccl < 4; ++ccl) {
        const int ch = cq * 32 + cg * 4 + ccl;
        const float bi = b2f(pwb[ch]);
        const float bfg = b2f(pwb[256 + ch]);
        const float bo = b2f(pwb[512 + ch]);
        const float bg = b2f(pwb[768 + ch]);
        if (p0 < 441) {
            float ig = sigf(acc0[ccl * 4 + 0] + bi);
            float fg = sigf(acc0[ccl * 4 + 1] + bfg);
            float og = sigf(acc0[ccl * 4 + 2] + bo);
            float gg = tanhfast(acc0[ccl * 4 + 3] + bg);
            int ci2 = (b * 256 + ch) * 441 + p0;
            float c2 = fg * c[ci2] + ig * gg;
            float h2 = og * tanhfast(c2);
            c[ci2] = c2; h[ci2] = h2;
            hs_t[ci2] = f2b(h2);
        }
        if (p1 < 441) {
            float ig = sigf(acc1[ccl * 4 + 0] + bi);
            float fg = sigf(acc1[ccl * 4 + 1] + bfg);
            float og = sigf(acc1[ccl * 4 + 2] + bo);
            float gg = tanhfast(acc1[ccl * 4 + 3] + bg);
            int ci2 = (b * 256 + ch) * 441 + p1;
            float c2 = fg * c[ci2] + ig * gg;
            float h2 = og * tanhfast(c2);
            c[ci2] = c2; h[ci2] = h2;
            hs_t[ci2] = f2b(h2);
        }
    }
}

// K6: up2 + conv 256->128 + relu : hs_t[z,256,21,21] -> d1t[z,128,42,42]
__global__ __launch_bounds__(256) void k_dec1(
    const bf16* __restrict__ hs_t, const bf16* __restrict__ w,
    const bf16* __restrict__ bias, bf16* __restrict__ d1t)
{
    __shared__ __align__(16) float in_s[16][5][23];
    __shared__ __align__(16) float wr_s[16][2][2][3][32];  // [ic][py][a][kx][oc]
    const int z = blockIdx.z, rt = blockIdx.x, oq = blockIdx.y;
    const int tid = threadIdx.x;
    const int s = tid & 127, og = tid >> 7;
    const bool act = (s < 126);
    const int row = (s < 126) ? (s / 21) : 5, col0 = s % 21, col1 = col0 + 21;
    const int r0 = rt * 6;
    const int oy = r0 + row;
    const int py = oy & 1;
    const int rlb = (row + 1) >> 1;
    int cs0[3], cs1[3];
    #pragma unroll
    for (int kx = 0; kx < 3; ++kx) {
        cs0[kx] = (col0 + kx + 1) >> 1;
        cs1[kx] = (col1 + kx + 1) >> 1;
    }
    float acc0[16], acc1[16];
    #pragma unroll
    for (int i = 0; i < 16; ++i) { acc0[i] = 0.f; acc1[i] = 0.f; }
    for (int cc = 0; cc < 16; ++cc) {
        const int c0 = cc * 16;
        __syncthreads();
        for (int i = tid; i < 1840; i += 256) {
            int ci = i / 115, rem = i % 115, r = rem / 23, gc = rem % 23;
            int gy = 3 * rt - 1 + r, gx = gc - 1;
            float v = 0.f;
            if (gy >= 0 && gy < 21 && gx >= 0 && gx < 21)
                v = b2f(hs_t[((z * 256 + c0 + ci) * 21 + gy) * 21 + gx]);
            in_s[ci][r][gc] = v;
        }
        for (int i = tid; i < 6144; i += 256) {
            int ol = i & 31; int rest = i >> 5;
            int kx = rest % 3; rest /= 3;
            int a = rest & 1; rest >>= 1;
            int pyi = rest & 1; int ci = rest >> 1;
            const bf16* wb = w + ((oq * 32 + ol) * 256 + c0 + ci) * 9;
            float v;
            if (pyi == 0) v = (a == 0) ? b2f(wb[kx]) : b2f(wb[3 + kx]) + b2f(wb[6 + kx]);
            else          v = (a == 0) ? b2f(wb[kx]) + b2f(wb[3 + kx]) : b2f(wb[6 + kx]);
            wr_s[ci][pyi][a][kx][ol] = v;
        }
        __syncthreads();
        #pragma unroll 2
        for (int ci = 0; ci < 16; ++ci) {
            #pragma unroll
            for (int a = 0; a < 2; ++a) {
                #pragma unroll
                for (int kx = 0; kx < 3; ++kx) {
                    const float v0 = in_s[ci][rlb + a][cs0[kx]];
                    const float v1 = in_s[ci][rlb + a][cs1[kx]];
                    const float4 q0 = *(const float4*)&wr_s[ci][py][a][kx][og * 16];
                    const float4 q1 = *(const float4*)&wr_s[ci][py][a][kx][og * 16 + 4];
                    const float4 q2 = *(const float4*)&wr_s[ci][py][a][kx][og * 16 + 8];
                    const float4 q3 = *(const float4*)&wr_s[ci][py][a][kx][og * 16 + 12];
                    const float wv[16] = {q0.x, q0.y, q0.z, q0.w, q1.x, q1.y, q1.z, q1.w,
                                          q2.x, q2.y, q2.z, q2.w, q3.x, q3.y, q3.z, q3.w};
                    #pragma unroll
                    for (int j = 0; j < 16; ++j) {
                        acc0[j] += wv[j] * v0;
                        acc1[j] += wv[j] * v1;
                    }
                }
            }
        }
    }
    if (act) {
        #pragma unroll
        for (int j = 0; j < 16; ++j) {
            const int oc = oq * 32 + og * 16 + j;
            const float bv = b2f(bias[oc]);
            d1t[((z * 128 + oc) * 42 + oy) * 42 + col0] = f2b(fmaxf(acc0[j] + bv, 0.f));
            d1t[((z * 128 + oc) * 42 + oy) * 42 + col1] = f2b(fmaxf(acc1[j] + bv, 0.f));
        }
    }
}

// K7: up2 + conv 128->64 + relu : d1t[z,128,42,42] -> d2t[z,64,84,84]
__global__ __launch_bounds__(256) void k_dec2(
    const bf16* __restrict__ d1t, const bf16* __restrict__ w,
    const bf16* __restrict__ bias, bf16* __restrict__ d2t)
{
    __shared__ __align__(16) float in_s[16][4][44];
    __shared__ __align__(16) float wr_s[16][2][2][3][32];
    const int z = blockIdx.z, rt = blockIdx.x, oq = blockIdx.y;
    const int tid = threadIdx.x;
    const int s = tid & 127, og = tid >> 7;
    const bool act = (s < 126);
    const int row = (s < 126) ? (s / 42) : 2, col0 = s % 42, col1 = col0 + 42;
    const int r0 = rt * 3;
    const int oy = r0 + row;
    const int py = oy & 1;
    const int base = ((r0 + 1) >> 1) - 1;
    const int rlb = ((oy + 1) >> 1) - 1 - base;
    int cs0[3], cs1[3];
    #pragma unroll
    for (int kx = 0; kx < 3; ++kx) {
        cs0[kx] = (col0 + kx + 1) >> 1;
        cs1[kx] = (col1 + kx + 1) >> 1;
    }
    float acc0[16], acc1[16];
    #pragma unroll
    for (int i = 0; i < 16; ++i) { acc0[i] = 0.f; acc1[i] = 0.f; }
    for (int cc = 0; cc < 8; ++cc) {
        const int c0 = cc * 16;
        __syncthreads();
        for (int i = tid; i < 2816; i += 256) {
            int ci = i / 176, rem = i % 176, r = rem / 44, gc = rem % 44;
            int gy = base + r, gx = gc - 1;
            float v = 0.f;
            if (gy >= 0 && gy < 42 && gx >= 0 && gx < 42)
                v = b2f(d1t[((z * 128 + c0 + ci) * 42 + gy) * 42 + gx]);
            in_s[ci][r][gc] = v;
        }
        for (int i = tid; i < 6144; i += 256) {
            int ol = i & 31; int rest = i >> 5;
            int kx = rest % 3; rest /= 3;
            int a = rest & 1; rest >>= 1;
            int pyi = rest & 1; int ci = rest >> 1;
            const bf16* wb = w + ((oq * 32 + ol) * 128 + c0 + ci) * 9;
            float v;
            if (pyi == 0) v = (a == 0) ? b2f(wb[kx]) : b2f(wb[3 + kx]) + b2f(wb[6 + kx]);
            else          v = (a == 0) ? b2f(wb[kx]) + b2f(wb[3 + kx]) : b2f(wb[6 + kx]);
            wr_s[ci][pyi][a][kx][ol] = v;
        }
        __syncthreads();
        #pragma unroll 2
        for (int ci = 0; ci < 16; ++ci) {
            #pragma unroll
            for (int a = 0; a < 2; ++a) {
                #pragma unroll
                for (int kx = 0; kx < 3; ++kx) {
                    const float v0 = in_s[ci][rlb + a][cs0[kx]];
                    const float v1 = in_s[ci][rlb + a][cs1[kx]];
                    const float4 q0 = *(const float4*)&wr_s[ci][py][a][kx][og * 16];
                    const float4 q1 = *(const float4*)&wr_s[ci][py][a][kx][og * 16 + 4];
                    const float4 q2 = *(const float4*)&wr_s[ci][py][a][kx][og * 16 + 8];
                    const float4 q3 = *(const float4*)&wr_s[ci][py][a][kx][og * 16 + 12];
                    const float wv[16] = {q0.x, q0.y, q0.z, q0.w, q1.x, q1.y, q1.z, q1.w,
                                          q2.x, q2.y, q2.z, q2.w, q3.x, q3.y, q3.z, q3.w};
                    #pragma unroll
                    for (int j = 0; j < 16; ++j) {
                        acc0[j] += wv[j] * v0;
                        acc1[j] += wv[j] * v1;
                    }
                }
            }
        }
    }
    if (act) {
        #pragma unroll
        for (int j = 0; j < 16; ++j) {
            const int oc = oq * 32 + og * 16 + j;
            const float bv = b2f(bias[oc]);
            d2t[((z * 64 + oc) * 84 + oy) * 84 + col0] = f2b(fmaxf(acc0[j] + bv, 0.f));
            d2t[((z * 64 + oc) * 84 + oy) * 84 + col1] = f2b(fmaxf(acc1[j] + bv, 0.f));
        }
    }
}

// K8: 1x1 conv 64->1 + bias : d2t[z] -> out frame ((b0+z)*16+t); dual-dtype out
__global__ __launch_bounds__(256) void k_dec3(
    const bf16* __restrict__ d2t, const bf16* __restrict__ w3,
    const bf16* __restrict__ b3, void* __restrict__ out, int t, int b0, int ntot,
    const int* __restrict__ flag)
{
    const int idx = blockIdx.x * 256 + threadIdx.x;
    if (idx >= ntot) return;
    const int z = idx / 7056, p = idx % 7056;
    float s = b2f(b3[0]);
    const bf16* bp = d2t + z * 64 * 7056 + p;
    #pragma unroll
    for (int ci = 0; ci < 64; ++ci)
        s += b2f(w3[ci]) * b2f(bp[ci * 7056]);
    const int oi = ((b0 + z) * 16 + t) * 7056 + p;
    if (*flag) ((float*)out)[oi] = s;
    else       ((bf16*)out)[oi]  = f2b(s);
}

// K9: flush final h,c (f32) -> d_out; dual-dtype out
__global__ __launch_bounds__(256) void k_out_hc(
    const float* __restrict__ h, const float* __restrict__ c,
    void* __restrict__ out, int b0, int n, const int* __restrict__ flag)
{
    int idx = blockIdx.x * 256 + threadIdx.x;
    if (idx >= n) return;
    const int oh = 903168 + b0 * 112896 + idx;
    const int oc = 1806336 + b0 * 112896 + idx;
    if (*flag) { ((float*)out)[oh] = h[idx]; ((float*)out)[oc] = c[idx]; }
    else       { ((bf16*)out)[oh]  = f2b(h[idx]); ((bf16*)out)[oc]  = f2b(c[idx]); }
}

extern "C" void kernel_launch(void* const* d_in, const int* in_sizes, int n_in,
                              void* d_out, int out_size, void* d_ws, size_t ws_size,
                              hipStream_t stream)
{
    char* wsb = (char*)d_ws;
    // canonical bf16 weights (offsets, bytes); index 0 = x is NOT canonicalized
    static const int wsz[15] = {1728, 64, 73728, 128, 294912, 256, 4608, 524288,
                                1024, 294912, 128, 73728, 64, 64, 1};
    static const long woff[15] = {0, 3456, 3584, 151040, 151296, 741120, 741632,
                                  750848, 1799424, 1801472, 2391296, 2391552,
                                  2539008, 2539136, 2539264};
    const long FLAG_OFF = 2539280;
    const long CE = 2539296;  // common end (16B aligned)
    int* flag = (int*)(wsb + FLAG_OFF);

    k_detect<<<1, 256, 0, stream>>>((const unsigned short*)d_in[0], 262144, flag);
    bf16* cw[15];
    for (int i = 0; i < 15; ++i) {
        cw[i] = (bf16*)(wsb + woff[i]);
        k_canon<<<(wsz[i] + 255) / 256, 256, 0, stream>>>(d_in[i + 1], cw[i], wsz[i], flag);
    }
    const void* x = d_in[0];
    bf16 *enc_w1 = cw[0], *enc_b1 = cw[1], *enc_w2 = cw[2], *enc_b2 = cw[3],
         *enc_w3 = cw[4], *enc_b3 = cw[5], *dw_w = cw[6], *pw_w = cw[7],
         *pw_b = cw[8], *dec_w1 = cw[9], *dec_b1 = cw[10], *dec_w2 = cw[11],
         *dec_b2 = cw[12], *dec_w3 = cw[13], *dec_b3 = cw[14];

    const long SZ_FEATS_BIG = 28901376, SZ_P1C = 3612672, SZ_P2C = 1806336;
    const long BIG_NEED = CE + SZ_FEATS_BIG + SZ_P1C + SZ_P2C + 3612672 + 3612672 +
                          7225344 + 1806336 + 3612672 + 7225344;  // = 63,954,720

    if (ws_size >= (size_t)BIG_NEED) {
        // BIG: all 8 batches together, no aliasing
        bf16*  feats = (bf16*)(wsb + CE);
        bf16*  p1c   = (bf16*)(wsb + CE + 28901376);
        bf16*  p2c   = (bf16*)(wsb + CE + 32514048);
        float* hbuf  = (float*)(wsb + CE + 34320384);
        float* cbuf  = (float*)(wsb + CE + 37933056);
        float* dwout = (float*)(wsb + CE + 41545728);
        bf16*  hs_t  = (bf16*)(wsb + CE + 48771072);
        bf16*  d1t   = (bf16*)(wsb + CE + 50577408);
        bf16*  d2t   = (bf16*)(wsb + CE + 54190080);
        for (int f0 = 0; f0 < 128; f0 += 16) {
            k_conv1_pool<<<dim3(36, 16), 256, 0, stream>>>(x, enc_w1, enc_b1, p1c, f0, flag);
            k_conv2_pool<<<dim3(7, 4, 16), 256, 0, stream>>>(p1c, enc_w2, enc_b2, p2c);
            k_conv3<<<dim3(4, 8, 16), 256, 0, stream>>>(p2c, enc_w3, enc_b3, feats, f0);
        }
        hipMemsetAsync(hbuf, 0, 2 * 3612672, stream);
        for (int t = 0; t < 16; ++t) {
            k_dw<<<7056, 256, 0, stream>>>(feats, hbuf, dw_w, dwout, t, 8 * 512 * 441);
            k_pw_gate<<<dim3(7, 8, 8), 256, 0, stream>>>(dwout, pw_w, pw_b, hbuf, cbuf, hs_t);
            k_dec1<<<dim3(7, 4, 8), 256, 0, stream>>>(hs_t, dec_w1, dec_b1, d1t);
            k_dec2<<<dim3(28, 2, 8), 256, 0, stream>>>(d1t, dec_w2, dec_b2, d2t);
            k_dec3<<<221, 256, 0, stream>>>(d2t, dec_w3, dec_b3, d_out, t, 0, 8 * 7056, flag);
        }
        k_out_hc<<<3528, 256, 0, stream>>>(hbuf, cbuf, d_out, 0, 8 * 112896, flag);
    } else {
        // SMALL: per-batch sequential (peak ~15 MB)
        bf16*  featsb = (bf16*)(wsb + CE);
        bf16*  p1c    = (bf16*)(wsb + CE + 3612672);
        bf16*  p2c    = (bf16*)(wsb + CE + 7225344);
        float* hbuf   = (float*)(wsb + CE + 9031680);
        float* cbuf   = (float*)(wsb + CE + 9483264);
        float* dwout  = (float*)(wsb + CE + 9934848);
        bf16*  hs_t   = (bf16*)(wsb + CE + 10838016);
        bf16*  d1t    = (bf16*)(wsb + CE + 11063808);
        bf16*  d2t    = (bf16*)(wsb + CE + 11515392);
        for (int b0 = 0; b0 < 8; ++b0) {
            k_conv1_pool<<<dim3(36, 16), 256, 0, stream>>>(x, enc_w1, enc_b1, p1c, b0 * 16, flag);
            k_conv2_pool<<<dim3(7, 4, 16), 256, 0, stream>>>(p1c, enc_w2, enc_b2, p2c);
            k_conv3<<<dim3(4, 8, 16), 256, 0, stream>>>(p2c, enc_w3, enc_b3, featsb, 0);
            hipMemsetAsync(hbuf, 0, 2 * 451584, stream);
            for (int t = 0; t < 16; ++t) {
                k_dw<<<882, 256, 0, stream>>>(featsb, hbuf, dw_w, dwout, t, 512 * 441);
                k_pw_gate<<<dim3(7, 8, 1), 256, 0, stream>>>(dwout, pw_w, pw_b, hbuf, cbuf, hs_t);
                k_dec1<<<dim3(7, 4, 1), 256, 0, stream>>>(hs_t, dec_w1, dec_b1, d1t);
                k_dec2<<<dim3(28, 2, 1), 256, 0, stream>>>(d1t, dec_w2, dec_b2, d2t);
                k_dec3<<<28, 256, 0, stream>>>(d2t, dec_w3, dec_b3, d_out, t, b0, 7056, flag);
            }
            k_out_hc<<<441, 256, 0, stream>>>(hbuf, cbuf, d_out, b0, 112896, flag);
        }
    }
}

// Round 5
// 10527.336 us; speedup vs baseline: 1.1632x; 1.1632x over previous
//
#include <hip/hip_runtime.h>
#include <hip/hip_bf16.h>

typedef __hip_bfloat16 bf16;
#define DEV static __device__ __forceinline__

DEV float b2f(bf16 v) { return __bfloat162float(v); }
DEV bf16  f2b(float v) { return __float2bfloat16(v); }
DEV float sigf(float x) { return 1.0f / (1.0f + __expf(-x)); }
DEV float tanhfast(float x) { return 2.0f / (1.0f + __expf(-2.0f * x)) - 1.0f; }

// ---------------------------------------------------------------------------
// Inputs/outputs are fp32 (proved round 4); compute in bf16/f32 mixed.
// B=8, T=16. Encoder 3->64@84 pool, 64->128@42 pool, 128->256@21.
// ConvLSTM @21x21 (dw 3x3 512ch, pw 512->1024 gates). Decoder up2+conv
// 256->128@42, up2+conv 128->64@84, 1x1 64->1.
//
// Round-5: occupancy attack. feats stored T-MAJOR (slot = t*8+b); h_t written
// into the dead feats slot of step t-1 (hs0 separate) so the decoder runs
// AFTER the LSTM over all 128 frames in 8 chunks of 16 (grids ~900 blocks
// instead of 224). dec1/dec2 re-tiled (ci-chunk 8, ~15 KB LDS). pw_gate 32
// px/block (896 blocks).
//
// ws layout (confirmed ws_size >= 63,954,720 from round 4):
//   [0, 2,539,296)          canonical bf16 weights + flag
//   feats  @ CE          28,901,376   (slots [t*8+b], 112,896 elem/frame)
//   hs0    @ CE+28,901,376  1,806,336
//   h f32  @ CE+30,707,712  3,612,672
//   c f32  @ CE+34,320,384  3,612,672
//   dwout  @ CE+37,933,056  7,225,344   | d1c (decode) aliases, same size
//   d2c    @ CE+45,158,400 14,450,688   | p1c+p2c (encode) alias within
//   end = CE+59,609,088 = 62,148,384
// ---------------------------------------------------------------------------

__global__ void k_detect(const unsigned short* __restrict__ xb, int nscan, int* flag)
{
    __shared__ int cnt_s[256];
    int tid = threadIdx.x;
    int c = 0;
    for (int i = tid; i < nscan; i += 256) {
        unsigned int e = (xb[i] >> 7) & 0xFF;
        c += (e >= 0xC0);
    }
    cnt_s[tid] = c;
    __syncthreads();
    for (int off = 128; off > 0; off >>= 1) {
        if (tid < off) cnt_s[tid] += cnt_s[tid + off];
        __syncthreads();
    }
    if (tid == 0) *flag = (cnt_s[0] > 1000) ? 1 : 0;
}

__global__ __launch_bounds__(256) void k_canon(
    const void* __restrict__ src, bf16* __restrict__ dst, int n,
    const int* __restrict__ flag)
{
    int i = blockIdx.x * 256 + threadIdx.x;
    if (i >= n) return;
    if (*flag) dst[i] = f2b(((const float*)src)[i]);
    else       dst[i] = ((const bf16*)src)[i];
}

// K1: conv 3->64 + relu + pool : x[f0+z] -> p1c[z,64,42,42], z in [0,32)
__global__ __launch_bounds__(256) void k_conv1_pool(
    const void* __restrict__ xv, const bf16* __restrict__ w,
    const bf16* __restrict__ bias, bf16* __restrict__ p1c, int fbase,
    const int* __restrict__ flag)
{
    __shared__ __align__(16) float in_s[3][16][16];
    __shared__ __align__(16) float w_s[1728];
    __shared__ __align__(16) float b_s[64];
    const int z = blockIdx.y;
    const int n = fbase + z;
    const int ty = blockIdx.x / 6, tx = blockIdx.x % 6;
    const int tid = threadIdx.x;
    const int isf32 = *flag;
    for (int i = tid; i < 1728; i += 256) w_s[i] = b2f(w[i]);
    if (tid < 64) b_s[tid] = b2f(bias[tid]);
    const int iy0 = ty * 14 - 1, ix0 = tx * 14 - 1;
    for (int i = tid; i < 768; i += 256) {
        int ci = i >> 8, r = (i >> 4) & 15, col = i & 15;
        int gy = iy0 + r, gx = ix0 + col;
        float v = 0.f;
        if (gy >= 0 && gy < 84 && gx >= 0 && gx < 84) {
            int idx = (n * 3 + ci) * 7056 + gy * 84 + gx;
            v = isf32 ? ((const float*)xv)[idx] : b2f(((const bf16*)xv)[idx]);
        }
        in_s[ci][r][col] = v;
    }
    __syncthreads();
    for (int idx = tid; idx < 3136; idx += 256) {
        int oc = idx / 49, p = idx % 49;
        int py = p / 7, px = p % 7;
        float m = 0.f;
        #pragma unroll
        for (int pp = 0; pp < 4; ++pp) {
            int a = pp >> 1, bb = pp & 1;
            float sacc = b_s[oc];
            for (int ci = 0; ci < 3; ++ci)
                #pragma unroll
                for (int ky = 0; ky < 3; ++ky)
                    #pragma unroll
                    for (int kx = 0; kx < 3; ++kx)
                        sacc += w_s[(oc * 3 + ci) * 9 + ky * 3 + kx] *
                                in_s[ci][2 * py + a + ky][2 * px + bb + kx];
            m = fmaxf(m, sacc);
        }
        p1c[((z * 64 + oc) * 42 + ty * 7 + py) * 42 + tx * 7 + px] = f2b(m);
    }
}

// K2: conv 64->128 + relu + pool : p1c[z] -> p2c[z,128,21,21]
__global__ __launch_bounds__(256) void k_conv2_pool(
    const bf16* __restrict__ p1c, const bf16* __restrict__ w,
    const bf16* __restrict__ bias, bf16* __restrict__ p2c)
{
    __shared__ __align__(16) float in_s[16][8][44];
    __shared__ __align__(16) float w_s[16][9][32];
    const int z = blockIdx.z, rt = blockIdx.x, oq = blockIdx.y;
    const int tid = threadIdx.x;
    const int s = tid & 63, og = tid >> 6;
    const int pr = (s < 63) ? (s / 21) : 2, pc = s % 21;
    const bool act = (s < 63);
    const int r0 = rt * 3;
    const int iy0 = r0 * 2 - 1;
    float acc[32];
    #pragma unroll
    for (int i = 0; i < 32; ++i) acc[i] = 0.f;
    for (int cc = 0; cc < 4; ++cc) {
        const int c0 = cc * 16;
        __syncthreads();
        for (int i = tid; i < 5632; i += 256) {
            int ci = i / 352, rem = i % 352, r = rem / 44, col = rem % 44;
            int gy = iy0 + r, gx = col - 1;
            float v = 0.f;
            if (gy >= 0 && gy < 42 && gx >= 0 && gx < 42)
                v = b2f(p1c[((z * 64 + c0 + ci) * 42 + gy) * 42 + gx]);
            in_s[ci][r][col] = v;
        }
        for (int i = tid; i < 4608; i += 256) {
            int ci = i / 288, rem = i % 288, tap = rem / 32, ol = rem & 31;
            w_s[ci][tap][ol] = b2f(w[((oq * 32 + ol) * 64 + c0 + ci) * 9 + tap]);
        }
        __syncthreads();
        if (act) {
            #pragma unroll 1
            for (int ci = 0; ci < 16; ++ci) {
                float iv[4][4];
                #pragma unroll
                for (int r = 0; r < 4; ++r)
                    #pragma unroll
                    for (int col = 0; col < 4; ++col)
                        iv[r][col] = in_s[ci][2 * pr + r][2 * pc + col];
                #pragma unroll
                for (int tap = 0; tap < 9; ++tap) {
                    const int ky = tap / 3, kx = tap % 3;
                    const float4 w0 = *(const float4*)&w_s[ci][tap][og * 8];
                    const float4 w1 = *(const float4*)&w_s[ci][tap][og * 8 + 4];
                    const float wv[8] = {w0.x, w0.y, w0.z, w0.w, w1.x, w1.y, w1.z, w1.w};
                    #pragma unroll
                    for (int j = 0; j < 8; ++j)
                        #pragma unroll
                        for (int pp = 0; pp < 4; ++pp)
                            acc[j * 4 + pp] += wv[j] * iv[(pp >> 1) + ky][(pp & 1) + kx];
                }
            }
        }
    }
    if (act) {
        #pragma unroll
        for (int j = 0; j < 8; ++j) {
            const int oc = oq * 32 + og * 8 + j;
            const float bv = b2f(bias[oc]);
            float m = 0.f;
            #pragma unroll
            for (int pp = 0; pp < 4; ++pp) m = fmaxf(m, acc[j * 4 + pp] + bv);
            p2c[((z * 128 + oc) * 21 + r0 + pr) * 21 + pc] = f2b(m);
        }
    }
}

// K3: conv 128->256 + relu : p2c[z] -> feats slot ((t*8+b)), n = fbase+z
__global__ __launch_bounds__(256) void k_conv3(
    const bf16* __restrict__ p2c, const bf16* __restrict__ w,
    const bf16* __restrict__ bias, bf16* __restrict__ feats, int fbase)
{
    __shared__ __align__(16) float in_s[16][8][23];
    __shared__ __align__(16) float w_s[16][9][32];
    const int z = blockIdx.z, rt = blockIdx.x, oq = blockIdx.y;
    const int n = fbase + z;
    const int slot = (n & 15) * 8 + (n >> 4);   // t*8 + b
    const int tid = threadIdx.x;
    const int s = tid & 63, og = tid >> 6;
    const bool act = (s < 63);
    const int lr = (s < 63) ? (s / 21) : 2, col = s % 21;
    const int r0 = rt * 6;
    float acc[16];
    #pragma unroll
    for (int i = 0; i < 16; ++i) acc[i] = 0.f;
    for (int cc = 0; cc < 8; ++cc) {
        const int c0 = cc * 16;
        __syncthreads();
        for (int i = tid; i < 2944; i += 256) {
            int ci = i / 184, rem = i % 184, r = rem / 23, gcol = rem % 23;
            int gy = r0 - 1 + r, gx = gcol - 1;
            float v = 0.f;
            if (gy >= 0 && gy < 21 && gx >= 0 && gx < 21)
                v = b2f(p2c[((z * 128 + c0 + ci) * 21 + gy) * 21 + gx]);
            in_s[ci][r][gcol] = v;
        }
        for (int i = tid; i < 4608; i += 256) {
            int ci = i / 288, rem = i % 288, tap = rem / 32, ol = rem & 31;
            w_s[ci][tap][ol] = b2f(w[((oq * 32 + ol) * 128 + c0 + ci) * 9 + tap]);
        }
        __syncthreads();
        if (act) {
            #pragma unroll 1
            for (int ci = 0; ci < 16; ++ci) {
                float iv0[3][3], iv1[3][3];
                #pragma unroll
                for (int r = 0; r < 3; ++r)
                    #pragma unroll
                    for (int q = 0; q < 3; ++q) {
                        iv0[r][q] = in_s[ci][lr + r][col + q];
                        iv1[r][q] = in_s[ci][lr + 3 + r][col + q];
                    }
                #pragma unroll
                for (int tap = 0; tap < 9; ++tap) {
                    const int ky = tap / 3, kx = tap % 3;
                    const float4 w0 = *(const float4*)&w_s[ci][tap][og * 8];
                    const float4 w1 = *(const float4*)&w_s[ci][tap][og * 8 + 4];
                    const float wv[8] = {w0.x, w0.y, w0.z, w0.w, w1.x, w1.y, w1.z, w1.w};
                    #pragma unroll
                    for (int j = 0; j < 8; ++j) {
                        acc[j]     += wv[j] * iv0[ky][kx];
                        acc[j + 8] += wv[j] * iv1[ky][kx];
                    }
                }
            }
        }
    }
    if (act) {
        const int oy0 = r0 + lr, oy1 = oy0 + 3;
        #pragma unroll
        for (int j = 0; j < 8; ++j) {
            const int oc = oq * 32 + og * 8 + j;
            const float bv = b2f(bias[oc]);
            if (oy0 < 21)
                feats[((slot * 256 + oc) * 21 + oy0) * 21 + col] = f2b(fmaxf(acc[j] + bv, 0.f));
            if (oy1 < 21)
                feats[((slot * 256 + oc) * 21 + oy1) * 21 + col] = f2b(fmaxf(acc[j + 8] + bv, 0.f));
        }
    }
}

// K4: depthwise 3x3 on [feats slot t | h] -> dwout f32 [8,512,441]
__global__ __launch_bounds__(256) void k_dw(
    const bf16* __restrict__ feats, const float* __restrict__ h,
    const bf16* __restrict__ dww, float* __restrict__ dwout, int t)
{
    int idx = blockIdx.x * 256 + threadIdx.x;
    if (idx >= 8 * 512 * 441) return;
    const int p = idx % 441;
    const int ch = (idx / 441) & 511;
    const int b = idx / (441 * 512);
    const int y = p / 21, x = p % 21;
    float wv[9];
    #pragma unroll
    for (int k = 0; k < 9; ++k) wv[k] = b2f(dww[ch * 9 + k]);
    float s = 0.f;
    #pragma unroll
    for (int ky = 0; ky < 3; ++ky) {
        int iy = y + ky - 1;
        if (iy < 0 || iy >= 21) continue;
        #pragma unroll
        for (int kx = 0; kx < 3; ++kx) {
            int ix = x + kx - 1;
            if (ix < 0 || ix >= 21) continue;
            float v;
            if (ch < 256) v = b2f(feats[((t * 8 + b) * 256 + ch) * 441 + iy * 21 + ix]);
            else          v = h[(b * 256 + (ch - 256)) * 441 + iy * 21 + ix];
            s += wv[ky * 3 + kx] * v;
        }
    }
    dwout[idx] = s;
}

// K5: pointwise 512->1024 + gates; updates h,c; writes hst[b*112896 + ...]
// block: 32 px x 8 cg (4ch x 4 gates); grid (14, 8, 8)
__global__ __launch_bounds__(256) void k_pw_gate(
    const float* __restrict__ dwout, const bf16* __restrict__ pww,
    const bf16* __restrict__ pwb, float* __restrict__ h, float* __restrict__ c,
    bf16* __restrict__ hst)
{
    __shared__ __align__(16) float a_s[32][32];
    __shared__ __align__(16) float w_s[32][128];
    const int b = blockIdx.z, cq = blockIdx.y, pt = blockIdx.x;
    const int tid = threadIdx.x;
    const int s = tid & 31, cg = tid >> 5;
    const int p0 = pt * 32 + s;
    float acc[16];
    #pragma unroll
    for (int i = 0; i < 16; ++i) acc[i] = 0.f;
    for (int kk = 0; kk < 512; kk += 32) {
        __syncthreads();
        for (int i = tid; i < 1024; i += 256) {
            int k = i >> 5, pix = i & 31;
            int gp = pt * 32 + pix;
            a_s[k][pix] = (gp < 441) ? dwout[(b * 512 + kk + k) * 441 + gp] : 0.f;
        }
        for (int i = tid; i < 4096; i += 256) {
            int k = i >> 7, j = i & 127;
            int cgl = j >> 4, ccl = (j >> 2) & 3, gate = j & 3;
            int oc = gate * 256 + cq * 32 + cgl * 4 + ccl;
            w_s[k][j] = b2f(pww[oc * 512 + kk + k]);
        }
        __syncthreads();
        #pragma unroll 4
        for (int k = 0; k < 32; ++k) {
            const float a0 = a_s[k][s];
            const float4 q0 = *(const float4*)&w_s[k][cg * 16];
            const float4 q1 = *(const float4*)&w_s[k][cg * 16 + 4];
            const float4 q2 = *(const float4*)&w_s[k][cg * 16 + 8];
            const float4 q3 = *(const float4*)&w_s[k][cg * 16 + 12];
            const float wv[16] = {q0.x, q0.y, q0.z, q0.w, q1.x, q1.y, q1.z, q1.w,
                                  q2.x, q2.y, q2.z, q2.w, q3.x, q3.y, q3.z, q3.w};
            #pragma unroll
            for (int j = 0; j < 16; ++j) acc[j] += wv[j] * a0;
        }
    }
    if (p0 < 441) {
        #pragma unroll
        for (int ccl = 0; ccl < 4; ++ccl) {
            const int ch = cq * 32 + cg * 4 + ccl;
            float ig = sigf(acc[ccl * 4 + 0] + b2f(pwb[ch]));
            float fg = sigf(acc[ccl * 4 + 1] + b2f(pwb[256 + ch]));
            float og = sigf(acc[ccl * 4 + 2] + b2f(pwb[512 + ch]));
            float gg = tanhfast(acc[ccl * 4 + 3] + b2f(pwb[768 + ch]));
            int ci2 = (b * 256 + ch) * 441 + p0;
            float c2 = fg * c[ci2] + ig * gg;
            float h2 = og * tanhfast(c2);
            c[ci2] = c2; h[ci2] = h2;
            hst[ci2] = f2b(h2);
        }
    }
}

// K6: up2 + conv 256->128 + relu : hs frame (b,t) -> d1c[z,128,42,42]
// grid (14 rt, 4 oq, 16 z); thread: 1 px (3 rows x 42 cols) x 16 oc; ci-chunk 8
__global__ __launch_bounds__(256) void k_dec1(
    const bf16* __restrict__ feats, const bf16* __restrict__ hs0,
    const bf16* __restrict__ w, const bf16* __restrict__ bias,
    bf16* __restrict__ d1c, int c0f)
{
    __shared__ __align__(16) float in_s[8][3][23];
    __shared__ __align__(16) float wr_s[8][2][2][3][32];  // [ic][py][a][kx][oc]
    const int z = blockIdx.z, rt = blockIdx.x, oq = blockIdx.y;
    const int n = c0f + z, bb = n >> 4, tt = n & 15;
    const bf16* hsf = (tt == 0) ? (hs0 + bb * 112896)
                                : (feats + (((tt - 1) * 8 + bb) * 112896));
    const int tid = threadIdx.x;
    const int s = tid & 127, og = tid >> 7;
    const bool act = (s < 126);
    const int row = act ? (s / 42) : 0, col = s % 42;
    const int r0 = rt * 3;
    const int oy = r0 + row;
    const int py = oy & 1;
    const int base = ((r0 + 1) >> 1) - 1;
    const int rlb = ((oy + 1) >> 1) - 1 - base;
    int cs[3];
    #pragma unroll
    for (int kx = 0; kx < 3; ++kx) cs[kx] = (col + kx + 1) >> 1;
    float acc[16];
    #pragma unroll
    for (int i = 0; i < 16; ++i) acc[i] = 0.f;
    for (int cc = 0; cc < 32; ++cc) {
        const int ci0 = cc * 8;
        __syncthreads();
        for (int i = tid; i < 552; i += 256) {
            int ci = i / 69, rem = i % 69, r = rem / 23, gc = rem % 23;
            int gy = base + r, gx = gc - 1;
            float v = 0.f;
            if (gy >= 0 && gy < 21 && gx >= 0 && gx < 21)
                v = b2f(hsf[(ci0 + ci) * 441 + gy * 21 + gx]);
            in_s[ci][r][gc] = v;
        }
        for (int i = tid; i < 3072; i += 256) {
            int ol = i & 31; int rest = i >> 5;
            int kx = rest % 3; rest /= 3;
            int a = rest & 1; rest >>= 1;
            int pyi = rest & 1; int ci = rest >> 1;
            const bf16* wb = w + ((oq * 32 + ol) * 256 + ci0 + ci) * 9;
            float v;
            if (pyi == 0) v = (a == 0) ? b2f(wb[kx]) : b2f(wb[3 + kx]) + b2f(wb[6 + kx]);
            else          v = (a == 0) ? b2f(wb[kx]) + b2f(wb[3 + kx]) : b2f(wb[6 + kx]);
            wr_s[ci][pyi][a][kx][ol] = v;
        }
        __syncthreads();
        #pragma unroll 2
        for (int ci = 0; ci < 8; ++ci) {
            #pragma unroll
            for (int a = 0; a < 2; ++a) {
                #pragma unroll
                for (int kx = 0; kx < 3; ++kx) {
                    const float v0 = in_s[ci][rlb + a][cs[kx]];
                    const float4 q0 = *(const float4*)&wr_s[ci][py][a][kx][og * 16];
                    const float4 q1 = *(const float4*)&wr_s[ci][py][a][kx][og * 16 + 4];
                    const float4 q2 = *(const float4*)&wr_s[ci][py][a][kx][og * 16 + 8];
                    const float4 q3 = *(const float4*)&wr_s[ci][py][a][kx][og * 16 + 12];
                    const float wv[16] = {q0.x, q0.y, q0.z, q0.w, q1.x, q1.y, q1.z, q1.w,
                                          q2.x, q2.y, q2.z, q2.w, q3.x, q3.y, q3.z, q3.w};
                    #pragma unroll
                    for (int j = 0; j < 16; ++j) acc[j] += wv[j] * v0;
                }
            }
        }
    }
    if (act) {
        #pragma unroll
        for (int j = 0; j < 16; ++j) {
            const int oc = oq * 32 + og * 16 + j;
            d1c[((z * 128 + oc) * 42 + oy) * 42 + col] =
                f2b(fmaxf(acc[j] + b2f(bias[oc]), 0.f));
        }
    }
}

// K7: up2 + conv 128->64 + relu : d1c[z] -> d2c[z,64,84,84]
// grid (28 rt, 2 oq, 16 z); thread: 2 px x 16 oc; ci-chunk 8
__global__ __launch_bounds__(256) void k_dec2(
    const bf16* __restrict__ d1c, const bf16* __restrict__ w,
    const bf16* __restrict__ bias, bf16* __restrict__ d2c)
{
    __shared__ __align__(16) float in_s[8][3][44];
    __shared__ __align__(16) float wr_s[8][2][2][3][32];
    const int z = blockIdx.z, rt = blockIdx.x, oq = blockIdx.y;
    const int tid = threadIdx.x;
    const int s = tid & 127, og = tid >> 7;
    const bool act = (s < 126);
    const int row = act ? (s / 42) : 0, col0 = s % 42, col1 = col0 + 42;
    const int r0 = rt * 3;
    const int oy = r0 + row;
    const int py = oy & 1;
    const int base = ((r0 + 1) >> 1) - 1;
    const int rlb = ((oy + 1) >> 1) - 1 - base;
    int cs0[3], cs1[3];
    #pragma unroll
    for (int kx = 0; kx < 3; ++kx) {
        cs0[kx] = (col0 + kx + 1) >> 1;
        cs1[kx] = (col1 + kx + 1) >> 1;
    }
    float acc0[16], acc1[16];
    #pragma unroll
    for (int i = 0; i < 16; ++i) { acc0[i] = 0.f; acc1[i] = 0.f; }
    for (int cc = 0; cc < 16; ++cc) {
        const int ci0 = cc * 8;
        __syncthreads();
        for (int i = tid; i < 1056; i += 256) {
            int ci = i / 132, rem = i % 132, r = rem / 44, gc = rem % 44;
            int gy = base + r, gx = gc - 1;
            float v = 0.f;
            if (gy >= 0 && gy < 42 && gx >= 0 && gx < 42)
                v = b2f(d1c[((z * 128 + ci0 + ci) * 42 + gy) * 42 + gx]);
            in_s[ci][r][gc] = v;
        }
        for (int i = tid; i < 3072; i += 256) {
            int ol = i & 31; int rest = i >> 5;
            int kx = rest % 3; rest /= 3;
            int a = rest & 1; rest >>= 1;
            int pyi = rest & 1; int ci = rest >> 1;
            const bf16* wb = w + ((oq * 32 + ol) * 128 + ci0 + ci) * 9;
            float v;
            if (pyi == 0) v = (a == 0) ? b2f(wb[kx]) : b2f(wb[3 + kx]) + b2f(wb[6 + kx]);
            else          v = (a == 0) ? b2f(wb[kx]) + b2f(wb[3 + kx]) : b2f(wb[6 + kx]);
            wr_s[ci][pyi][a][kx][ol] = v;
        }
        __syncthreads();
        #pragma unroll 2
        for (int ci = 0; ci < 8; ++ci) {
            #pragma unroll
            for (int a = 0; a < 2; ++a) {
                #pragma unroll
                for (int kx = 0; kx < 3; ++kx) {
                    const float v0 = in_s[ci][rlb + a][cs0[kx]];
                    const float v1 = in_s[ci][rlb + a][cs1[kx]];
                    const float4 q0 = *(const float4*)&wr_s[ci][py][a][kx][og * 16];
                    const float4 q1 = *(const float4*)&wr_s[ci][py][a][kx][og * 16 + 4];
                    const float4 q2 = *(const float4*)&wr_s[ci][py][a][kx][og * 16 + 8];
                    const float4 q3 = *(const float4*)&wr_s[ci][py][a][kx][og * 16 + 12];
                    const float wv[16] = {q0.x, q0.y, q0.z, q0.w, q1.x, q1.y, q1.z, q1.w,
                                          q2.x, q2.y, q2.z, q2.w, q3.x, q3.y, q3.z, q3.w};
                    #pragma unroll
                    for (int j = 0; j < 16; ++j) {
                        acc0[j] += wv[j] * v0;
                        acc1[j] += wv[j] * v1;
                    }
                }
            }
        }
    }
    if (act) {
        #pragma unroll
        for (int j = 0; j < 16; ++j) {
            const int oc = oq * 32 + og * 16 + j;
            const float bv = b2f(bias[oc]);
            d2c[((z * 64 + oc) * 84 + oy) * 84 + col0] = f2b(fmaxf(acc0[j] + bv, 0.f));
            d2c[((z * 64 + oc) * 84 + oy) * 84 + col1] = f2b(fmaxf(acc1[j] + bv, 0.f));
        }
    }
}

// K8: 1x1 conv 64->1 : d2c[z] -> out frame (c0f+z)
__global__ __launch_bounds__(256) void k_dec3(
    const bf16* __restrict__ d2c, const bf16* __restrict__ w3,
    const bf16* __restrict__ b3, void* __restrict__ out, int c0f,
    const int* __restrict__ flag)
{
    const int idx = blockIdx.x * 256 + threadIdx.x;
    if (idx >= 16 * 7056) return;
    const int z = idx / 7056, p = idx % 7056;
    float s = b2f(b3[0]);
    const bf16* bp = d2c + z * 64 * 7056 + p;
    #pragma unroll
    for (int ci = 0; ci < 64; ++ci)
        s += b2f(w3[ci]) * b2f(bp[ci * 7056]);
    const int oi = (c0f + z) * 7056 + p;
    if (*flag) ((float*)out)[oi] = s;
    else       ((bf16*)out)[oi]  = f2b(s);
}

// K9: flush final h,c -> d_out
__global__ __launch_bounds__(256) void k_out_hc(
    const float* __restrict__ h, const float* __restrict__ c,
    void* __restrict__ out, const int* __restrict__ flag)
{
    int idx = blockIdx.x * 256 + threadIdx.x;
    if (idx >= 903168) return;
    if (*flag) {
        ((float*)out)[903168 + idx] = h[idx];
        ((float*)out)[1806336 + idx] = c[idx];
    } else {
        ((bf16*)out)[903168 + idx]  = f2b(h[idx]);
        ((bf16*)out)[1806336 + idx] = f2b(c[idx]);
    }
}

extern "C" void kernel_launch(void* const* d_in, const int* in_sizes, int n_in,
                              void* d_out, int out_size, void* d_ws, size_t ws_size,
                              hipStream_t stream)
{
    char* wsb = (char*)d_ws;
    static const int wsz[15] = {1728, 64, 73728, 128, 294912, 256, 4608, 524288,
                                1024, 294912, 128, 73728, 64, 64, 1};
    static const long woff[15] = {0, 3456, 3584, 151040, 151296, 741120, 741632,
                                  750848, 1799424, 1801472, 2391296, 2391552,
                                  2539008, 2539136, 2539264};
    const long FLAG_OFF = 2539280;
    const long CE = 2539296;
    int* flag = (int*)(wsb + FLAG_OFF);

    k_detect<<<1, 256, 0, stream>>>((const unsigned short*)d_in[0], 262144, flag);
    bf16* cw[15];
    for (int i = 0; i < 15; ++i) {
        cw[i] = (bf16*)(wsb + woff[i]);
        k_canon<<<(wsz[i] + 255) / 256, 256, 0, stream>>>(d_in[i + 1], cw[i], wsz[i], flag);
    }
    const void* x = d_in[0];
    bf16 *enc_w1 = cw[0], *enc_b1 = cw[1], *enc_w2 = cw[2], *enc_b2 = cw[3],
         *enc_w3 = cw[4], *enc_b3 = cw[5], *dw_w = cw[6], *pw_w = cw[7],
         *pw_b = cw[8], *dec_w1 = cw[9], *dec_b1 = cw[10], *dec_w2 = cw[11],
         *dec_b2 = cw[12], *dec_w3 = cw[13], *dec_b3 = cw[14];

    bf16*  feats = (bf16*)(wsb + CE);                     // 28,901,376 (t-major slots)
    bf16*  hs0   = (bf16*)(wsb + CE + 28901376);          //  1,806,336
    float* hbuf  = (float*)(wsb + CE + 30707712);         //  3,612,672
    float* cbuf  = (float*)(wsb + CE + 34320384);         //  3,612,672
    float* dwout = (float*)(wsb + CE + 37933056);         //  7,225,344
    bf16*  d1c   = (bf16*)(wsb + CE + 37933056);          //  aliases dwout (decode)
    bf16*  d2c   = (bf16*)(wsb + CE + 45158400);          // 14,450,688
    bf16*  p1c   = (bf16*)(wsb + CE + 45158400);          //  encode alias in d2c
    bf16*  p2c   = (bf16*)(wsb + CE + 52383744);          //  encode alias in d2c

    for (int f0 = 0; f0 < 128; f0 += 32) {
        k_conv1_pool<<<dim3(36, 32), 256, 0, stream>>>(x, enc_w1, enc_b1, p1c, f0, flag);
        k_conv2_pool<<<dim3(7, 4, 32), 256, 0, stream>>>(p1c, enc_w2, enc_b2, p2c);
        k_conv3<<<dim3(4, 8, 32), 256, 0, stream>>>(p2c, enc_w3, enc_b3, feats, f0);
    }
    hipMemsetAsync(hbuf, 0, 2 * 3612672, stream);
    for (int t = 0; t < 16; ++t) {
        bf16* hst = (t == 0) ? hs0 : (feats + (long)(t - 1) * 8 * 112896);
        k_dw<<<7056, 256, 0, stream>>>(feats, hbuf, dw_w, dwout, t);
        k_pw_gate<<<dim3(14, 8, 8), 256, 0, stream>>>(dwout, pw_w, pw_b, hbuf, cbuf, hst);
    }
    k_out_hc<<<3528, 256, 0, stream>>>(hbuf, cbuf, d_out, flag);
    for (int c0f = 0; c0f < 128; c0f += 16) {
        k_dec1<<<dim3(14, 4, 16), 256, 0, stream>>>(feats, hs0, dec_w1, dec_b1, d1c, c0f);
        k_dec2<<<dim3(28, 2, 16), 256, 0, stream>>>(d1c, dec_w2, dec_b2, d2c);
        k_dec3<<<441, 256, 0, stream>>>(d2c, dec_w3, dec_b3, d_out, c0f, flag);
    }
}

// Round 6
// 9175.861 us; speedup vs baseline: 1.3345x; 1.1473x over previous
//
#include <hip/hip_runtime.h>
#include <hip/hip_bf16.h>

typedef __hip_bfloat16 bf16;
#define DEV static __device__ __forceinline__

DEV float b2f(bf16 v) { return __bfloat162float(v); }
DEV bf16  f2b(float v) { return __float2bfloat16(v); }
DEV float sigf(float x) { return 1.0f / (1.0f + __expf(-x)); }
DEV float tanhfast(float x) { return 2.0f / (1.0f + __expf(-2.0f * x)) - 1.0f; }

// ---------------------------------------------------------------------------
// fp32 I/O (proved r4). B=8,T=16. Encoder 3->64@84p, 64->128@42p, 128->256@21.
// ConvLSTM @21x21 (dw 512ch, pw 512->1024). Decoder up2conv 256->128,
// up2conv 128->64 FUSED with 1x1 64->1 (partial-sum + atomicAdd).
//
// Round-6: dec1 back to 2px/thread (64:60 VALU:LDS), 32-frame decode chunks
// (grid 896); dec2+dec3 fused (no d2c, no dec3 launches); pw_gate back to
// 2px/thread (448 blocks).
//
// ws layout (peak 55,826,208 <= confirmed 63,954,720):
//   [0, CE)  canonical bf16 weights + flag, CE = 2,539,296
//   feats @CE              28,901,376  (t-major slots t*8+b)
//   hs0   @CE+28,901,376    1,806,336
//   h     @CE+30,707,712    3,612,672 f32
//   c     @CE+34,320,384    3,612,672 f32
//   dwout @CE+37,933,056    7,225,344 f32 (LSTM)   | d1c (decode) 14,450,688
//   p1c   @CE+37,933,056 (encode, in dwout/d1c region)
//   p2c   @CE+45,158,400    3,612,672 (encode)
//   outacc@CE+52,383,744      903,168 f32 (decode, memset per chunk)
// ---------------------------------------------------------------------------

__global__ void k_detect(const unsigned short* __restrict__ xb, int nscan, int* flag)
{
    __shared__ int cnt_s[256];
    int tid = threadIdx.x;
    int c = 0;
    for (int i = tid; i < nscan; i += 256) {
        unsigned int e = (xb[i] >> 7) & 0xFF;
        c += (e >= 0xC0);
    }
    cnt_s[tid] = c;
    __syncthreads();
    for (int off = 128; off > 0; off >>= 1) {
        if (tid < off) cnt_s[tid] += cnt_s[tid + off];
        __syncthreads();
    }
    if (tid == 0) *flag = (cnt_s[0] > 1000) ? 1 : 0;
}

__global__ __launch_bounds__(256) void k_canon(
    const void* __restrict__ src, bf16* __restrict__ dst, int n,
    const int* __restrict__ flag)
{
    int i = blockIdx.x * 256 + threadIdx.x;
    if (i >= n) return;
    if (*flag) dst[i] = f2b(((const float*)src)[i]);
    else       dst[i] = ((const bf16*)src)[i];
}

// K1: conv 3->64 + relu + pool : x[f0+z] -> p1c[z,64,42,42]
__global__ __launch_bounds__(256) void k_conv1_pool(
    const void* __restrict__ xv, const bf16* __restrict__ w,
    const bf16* __restrict__ bias, bf16* __restrict__ p1c, int fbase,
    const int* __restrict__ flag)
{
    __shared__ __align__(16) float in_s[3][16][16];
    __shared__ __align__(16) float w_s[1728];
    __shared__ __align__(16) float b_s[64];
    const int z = blockIdx.y;
    const int n = fbase + z;
    const int ty = blockIdx.x / 6, tx = blockIdx.x % 6;
    const int tid = threadIdx.x;
    const int isf32 = *flag;
    for (int i = tid; i < 1728; i += 256) w_s[i] = b2f(w[i]);
    if (tid < 64) b_s[tid] = b2f(bias[tid]);
    const int iy0 = ty * 14 - 1, ix0 = tx * 14 - 1;
    for (int i = tid; i < 768; i += 256) {
        int ci = i >> 8, r = (i >> 4) & 15, col = i & 15;
        int gy = iy0 + r, gx = ix0 + col;
        float v = 0.f;
        if (gy >= 0 && gy < 84 && gx >= 0 && gx < 84) {
            int idx = (n * 3 + ci) * 7056 + gy * 84 + gx;
            v = isf32 ? ((const float*)xv)[idx] : b2f(((const bf16*)xv)[idx]);
        }
        in_s[ci][r][col] = v;
    }
    __syncthreads();
    for (int idx = tid; idx < 3136; idx += 256) {
        int oc = idx / 49, p = idx % 49;
        int py = p / 7, px = p % 7;
        float m = 0.f;
        #pragma unroll
        for (int pp = 0; pp < 4; ++pp) {
            int a = pp >> 1, bb = pp & 1;
            float sacc = b_s[oc];
            for (int ci = 0; ci < 3; ++ci)
                #pragma unroll
                for (int ky = 0; ky < 3; ++ky)
                    #pragma unroll
                    for (int kx = 0; kx < 3; ++kx)
                        sacc += w_s[(oc * 3 + ci) * 9 + ky * 3 + kx] *
                                in_s[ci][2 * py + a + ky][2 * px + bb + kx];
            m = fmaxf(m, sacc);
        }
        p1c[((z * 64 + oc) * 42 + ty * 7 + py) * 42 + tx * 7 + px] = f2b(m);
    }
}

// K2: conv 64->128 + relu + pool : p1c[z] -> p2c[z,128,21,21]
__global__ __launch_bounds__(256) void k_conv2_pool(
    const bf16* __restrict__ p1c, const bf16* __restrict__ w,
    const bf16* __restrict__ bias, bf16* __restrict__ p2c)
{
    __shared__ __align__(16) float in_s[16][8][44];
    __shared__ __align__(16) float w_s[16][9][32];
    const int z = blockIdx.z, rt = blockIdx.x, oq = blockIdx.y;
    const int tid = threadIdx.x;
    const int s = tid & 63, og = tid >> 6;
    const int pr = (s < 63) ? (s / 21) : 2, pc = s % 21;
    const bool act = (s < 63);
    const int r0 = rt * 3;
    const int iy0 = r0 * 2 - 1;
    float acc[32];
    #pragma unroll
    for (int i = 0; i < 32; ++i) acc[i] = 0.f;
    for (int cc = 0; cc < 4; ++cc) {
        const int c0 = cc * 16;
        __syncthreads();
        for (int i = tid; i < 5632; i += 256) {
            int ci = i / 352, rem = i % 352, r = rem / 44, col = rem % 44;
            int gy = iy0 + r, gx = col - 1;
            float v = 0.f;
            if (gy >= 0 && gy < 42 && gx >= 0 && gx < 42)
                v = b2f(p1c[((z * 64 + c0 + ci) * 42 + gy) * 42 + gx]);
            in_s[ci][r][col] = v;
        }
        for (int i = tid; i < 4608; i += 256) {
            int ci = i / 288, rem = i % 288, tap = rem / 32, ol = rem & 31;
            w_s[ci][tap][ol] = b2f(w[((oq * 32 + ol) * 64 + c0 + ci) * 9 + tap]);
        }
        __syncthreads();
        if (act) {
            #pragma unroll 1
            for (int ci = 0; ci < 16; ++ci) {
                float iv[4][4];
                #pragma unroll
                for (int r = 0; r < 4; ++r)
                    #pragma unroll
                    for (int col = 0; col < 4; ++col)
                        iv[r][col] = in_s[ci][2 * pr + r][2 * pc + col];
                #pragma unroll
                for (int tap = 0; tap < 9; ++tap) {
                    const int ky = tap / 3, kx = tap % 3;
                    const float4 w0 = *(const float4*)&w_s[ci][tap][og * 8];
                    const float4 w1 = *(const float4*)&w_s[ci][tap][og * 8 + 4];
                    const float wv[8] = {w0.x, w0.y, w0.z, w0.w, w1.x, w1.y, w1.z, w1.w};
                    #pragma unroll
                    for (int j = 0; j < 8; ++j)
                        #pragma unroll
                        for (int pp = 0; pp < 4; ++pp)
                            acc[j * 4 + pp] += wv[j] * iv[(pp >> 1) + ky][(pp & 1) + kx];
                }
            }
        }
    }
    if (act) {
        #pragma unroll
        for (int j = 0; j < 8; ++j) {
            const int oc = oq * 32 + og * 8 + j;
            const float bv = b2f(bias[oc]);
            float m = 0.f;
            #pragma unroll
            for (int pp = 0; pp < 4; ++pp) m = fmaxf(m, acc[j * 4 + pp] + bv);
            p2c[((z * 128 + oc) * 21 + r0 + pr) * 21 + pc] = f2b(m);
        }
    }
}

// K3: conv 128->256 + relu : p2c[z] -> feats slot (t*8+b), n = fbase+z
__global__ __launch_bounds__(256) void k_conv3(
    const bf16* __restrict__ p2c, const bf16* __restrict__ w,
    const bf16* __restrict__ bias, bf16* __restrict__ feats, int fbase)
{
    __shared__ __align__(16) float in_s[16][8][23];
    __shared__ __align__(16) float w_s[16][9][32];
    const int z = blockIdx.z, rt = blockIdx.x, oq = blockIdx.y;
    const int n = fbase + z;
    const int slot = (n & 15) * 8 + (n >> 4);
    const int tid = threadIdx.x;
    const int s = tid & 63, og = tid >> 6;
    const bool act = (s < 63);
    const int lr = (s < 63) ? (s / 21) : 2, col = s % 21;
    const int r0 = rt * 6;
    float acc[16];
    #pragma unroll
    for (int i = 0; i < 16; ++i) acc[i] = 0.f;
    for (int cc = 0; cc < 8; ++cc) {
        const int c0 = cc * 16;
        __syncthreads();
        for (int i = tid; i < 2944; i += 256) {
            int ci = i / 184, rem = i % 184, r = rem / 23, gcol = rem % 23;
            int gy = r0 - 1 + r, gx = gcol - 1;
            float v = 0.f;
            if (gy >= 0 && gy < 21 && gx >= 0 && gx < 21)
                v = b2f(p2c[((z * 128 + c0 + ci) * 21 + gy) * 21 + gx]);
            in_s[ci][r][gcol] = v;
        }
        for (int i = tid; i < 4608; i += 256) {
            int ci = i / 288, rem = i % 288, tap = rem / 32, ol = rem & 31;
            w_s[ci][tap][ol] = b2f(w[((oq * 32 + ol) * 128 + c0 + ci) * 9 + tap]);
        }
        __syncthreads();
        if (act) {
            #pragma unroll 1
            for (int ci = 0; ci < 16; ++ci) {
                float iv0[3][3], iv1[3][3];
                #pragma unroll
                for (int r = 0; r < 3; ++r)
                    #pragma unroll
                    for (int q = 0; q < 3; ++q) {
                        iv0[r][q] = in_s[ci][lr + r][col + q];
                        iv1[r][q] = in_s[ci][lr + 3 + r][col + q];
                    }
                #pragma unroll
                for (int tap = 0; tap < 9; ++tap) {
                    const int ky = tap / 3, kx = tap % 3;
                    const float4 w0 = *(const float4*)&w_s[ci][tap][og * 8];
                    const float4 w1 = *(const float4*)&w_s[ci][tap][og * 8 + 4];
                    const float wv[8] = {w0.x, w0.y, w0.z, w0.w, w1.x, w1.y, w1.z, w1.w};
                    #pragma unroll
                    for (int j = 0; j < 8; ++j) {
                        acc[j]     += wv[j] * iv0[ky][kx];
                        acc[j + 8] += wv[j] * iv1[ky][kx];
                    }
                }
            }
        }
    }
    if (act) {
        const int oy0 = r0 + lr, oy1 = oy0 + 3;
        #pragma unroll
        for (int j = 0; j < 8; ++j) {
            const int oc = oq * 32 + og * 8 + j;
            const float bv = b2f(bias[oc]);
            if (oy0 < 21)
                feats[((slot * 256 + oc) * 21 + oy0) * 21 + col] = f2b(fmaxf(acc[j] + bv, 0.f));
            if (oy1 < 21)
                feats[((slot * 256 + oc) * 21 + oy1) * 21 + col] = f2b(fmaxf(acc[j + 8] + bv, 0.f));
        }
    }
}

// K4: depthwise 3x3 on [feats slot t | h] -> dwout f32 [8,512,441]
__global__ __launch_bounds__(256) void k_dw(
    const bf16* __restrict__ feats, const float* __restrict__ h,
    const bf16* __restrict__ dww, float* __restrict__ dwout, int t)
{
    int idx = blockIdx.x * 256 + threadIdx.x;
    if (idx >= 8 * 512 * 441) return;
    const int p = idx % 441;
    const int ch = (idx / 441) & 511;
    const int b = idx / (441 * 512);
    const int y = p / 21, x = p % 21;
    float wv[9];
    #pragma unroll
    for (int k = 0; k < 9; ++k) wv[k] = b2f(dww[ch * 9 + k]);
    float s = 0.f;
    #pragma unroll
    for (int ky = 0; ky < 3; ++ky) {
        int iy = y + ky - 1;
        if (iy < 0 || iy >= 21) continue;
        #pragma unroll
        for (int kx = 0; kx < 3; ++kx) {
            int ix = x + kx - 1;
            if (ix < 0 || ix >= 21) continue;
            float v;
            if (ch < 256) v = b2f(feats[((t * 8 + b) * 256 + ch) * 441 + iy * 21 + ix]);
            else          v = h[(b * 256 + (ch - 256)) * 441 + iy * 21 + ix];
            s += wv[ky * 3 + kx] * v;
        }
    }
    dwout[idx] = s;
}

// K5: pointwise 512->1024 + gates (2 px/thread); grid (7,8,8)
__global__ __launch_bounds__(256) void k_pw_gate(
    const float* __restrict__ dwout, const bf16* __restrict__ pww,
    const bf16* __restrict__ pwb, float* __restrict__ h, float* __restrict__ c,
    bf16* __restrict__ hst)
{
    __shared__ __align__(16) float a_s[32][64];
    __shared__ __align__(16) float w_s[32][128];
    const int b = blockIdx.z, cq = blockIdx.y, pt = blockIdx.x;
    const int tid = threadIdx.x;
    const int s = tid & 31, cg = tid >> 5;
    const int p0 = pt * 64 + s, p1 = p0 + 32;
    float acc0[16], acc1[16];
    #pragma unroll
    for (int i = 0; i < 16; ++i) { acc0[i] = 0.f; acc1[i] = 0.f; }
    for (int kk = 0; kk < 512; kk += 32) {
        __syncthreads();
        for (int i = tid; i < 2048; i += 256) {
            int k = i >> 6, pix = i & 63;
            int gp = pt * 64 + pix;
            a_s[k][pix] = (gp < 441) ? dwout[(b * 512 + kk + k) * 441 + gp] : 0.f;
        }
        for (int i = tid; i < 4096; i += 256) {
            int k = i >> 7, j = i & 127;
            int cgl = j >> 4, ccl = (j >> 2) & 3, gate = j & 3;
            int oc = gate * 256 + cq * 32 + cgl * 4 + ccl;
            w_s[k][j] = b2f(pww[oc * 512 + kk + k]);
        }
        __syncthreads();
        #pragma unroll 4
        for (int k = 0; k < 32; ++k) {
            const float a0 = a_s[k][s], a1 = a_s[k][s + 32];
            const float4 q0 = *(const float4*)&w_s[k][cg * 16];
            const float4 q1 = *(const float4*)&w_s[k][cg * 16 + 4];
            const float4 q2 = *(const float4*)&w_s[k][cg * 16 + 8];
            const float4 q3 = *(const float4*)&w_s[k][cg * 16 + 12];
            const float wv[16] = {q0.x, q0.y, q0.z, q0.w, q1.x, q1.y, q1.z, q1.w,
                                  q2.x, q2.y, q2.z, q2.w, q3.x, q3.y, q3.z, q3.w};
            #pragma unroll
            for (int j = 0; j < 16; ++j) { acc0[j] += wv[j] * a0; acc1[j] += wv[j] * a1; }
        }
    }
    #pragma unroll
    for (int ccl = 0; ccl < 4; ++ccl) {
        const int ch = cq * 32 + cg * 4 + ccl;
        const float bi = b2f(pwb[ch]);
        const float bfg = b2f(pwb[256 + ch]);
        const float bo = b2f(pwb[512 + ch]);
        const float bg = b2f(pwb[768 + ch]);
        if (p0 < 441) {
            float ig = sigf(acc0[ccl * 4 + 0] + bi);
            float fg = sigf(acc0[ccl * 4 + 1] + bfg);
            float og = sigf(acc0[ccl * 4 + 2] + bo);
            float gg = tanhfast(acc0[ccl * 4 + 3] + bg);
            int ci2 = (b * 256 + ch) * 441 + p0;
            float c2 = fg * c[ci2] + ig * gg;
            float h2 = og * tanhfast(c2);
            c[ci2] = c2; h[ci2] = h2;
            hst[ci2] = f2b(h2);
        }
        if (p1 < 441) {
            float ig = sigf(acc1[ccl * 4 + 0] + bi);
            float fg = sigf(acc1[ccl * 4 + 1] + bfg);
            float og = sigf(acc1[ccl * 4 + 2] + bo);
            float gg = tanhfast(acc1[ccl * 4 + 3] + bg);
            int ci2 = (b * 256 + ch) * 441 + p1;
            float c2 = fg * c[ci2] + ig * gg;
            float h2 = og * tanhfast(c2);
            c[ci2] = c2; h[ci2] = h2;
            hst[ci2] = f2b(h2);
        }
    }
}

// K6: up2 + conv 256->128 + relu (2px x 16oc/thread): -> d1c[z,128,42,42], z<32
__global__ __launch_bounds__(256) void k_dec1(
    const bf16* __restrict__ feats, const bf16* __restrict__ hs0,
    const bf16* __restrict__ w, const bf16* __restrict__ bias,
    bf16* __restrict__ d1c, int c0f)
{
    __shared__ __align__(16) float in_s[16][5][23];
    __shared__ __align__(16) float wr_s[16][2][2][3][32];
    const int z = blockIdx.z, rt = blockIdx.x, oq = blockIdx.y;
    const int n = c0f + z, bb = n >> 4, tt = n & 15;
    const bf16* hsf = (tt == 0) ? (hs0 + bb * 112896)
                                : (feats + (((tt - 1) * 8 + bb) * 112896));
    const int tid = threadIdx.x;
    const int s = tid & 127, og = tid >> 7;
    const bool act = (s < 126);
    const int row = act ? (s / 21) : 5, col0 = s % 21, col1 = col0 + 21;
    const int r0 = rt * 6;
    const int oy = r0 + row;
    const int py = oy & 1;
    const int rlb = (row + 1) >> 1;
    int cs0[3], cs1[3];
    #pragma unroll
    for (int kx = 0; kx < 3; ++kx) {
        cs0[kx] = (col0 + kx + 1) >> 1;
        cs1[kx] = (col1 + kx + 1) >> 1;
    }
    float acc0[16], acc1[16];
    #pragma unroll
    for (int i = 0; i < 16; ++i) { acc0[i] = 0.f; acc1[i] = 0.f; }
    for (int cc = 0; cc < 16; ++cc) {
        const int c0 = cc * 16;
        __syncthreads();
        for (int i = tid; i < 1840; i += 256) {
            int ci = i / 115, rem = i % 115, r = rem / 23, gc = rem % 23;
            int gy = 3 * rt - 1 + r, gx = gc - 1;
            float v = 0.f;
            if (gy >= 0 && gy < 21 && gx >= 0 && gx < 21)
                v = b2f(hsf[(c0 + ci) * 441 + gy * 21 + gx]);
            in_s[ci][r][gc] = v;
        }
        for (int i = tid; i < 6144; i += 256) {
            int ol = i & 31; int rest = i >> 5;
            int kx = rest % 3; rest /= 3;
            int a = rest & 1; rest >>= 1;
            int pyi = rest & 1; int ci = rest >> 1;
            const bf16* wb = w + ((oq * 32 + ol) * 256 + c0 + ci) * 9;
            float v;
            if (pyi == 0) v = (a == 0) ? b2f(wb[kx]) : b2f(wb[3 + kx]) + b2f(wb[6 + kx]);
            else          v = (a == 0) ? b2f(wb[kx]) + b2f(wb[3 + kx]) : b2f(wb[6 + kx]);
            wr_s[ci][pyi][a][kx][ol] = v;
        }
        __syncthreads();
        #pragma unroll 2
        for (int ci = 0; ci < 16; ++ci) {
            #pragma unroll
            for (int a = 0; a < 2; ++a) {
                #pragma unroll
                for (int kx = 0; kx < 3; ++kx) {
                    const float v0 = in_s[ci][rlb + a][cs0[kx]];
                    const float v1 = in_s[ci][rlb + a][cs1[kx]];
                    const float4 q0 = *(const float4*)&wr_s[ci][py][a][kx][og * 16];
                    const float4 q1 = *(const float4*)&wr_s[ci][py][a][kx][og * 16 + 4];
                    const float4 q2 = *(const float4*)&wr_s[ci][py][a][kx][og * 16 + 8];
                    const float4 q3 = *(const float4*)&wr_s[ci][py][a][kx][og * 16 + 12];
                    const float wv[16] = {q0.x, q0.y, q0.z, q0.w, q1.x, q1.y, q1.z, q1.w,
                                          q2.x, q2.y, q2.z, q2.w, q3.x, q3.y, q3.z, q3.w};
                    #pragma unroll
                    for (int j = 0; j < 16; ++j) {
                        acc0[j] += wv[j] * v0;
                        acc1[j] += wv[j] * v1;
                    }
                }
            }
        }
    }
    if (act) {
        #pragma unroll
        for (int j = 0; j < 16; ++j) {
            const int oc = oq * 32 + og * 16 + j;
            const float bv = b2f(bias[oc]);
            d1c[((z * 128 + oc) * 42 + oy) * 42 + col0] = f2b(fmaxf(acc0[j] + bv, 0.f));
            d1c[((z * 128 + oc) * 42 + oy) * 42 + col1] = f2b(fmaxf(acc1[j] + bv, 0.f));
        }
    }
}

// K7: up2 + conv 128->64 + relu FUSED with 1x1 64->1: atomicAdd partial sums
// grid (28 rt, 2 oq, 32 z)
__global__ __launch_bounds__(256) void k_dec2f(
    const bf16* __restrict__ d1c, const bf16* __restrict__ w,
    const bf16* __restrict__ bias, const bf16* __restrict__ w3,
    float* __restrict__ outacc)
{
    __shared__ __align__(16) float in_s[8][3][44];
    __shared__ __align__(16) float wr_s[8][2][2][3][32];
    __shared__ float p_s[256][2];
    const int z = blockIdx.z, rt = blockIdx.x, oq = blockIdx.y;
    const int tid = threadIdx.x;
    const int s = tid & 127, og = tid >> 7;
    const bool act = (s < 126);
    const int row = act ? (s / 42) : 0, col0 = s % 42, col1 = col0 + 42;
    const int r0 = rt * 3;
    const int oy = r0 + row;
    const int py = oy & 1;
    const int base = ((r0 + 1) >> 1) - 1;
    const int rlb = ((oy + 1) >> 1) - 1 - base;
    int cs0[3], cs1[3];
    #pragma unroll
    for (int kx = 0; kx < 3; ++kx) {
        cs0[kx] = (col0 + kx + 1) >> 1;
        cs1[kx] = (col1 + kx + 1) >> 1;
    }
    float acc0[16], acc1[16];
    #pragma unroll
    for (int i = 0; i < 16; ++i) { acc0[i] = 0.f; acc1[i] = 0.f; }
    for (int cc = 0; cc < 16; ++cc) {
        const int ci0 = cc * 8;
        __syncthreads();
        for (int i = tid; i < 1056; i += 256) {
            int ci = i / 132, rem = i % 132, r = rem / 44, gc = rem % 44;
            int gy = base + r, gx = gc - 1;
            float v = 0.f;
            if (gy >= 0 && gy < 42 && gx >= 0 && gx < 42)
                v = b2f(d1c[((z * 128 + ci0 + ci) * 42 + gy) * 42 + gx]);
            in_s[ci][r][gc] = v;
        }
        for (int i = tid; i < 3072; i += 256) {
            int ol = i & 31; int rest = i >> 5;
            int kx = rest % 3; rest /= 3;
            int a = rest & 1; rest >>= 1;
            int pyi = rest & 1; int ci = rest >> 1;
            const bf16* wb = w + ((oq * 32 + ol) * 128 + ci0 + ci) * 9;
            float v;
            if (pyi == 0) v = (a == 0) ? b2f(wb[kx]) : b2f(wb[3 + kx]) + b2f(wb[6 + kx]);
            else          v = (a == 0) ? b2f(wb[kx]) + b2f(wb[3 + kx]) : b2f(wb[6 + kx]);
            wr_s[ci][pyi][a][kx][ol] = v;
        }
        __syncthreads();
        #pragma unroll 2
        for (int ci = 0; ci < 8; ++ci) {
            #pragma unroll
            for (int a = 0; a < 2; ++a) {
                #pragma unroll
                for (int kx = 0; kx < 3; ++kx) {
                    const float v0 = in_s[ci][rlb + a][cs0[kx]];
                    const float v1 = in_s[ci][rlb + a][cs1[kx]];
                    const float4 q0 = *(const float4*)&wr_s[ci][py][a][kx][og * 16];
                    const float4 q1 = *(const float4*)&wr_s[ci][py][a][kx][og * 16 + 4];
                    const float4 q2 = *(const float4*)&wr_s[ci][py][a][kx][og * 16 + 8];
                    const float4 q3 = *(const float4*)&wr_s[ci][py][a][kx][og * 16 + 12];
                    const float wv[16] = {q0.x, q0.y, q0.z, q0.w, q1.x, q1.y, q1.z, q1.w,
                                          q2.x, q2.y, q2.z, q2.w, q3.x, q3.y, q3.z, q3.w};
                    #pragma unroll
                    for (int j = 0; j < 16; ++j) {
                        acc0[j] += wv[j] * v0;
                        acc1[j] += wv[j] * v1;
                    }
                }
            }
        }
    }
    // fused epilogue: relu + scale by w3, reduce 16 oc -> partial scalar
    float part0 = 0.f, part1 = 0.f;
    if (act) {
        #pragma unroll
        for (int j = 0; j < 16; ++j) {
            const int oc = oq * 32 + og * 16 + j;
            const float bv = b2f(bias[oc]);
            const float wv3 = b2f(w3[oc]);
            part0 += wv3 * fmaxf(acc0[j] + bv, 0.f);
            part1 += wv3 * fmaxf(acc1[j] + bv, 0.f);
        }
    }
    __syncthreads();
    p_s[tid][0] = part0;
    p_s[tid][1] = part1;
    __syncthreads();
    if (tid < 128 && act) {
        float s0 = p_s[tid][0] + p_s[tid + 128][0];
        float s1 = p_s[tid][1] + p_s[tid + 128][1];
        atomicAdd(&outacc[z * 7056 + oy * 84 + col0], s0);
        atomicAdd(&outacc[z * 7056 + oy * 84 + col1], s1);
    }
}

// K8: finalize: out[(c0f+z)*7056+p] = outacc + b3
__global__ __launch_bounds__(256) void k_outfin(
    const float* __restrict__ outacc, const bf16* __restrict__ b3,
    void* __restrict__ out, int c0f, const int* __restrict__ flag)
{
    int idx = blockIdx.x * 256 + threadIdx.x;
    if (idx >= 32 * 7056) return;
    float v = outacc[idx] + b2f(b3[0]);
    const int oi = (c0f + idx / 7056) * 7056 + idx % 7056;
    if (*flag) ((float*)out)[oi] = v;
    else       ((bf16*)out)[oi]  = f2b(v);
}

// K9: flush final h,c -> d_out
__global__ __launch_bounds__(256) void k_out_hc(
    const float* __restrict__ h, const float* __restrict__ c,
    void* __restrict__ out, const int* __restrict__ flag)
{
    int idx = blockIdx.x * 256 + threadIdx.x;
    if (idx >= 903168) return;
    if (*flag) {
        ((float*)out)[903168 + idx] = h[idx];
        ((float*)out)[1806336 + idx] = c[idx];
    } else {
        ((bf16*)out)[903168 + idx]  = f2b(h[idx]);
        ((bf16*)out)[1806336 + idx] = f2b(c[idx]);
    }
}

extern "C" void kernel_launch(void* const* d_in, const int* in_sizes, int n_in,
                              void* d_out, int out_size, void* d_ws, size_t ws_size,
                              hipStream_t stream)
{
    char* wsb = (char*)d_ws;
    static const int wsz[15] = {1728, 64, 73728, 128, 294912, 256, 4608, 524288,
                                1024, 294912, 128, 73728, 64, 64, 1};
    static const long woff[15] = {0, 3456, 3584, 151040, 151296, 741120, 741632,
                                  750848, 1799424, 1801472, 2391296, 2391552,
                                  2539008, 2539136, 2539264};
    const long FLAG_OFF = 2539280;
    const long CE = 2539296;
    int* flag = (int*)(wsb + FLAG_OFF);

    k_detect<<<1, 256, 0, stream>>>((const unsigned short*)d_in[0], 262144, flag);
    bf16* cw[15];
    for (int i = 0; i < 15; ++i) {
        cw[i] = (bf16*)(wsb + woff[i]);
        k_canon<<<(wsz[i] + 255) / 256, 256, 0, stream>>>(d_in[i + 1], cw[i], wsz[i], flag);
    }
    const void* x = d_in[0];
    bf16 *enc_w1 = cw[0], *enc_b1 = cw[1], *enc_w2 = cw[2], *enc_b2 = cw[3],
         *enc_w3 = cw[4], *enc_b3 = cw[5], *dw_w = cw[6], *pw_w = cw[7],
         *pw_b = cw[8], *dec_w1 = cw[9], *dec_b1 = cw[10], *dec_w2 = cw[11],
         *dec_b2 = cw[12], *dec_w3 = cw[13], *dec_b3 = cw[14];

    bf16*  feats  = (bf16*)(wsb + CE);                  // 28,901,376
    bf16*  hs0    = (bf16*)(wsb + CE + 28901376);       //  1,806,336
    float* hbuf   = (float*)(wsb + CE + 30707712);      //  3,612,672
    float* cbuf   = (float*)(wsb + CE + 34320384);      //  3,612,672
    float* dwout  = (float*)(wsb + CE + 37933056);      //  7,225,344 (LSTM)
    bf16*  d1c    = (bf16*)(wsb + CE + 37933056);       // 14,450,688 (decode)
    bf16*  p1c    = (bf16*)(wsb + CE + 37933056);       //  7,225,344 (encode)
    bf16*  p2c    = (bf16*)(wsb + CE + 45158400);       //  3,612,672 (encode)
    float* outacc = (float*)(wsb + CE + 52383744);      //    903,168 (decode)

    for (int f0 = 0; f0 < 128; f0 += 32) {
        k_conv1_pool<<<dim3(36, 32), 256, 0, stream>>>(x, enc_w1, enc_b1, p1c, f0, flag);
        k_conv2_pool<<<dim3(7, 4, 32), 256, 0, stream>>>(p1c, enc_w2, enc_b2, p2c);
        k_conv3<<<dim3(4, 8, 32), 256, 0, stream>>>(p2c, enc_w3, enc_b3, feats, f0);
    }
    hipMemsetAsync(hbuf, 0, 2 * 3612672, stream);
    for (int t = 0; t < 16; ++t) {
        bf16* hst = (t == 0) ? hs0 : (feats + (long)(t - 1) * 8 * 112896);
        k_dw<<<7056, 256, 0, stream>>>(feats, hbuf, dw_w, dwout, t);
        k_pw_gate<<<dim3(7, 8, 8), 256, 0, stream>>>(dwout, pw_w, pw_b, hbuf, cbuf, hst);
    }
    k_out_hc<<<3528, 256, 0, stream>>>(hbuf, cbuf, d_out, flag);
    for (int c0f = 0; c0f < 128; c0f += 32) {
        k_dec1<<<dim3(7, 4, 32), 256, 0, stream>>>(feats, hs0, dec_w1, dec_b1, d1c, c0f);
        hipMemsetAsync(outacc, 0, 903168, stream);
        k_dec2f<<<dim3(28, 2, 32), 256, 0, stream>>>(d1c, dec_w2, dec_b2, dec_w3, outacc);
        k_outfin<<<882, 256, 0, stream>>>(outacc, dec_b3, d_out, c0f, flag);
    }
}

// Round 7
// 7412.056 us; speedup vs baseline: 1.6520x; 1.2380x over previous
//
#include <hip/hip_runtime.h>
#include <hip/hip_bf16.h>

typedef __hip_bfloat16 bf16;
#define DEV static __device__ __forceinline__

DEV float b2f(bf16 v) { return __bfloat162float(v); }
DEV bf16  f2b(float v) { return __float2bfloat16(v); }
DEV float sigf(float x) { return 1.0f / (1.0f + __expf(-x)); }
DEV float tanhfast(float x) { return 2.0f / (1.0f + __expf(-2.0f * x)) - 1.0f; }

// ---------------------------------------------------------------------------
// fp32 I/O (proved r4). Round-7: decoder rewritten in PARITY-PLANE form.
// up2+3x3 conv == 4 sub-convs (one per output parity (py,px)), each with
// 2x2 combined weights (row-set x col-set sums). Block = one parity ->
// (py,px) wave-uniform -> weight b128 reads are pure broadcasts; thread =
// 4 px x 16 oc -> VALU-bound (128 FMA-cyc vs ~71 LDS-cyc per (ci,a,b)).
// ws layout unchanged from round 6 (peak ~55.8 MB <= confirmed 63.9 MB).
// ---------------------------------------------------------------------------

__global__ void k_detect(const unsigned short* __restrict__ xb, int nscan, int* flag)
{
    __shared__ int cnt_s[256];
    int tid = threadIdx.x;
    int c = 0;
    for (int i = tid; i < nscan; i += 256) {
        unsigned int e = (xb[i] >> 7) & 0xFF;
        c += (e >= 0xC0);
    }
    cnt_s[tid] = c;
    __syncthreads();
    for (int off = 128; off > 0; off >>= 1) {
        if (tid < off) cnt_s[tid] += cnt_s[tid + off];
        __syncthreads();
    }
    if (tid == 0) *flag = (cnt_s[0] > 1000) ? 1 : 0;
}

__global__ __launch_bounds__(256) void k_canon(
    const void* __restrict__ src, bf16* __restrict__ dst, int n,
    const int* __restrict__ flag)
{
    int i = blockIdx.x * 256 + threadIdx.x;
    if (i >= n) return;
    if (*flag) dst[i] = f2b(((const float*)src)[i]);
    else       dst[i] = ((const bf16*)src)[i];
}

// K1: conv 3->64 + relu + pool : x[f0+z] -> p1c[z,64,42,42]
__global__ __launch_bounds__(256) void k_conv1_pool(
    const void* __restrict__ xv, const bf16* __restrict__ w,
    const bf16* __restrict__ bias, bf16* __restrict__ p1c, int fbase,
    const int* __restrict__ flag)
{
    __shared__ __align__(16) float in_s[3][16][16];
    __shared__ __align__(16) float w_s[1728];
    __shared__ __align__(16) float b_s[64];
    const int z = blockIdx.y;
    const int n = fbase + z;
    const int ty = blockIdx.x / 6, tx = blockIdx.x % 6;
    const int tid = threadIdx.x;
    const int isf32 = *flag;
    for (int i = tid; i < 1728; i += 256) w_s[i] = b2f(w[i]);
    if (tid < 64) b_s[tid] = b2f(bias[tid]);
    const int iy0 = ty * 14 - 1, ix0 = tx * 14 - 1;
    for (int i = tid; i < 768; i += 256) {
        int ci = i >> 8, r = (i >> 4) & 15, col = i & 15;
        int gy = iy0 + r, gx = ix0 + col;
        float v = 0.f;
        if (gy >= 0 && gy < 84 && gx >= 0 && gx < 84) {
            int idx = (n * 3 + ci) * 7056 + gy * 84 + gx;
            v = isf32 ? ((const float*)xv)[idx] : b2f(((const bf16*)xv)[idx]);
        }
        in_s[ci][r][col] = v;
    }
    __syncthreads();
    for (int idx = tid; idx < 3136; idx += 256) {
        int oc = idx / 49, p = idx % 49;
        int py = p / 7, px = p % 7;
        float m = 0.f;
        #pragma unroll
        for (int pp = 0; pp < 4; ++pp) {
            int a = pp >> 1, bb = pp & 1;
            float sacc = b_s[oc];
            for (int ci = 0; ci < 3; ++ci)
                #pragma unroll
                for (int ky = 0; ky < 3; ++ky)
                    #pragma unroll
                    for (int kx = 0; kx < 3; ++kx)
                        sacc += w_s[(oc * 3 + ci) * 9 + ky * 3 + kx] *
                                in_s[ci][2 * py + a + ky][2 * px + bb + kx];
            m = fmaxf(m, sacc);
        }
        p1c[((z * 64 + oc) * 42 + ty * 7 + py) * 42 + tx * 7 + px] = f2b(m);
    }
}

// K2: conv 64->128 + relu + pool : p1c[z] -> p2c[z,128,21,21]
__global__ __launch_bounds__(256) void k_conv2_pool(
    const bf16* __restrict__ p1c, const bf16* __restrict__ w,
    const bf16* __restrict__ bias, bf16* __restrict__ p2c)
{
    __shared__ __align__(16) float in_s[16][8][44];
    __shared__ __align__(16) float w_s[16][9][32];
    const int z = blockIdx.z, rt = blockIdx.x, oq = blockIdx.y;
    const int tid = threadIdx.x;
    const int s = tid & 63, og = tid >> 6;
    const int pr = (s < 63) ? (s / 21) : 2, pc = s % 21;
    const bool act = (s < 63);
    const int r0 = rt * 3;
    const int iy0 = r0 * 2 - 1;
    float acc[32];
    #pragma unroll
    for (int i = 0; i < 32; ++i) acc[i] = 0.f;
    for (int cc = 0; cc < 4; ++cc) {
        const int c0 = cc * 16;
        __syncthreads();
        for (int i = tid; i < 5632; i += 256) {
            int ci = i / 352, rem = i % 352, r = rem / 44, col = rem % 44;
            int gy = iy0 + r, gx = col - 1;
            float v = 0.f;
            if (gy >= 0 && gy < 42 && gx >= 0 && gx < 42)
                v = b2f(p1c[((z * 64 + c0 + ci) * 42 + gy) * 42 + gx]);
            in_s[ci][r][col] = v;
        }
        for (int i = tid; i < 4608; i += 256) {
            int ci = i / 288, rem = i % 288, tap = rem / 32, ol = rem & 31;
            w_s[ci][tap][ol] = b2f(w[((oq * 32 + ol) * 64 + c0 + ci) * 9 + tap]);
        }
        __syncthreads();
        if (act) {
            #pragma unroll 1
            for (int ci = 0; ci < 16; ++ci) {
                float iv[4][4];
                #pragma unroll
                for (int r = 0; r < 4; ++r)
                    #pragma unroll
                    for (int col = 0; col < 4; ++col)
                        iv[r][col] = in_s[ci][2 * pr + r][2 * pc + col];
                #pragma unroll
                for (int tap = 0; tap < 9; ++tap) {
                    const int ky = tap / 3, kx = tap % 3;
                    const float4 w0 = *(const float4*)&w_s[ci][tap][og * 8];
                    const float4 w1 = *(const float4*)&w_s[ci][tap][og * 8 + 4];
                    const float wv[8] = {w0.x, w0.y, w0.z, w0.w, w1.x, w1.y, w1.z, w1.w};
                    #pragma unroll
                    for (int j = 0; j < 8; ++j)
                        #pragma unroll
                        for (int pp = 0; pp < 4; ++pp)
                            acc[j * 4 + pp] += wv[j] * iv[(pp >> 1) + ky][(pp & 1) + kx];
                }
            }
        }
    }
    if (act) {
        #pragma unroll
        for (int j = 0; j < 8; ++j) {
            const int oc = oq * 32 + og * 8 + j;
            const float bv = b2f(bias[oc]);
            float m = 0.f;
            #pragma unroll
            for (int pp = 0; pp < 4; ++pp) m = fmaxf(m, acc[j * 4 + pp] + bv);
            p2c[((z * 128 + oc) * 21 + r0 + pr) * 21 + pc] = f2b(m);
        }
    }
}

// K3: conv 128->256 + relu : p2c[z] -> feats slot (t*8+b), n = fbase+z
__global__ __launch_bounds__(256) void k_conv3(
    const bf16* __restrict__ p2c, const bf16* __restrict__ w,
    const bf16* __restrict__ bias, bf16* __restrict__ feats, int fbase)
{
    __shared__ __align__(16) float in_s[16][8][23];
    __shared__ __align__(16) float w_s[16][9][32];
    const int z = blockIdx.z, rt = blockIdx.x, oq = blockIdx.y;
    const int n = fbase + z;
    const int slot = (n & 15) * 8 + (n >> 4);
    const int tid = threadIdx.x;
    const int s = tid & 63, og = tid >> 6;
    const bool act = (s < 63);
    const int lr = (s < 63) ? (s / 21) : 2, col = s % 21;
    const int r0 = rt * 6;
    float acc[16];
    #pragma unroll
    for (int i = 0; i < 16; ++i) acc[i] = 0.f;
    for (int cc = 0; cc < 8; ++cc) {
        const int c0 = cc * 16;
        __syncthreads();
        for (int i = tid; i < 2944; i += 256) {
            int ci = i / 184, rem = i % 184, r = rem / 23, gcol = rem % 23;
            int gy = r0 - 1 + r, gx = gcol - 1;
            float v = 0.f;
            if (gy >= 0 && gy < 21 && gx >= 0 && gx < 21)
                v = b2f(p2c[((z * 128 + c0 + ci) * 21 + gy) * 21 + gx]);
            in_s[ci][r][gcol] = v;
        }
        for (int i = tid; i < 4608; i += 256) {
            int ci = i / 288, rem = i % 288, tap = rem / 32, ol = rem & 31;
            w_s[ci][tap][ol] = b2f(w[((oq * 32 + ol) * 128 + c0 + ci) * 9 + tap]);
        }
        __syncthreads();
        if (act) {
            #pragma unroll 1
            for (int ci = 0; ci < 16; ++ci) {
                float iv0[3][3], iv1[3][3];
                #pragma unroll
                for (int r = 0; r < 3; ++r)
                    #pragma unroll
                    for (int q = 0; q < 3; ++q) {
                        iv0[r][q] = in_s[ci][lr + r][col + q];
                        iv1[r][q] = in_s[ci][lr + 3 + r][col + q];
                    }
                #pragma unroll
                for (int tap = 0; tap < 9; ++tap) {
                    const int ky = tap / 3, kx = tap % 3;
                    const float4 w0 = *(const float4*)&w_s[ci][tap][og * 8];
                    const float4 w1 = *(const float4*)&w_s[ci][tap][og * 8 + 4];
                    const float wv[8] = {w0.x, w0.y, w0.z, w0.w, w1.x, w1.y, w1.z, w1.w};
                    #pragma unroll
                    for (int j = 0; j < 8; ++j) {
                        acc[j]     += wv[j] * iv0[ky][kx];
                        acc[j + 8] += wv[j] * iv1[ky][kx];
                    }
                }
            }
        }
    }
    if (act) {
        const int oy0 = r0 + lr, oy1 = oy0 + 3;
        #pragma unroll
        for (int j = 0; j < 8; ++j) {
            const int oc = oq * 32 + og * 8 + j;
            const float bv = b2f(bias[oc]);
            if (oy0 < 21)
                feats[((slot * 256 + oc) * 21 + oy0) * 21 + col] = f2b(fmaxf(acc[j] + bv, 0.f));
            if (oy1 < 21)
                feats[((slot * 256 + oc) * 21 + oy1) * 21 + col] = f2b(fmaxf(acc[j + 8] + bv, 0.f));
        }
    }
}

// K4: depthwise 3x3 on [feats slot t | h] -> dwout f32 [8,512,441]
__global__ __launch_bounds__(256) void k_dw(
    const bf16* __restrict__ feats, const float* __restrict__ h,
    const bf16* __restrict__ dww, float* __restrict__ dwout, int t)
{
    int idx = blockIdx.x * 256 + threadIdx.x;
    if (idx >= 8 * 512 * 441) return;
    const int p = idx % 441;
    const int ch = (idx / 441) & 511;
    const int b = idx / (441 * 512);
    const int y = p / 21, x = p % 21;
    float wv[9];
    #pragma unroll
    for (int k = 0; k < 9; ++k) wv[k] = b2f(dww[ch * 9 + k]);
    float s = 0.f;
    #pragma unroll
    for (int ky = 0; ky < 3; ++ky) {
        int iy = y + ky - 1;
        if (iy < 0 || iy >= 21) continue;
        #pragma unroll
        for (int kx = 0; kx < 3; ++kx) {
            int ix = x + kx - 1;
            if (ix < 0 || ix >= 21) continue;
            float v;
            if (ch < 256) v = b2f(feats[((t * 8 + b) * 256 + ch) * 441 + iy * 21 + ix]);
            else          v = h[(b * 256 + (ch - 256)) * 441 + iy * 21 + ix];
            s += wv[ky * 3 + kx] * v;
        }
    }
    dwout[idx] = s;
}

// K5: pointwise 512->1024 + gates (2 px/thread); grid (7,8,8)
__global__ __launch_bounds__(256) void k_pw_gate(
    const float* __restrict__ dwout, const bf16* __restrict__ pww,
    const bf16* __restrict__ pwb, float* __restrict__ h, float* __restrict__ c,
    bf16* __restrict__ hst)
{
    __shared__ __align__(16) float a_s[32][64];
    __shared__ __align__(16) float w_s[32][128];
    const int b = blockIdx.z, cq = blockIdx.y, pt = blockIdx.x;
    const int tid = threadIdx.x;
    const int s = tid & 31, cg = tid >> 5;
    const int p0 = pt * 64 + s, p1 = p0 + 32;
    float acc0[16], acc1[16];
    #pragma unroll
    for (int i = 0; i < 16; ++i) { acc0[i] = 0.f; acc1[i] = 0.f; }
    for (int kk = 0; kk < 512; kk += 32) {
        __syncthreads();
        for (int i = tid; i < 2048; i += 256) {
            int k = i >> 6, pix = i & 63;
            int gp = pt * 64 + pix;
            a_s[k][pix] = (gp < 441) ? dwout[(b * 512 + kk + k) * 441 + gp] : 0.f;
        }
        for (int i = tid; i < 4096; i += 256) {
            int k = i >> 7, j = i & 127;
            int cgl = j >> 4, ccl = (j >> 2) & 3, gate = j & 3;
            int oc = gate * 256 + cq * 32 + cgl * 4 + ccl;
            w_s[k][j] = b2f(pww[oc * 512 + kk + k]);
        }
        __syncthreads();
        #pragma unroll 4
        for (int k = 0; k < 32; ++k) {
            const float a0 = a_s[k][s], a1 = a_s[k][s + 32];
            const float4 q0 = *(const float4*)&w_s[k][cg * 16];
            const float4 q1 = *(const float4*)&w_s[k][cg * 16 + 4];
            const float4 q2 = *(const float4*)&w_s[k][cg * 16 + 8];
            const float4 q3 = *(const float4*)&w_s[k][cg * 16 + 12];
            const float wv[16] = {q0.x, q0.y, q0.z, q0.w, q1.x, q1.y, q1.z, q1.w,
                                  q2.x, q2.y, q2.z, q2.w, q3.x, q3.y, q3.z, q3.w};
            #pragma unroll
            for (int j = 0; j < 16; ++j) { acc0[j] += wv[j] * a0; acc1[j] += wv[j] * a1; }
        }
    }
    #pragma unroll
    for (int ccl = 0; ccl < 4; ++ccl) {
        const int ch = cq * 32 + cg * 4 + ccl;
        const float bi = b2f(pwb[ch]);
        const float bfg = b2f(pwb[256 + ch]);
        const float bo = b2f(pwb[512 + ch]);
        const float bg = b2f(pwb[768 + ch]);
        if (p0 < 441) {
            float ig = sigf(acc0[ccl * 4 + 0] + bi);
            float fg = sigf(acc0[ccl * 4 + 1] + bfg);
            float og = sigf(acc0[ccl * 4 + 2] + bo);
            float gg = tanhfast(acc0[ccl * 4 + 3] + bg);
            int ci2 = (b * 256 + ch) * 441 + p0;
            float c2 = fg * c[ci2] + ig * gg;
            float h2 = og * tanhfast(c2);
            c[ci2] = c2; h[ci2] = h2;
            hst[ci2] = f2b(h2);
        }
        if (p1 < 441) {
            float ig = sigf(acc1[ccl * 4 + 0] + bi);
            float fg = sigf(acc1[ccl * 4 + 1] + bfg);
            float og = sigf(acc1[ccl * 4 + 2] + bo);
            float gg = tanhfast(acc1[ccl * 4 + 3] + bg);
            int ci2 = (b * 256 + ch) * 441 + p1;
            float c2 = fg * c[ci2] + ig * gg;
            float h2 = og * tanhfast(c2);
            c[ci2] = c2; h[ci2] = h2;
            hst[ci2] = f2b(h2);
        }
    }
}

// K6: up2+conv 256->128+relu, PARITY form. grid (4 par, 4 oq, 32 z).
// Thread: 4 input-grid pixels x 16 oc. Weights 2x2-combined per parity.
__global__ __launch_bounds__(256) void k_dec1(
    const bf16* __restrict__ feats, const bf16* __restrict__ hs0,
    const bf16* __restrict__ w, const bf16* __restrict__ bias,
    bf16* __restrict__ d1c, int c0f)
{
    __shared__ __align__(16) float in_s[8 * 529];      // [ci][23][23], rows/cols -1..21
    __shared__ __align__(16) float wc_s[8][2][2][32];  // [ci][a][b][oc]
    const int par = blockIdx.x, py = par >> 1, px = par & 1;
    const int oq = blockIdx.y, z = blockIdx.z;
    const int n = c0f + z, bb = n >> 4, tt = n & 15;
    const bf16* hsf = (tt == 0) ? (hs0 + bb * 112896)
                                : (feats + (((tt - 1) * 8 + bb) * 112896));
    const int tid = threadIdx.x;
    const int og = tid >> 7, s = tid & 127;
    int basep[4], iyv[4], ixv[4];
    bool val[4];
    #pragma unroll
    for (int q = 0; q < 4; ++q) {
        int p = s + q * 128;
        val[q] = (p < 441);
        int pc = val[q] ? p : 440;
        iyv[q] = pc / 21; ixv[q] = pc % 21;
        basep[q] = iyv[q] * 23 + ixv[q];
    }
    float acc[4][16];
    #pragma unroll
    for (int q = 0; q < 4; ++q)
        #pragma unroll
        for (int j = 0; j < 16; ++j) acc[q][j] = 0.f;
    for (int cc = 0; cc < 32; ++cc) {
        const int ci0 = cc * 8;
        __syncthreads();
        for (int i = tid; i < 4232; i += 256) {
            int ci = i / 529, rem = i % 529, r = rem / 23, col = rem % 23;
            int gy = r - 1, gx = col - 1;
            float v = 0.f;
            if (gy >= 0 && gy < 21 && gx >= 0 && gx < 21)
                v = b2f(hsf[(ci0 + ci) * 441 + gy * 21 + gx]);
            in_s[i] = v;
        }
        for (int i = tid; i < 1024; i += 256) {
            int ol = i & 31, rest = i >> 5;
            int b_ = rest & 1, a_ = (rest >> 1) & 1, ci = rest >> 2;
            const bf16* wb = w + ((oq * 32 + ol) * 256 + ci0 + ci) * 9;
            float v = 0.f;
            #pragma unroll
            for (int ky = 0; ky < 3; ++ky) {
                bool rok = (py == 0) ? (a_ == 0 ? (ky == 0) : (ky >= 1))
                                     : (a_ == 0 ? (ky <= 1) : (ky == 2));
                if (!rok) continue;
                #pragma unroll
                for (int kx = 0; kx < 3; ++kx) {
                    bool cok = (px == 0) ? (b_ == 0 ? (kx == 0) : (kx >= 1))
                                         : (b_ == 0 ? (kx <= 1) : (kx == 2));
                    if (cok) v += b2f(wb[ky * 3 + kx]);
                }
            }
            wc_s[ci][a_][b_][ol] = v;
        }
        __syncthreads();
        #pragma unroll 2
        for (int ci = 0; ci < 8; ++ci) {
            #pragma unroll
            for (int a = 0; a < 2; ++a) {
                #pragma unroll
                for (int b = 0; b < 2; ++b) {
                    const float4 q0 = *(const float4*)&wc_s[ci][a][b][og * 16];
                    const float4 q1 = *(const float4*)&wc_s[ci][a][b][og * 16 + 4];
                    const float4 q2 = *(const float4*)&wc_s[ci][a][b][og * 16 + 8];
                    const float4 q3 = *(const float4*)&wc_s[ci][a][b][og * 16 + 12];
                    const float wv[16] = {q0.x, q0.y, q0.z, q0.w, q1.x, q1.y, q1.z, q1.w,
                                          q2.x, q2.y, q2.z, q2.w, q3.x, q3.y, q3.z, q3.w};
                    const int ofs = ci * 529 + (py + a) * 23 + (px + b);
                    #pragma unroll
                    for (int q = 0; q < 4; ++q) {
                        const float v = in_s[ofs + basep[q]];
                        #pragma unroll
                        for (int j = 0; j < 16; ++j) acc[q][j] += wv[j] * v;
                    }
                }
            }
        }
    }
    #pragma unroll
    for (int q = 0; q < 4; ++q) {
        if (!val[q]) continue;
        const int oy = 2 * iyv[q] + py, ox = 2 * ixv[q] + px;
        #pragma unroll
        for (int j = 0; j < 16; ++j) {
            const int oc = oq * 32 + og * 16 + j;
            d1c[((z * 128 + oc) * 42 + oy) * 42 + ox] =
                f2b(fmaxf(acc[q][j] + b2f(bias[oc]), 0.f));
        }
    }
}

// K7: up2+conv 128->64+relu FUSED with 1x1 (w3 reduce + atomicAdd), PARITY form.
// grid x = par*4+band (16), y = oq (2), z (32). Bands of 11 input rows.
__global__ __launch_bounds__(256) void k_dec2f(
    const bf16* __restrict__ d1c, const bf16* __restrict__ w,
    const bf16* __restrict__ bias, const bf16* __restrict__ w3,
    float* __restrict__ outacc)
{
    __shared__ __align__(16) float in_s[8 * 572];      // [ci][13][44]
    __shared__ __align__(16) float wc_s[8][2][2][32];
    __shared__ float p_s[2][128][4];
    const int par = blockIdx.x >> 2, band = blockIdx.x & 3;
    const int py = par >> 1, px = par & 1;
    const int oq = blockIdx.y, z = blockIdx.z;
    const int iy0 = band * 11;
    const int nrows = (band == 3) ? 9 : 11;
    const int npx = nrows * 42;
    const int tid = threadIdx.x;
    const int og = tid >> 7, s = tid & 127;
    int basep[4], iylv[4], ixv[4];
    bool val[4];
    #pragma unroll
    for (int q = 0; q < 4; ++q) {
        int p = s + q * 128;
        val[q] = (p < npx);
        int pc = val[q] ? p : (npx - 1);
        iylv[q] = pc / 42; ixv[q] = pc % 42;
        basep[q] = iylv[q] * 44 + ixv[q];
    }
    float acc[4][16];
    #pragma unroll
    for (int q = 0; q < 4; ++q)
        #pragma unroll
        for (int j = 0; j < 16; ++j) acc[q][j] = 0.f;
    for (int cc = 0; cc < 16; ++cc) {
        const int ci0 = cc * 8;
        __syncthreads();
        for (int i = tid; i < 4576; i += 256) {
            int ci = i / 572, rem = i % 572, r = rem / 44, col = rem % 44;
            int gy = iy0 - 1 + r, gx = col - 1;
            float v = 0.f;
            if (gy >= 0 && gy < 42 && gx >= 0 && gx < 42)
                v = b2f(d1c[((z * 128 + ci0 + ci) * 42 + gy) * 42 + gx]);
            in_s[i] = v;
        }
        for (int i = tid; i < 1024; i += 256) {
            int ol = i & 31, rest = i >> 5;
            int b_ = rest & 1, a_ = (rest >> 1) & 1, ci = rest >> 2;
            const bf16* wb = w + ((oq * 32 + ol) * 128 + ci0 + ci) * 9;
            float v = 0.f;
            #pragma unroll
            for (int ky = 0; ky < 3; ++ky) {
                bool rok = (py == 0) ? (a_ == 0 ? (ky == 0) : (ky >= 1))
                                     : (a_ == 0 ? (ky <= 1) : (ky == 2));
                if (!rok) continue;
                #pragma unroll
                for (int kx = 0; kx < 3; ++kx) {
                    bool cok = (px == 0) ? (b_ == 0 ? (kx == 0) : (kx >= 1))
                                         : (b_ == 0 ? (kx <= 1) : (kx == 2));
                    if (cok) v += b2f(wb[ky * 3 + kx]);
                }
            }
            wc_s[ci][a_][b_][ol] = v;
        }
        __syncthreads();
        #pragma unroll 2
        for (int ci = 0; ci < 8; ++ci) {
            #pragma unroll
            for (int a = 0; a < 2; ++a) {
                #pragma unroll
                for (int b = 0; b < 2; ++b) {
                    const float4 q0 = *(const float4*)&wc_s[ci][a][b][og * 16];
                    const float4 q1 = *(const float4*)&wc_s[ci][a][b][og * 16 + 4];
                    const float4 q2 = *(const float4*)&wc_s[ci][a][b][og * 16 + 8];
                    const float4 q3 = *(const float4*)&wc_s[ci][a][b][og * 16 + 12];
                    const float wv[16] = {q0.x, q0.y, q0.z, q0.w, q1.x, q1.y, q1.z, q1.w,
                                          q2.x, q2.y, q2.z, q2.w, q3.x, q3.y, q3.z, q3.w};
                    const int ofs = ci * 572 + (py + a) * 44 + (px + b);
                    #pragma unroll
                    for (int q = 0; q < 4; ++q) {
                        const float v = in_s[ofs + basep[q]];
                        #pragma unroll
                        for (int j = 0; j < 16; ++j) acc[q][j] += wv[j] * v;
                    }
                }
            }
        }
    }
    // fused epilogue: relu + w3 reduce over this thread's 16 oc
    #pragma unroll
    for (int q = 0; q < 4; ++q) {
        float part = 0.f;
        #pragma unroll
        for (int j = 0; j < 16; ++j) {
            const int oc = oq * 32 + og * 16 + j;
            part += b2f(w3[oc]) * fmaxf(acc[q][j] + b2f(bias[oc]), 0.f);
        }
        p_s[og][s][q] = part;
    }
    __syncthreads();
    if (tid < 128) {
        #pragma unroll
        for (int q = 0; q < 4; ++q) {
            if (!val[q]) continue;
            const float sum = p_s[0][s][q] + p_s[1][s][q];
            const int oy = 2 * (iy0 + iylv[q]) + py, ox = 2 * ixv[q] + px;
            atomicAdd(&outacc[z * 7056 + oy * 84 + ox], sum);
        }
    }
}

// K8: finalize: out[(c0f+z)*7056+p] = outacc + b3
__global__ __launch_bounds__(256) void k_outfin(
    const float* __restrict__ outacc, const bf16* __restrict__ b3,
    void* __restrict__ out, int c0f, const int* __restrict__ flag)
{
    int idx = blockIdx.x * 256 + threadIdx.x;
    if (idx >= 32 * 7056) return;
    float v = outacc[idx] + b2f(b3[0]);
    const int oi = (c0f + idx / 7056) * 7056 + idx % 7056;
    if (*flag) ((float*)out)[oi] = v;
    else       ((bf16*)out)[oi]  = f2b(v);
}

// K9: flush final h,c -> d_out
__global__ __launch_bounds__(256) void k_out_hc(
    const float* __restrict__ h, const float* __restrict__ c,
    void* __restrict__ out, const int* __restrict__ flag)
{
    int idx = blockIdx.x * 256 + threadIdx.x;
    if (idx >= 903168) return;
    if (*flag) {
        ((float*)out)[903168 + idx] = h[idx];
        ((float*)out)[1806336 + idx] = c[idx];
    } else {
        ((bf16*)out)[903168 + idx]  = f2b(h[idx]);
        ((bf16*)out)[1806336 + idx] = f2b(c[idx]);
    }
}

extern "C" void kernel_launch(void* const* d_in, const int* in_sizes, int n_in,
                              void* d_out, int out_size, void* d_ws, size_t ws_size,
                              hipStream_t stream)
{
    char* wsb = (char*)d_ws;
    static const int wsz[15] = {1728, 64, 73728, 128, 294912, 256, 4608, 524288,
                                1024, 294912, 128, 73728, 64, 64, 1};
    static const long woff[15] = {0, 3456, 3584, 151040, 151296, 741120, 741632,
                                  750848, 1799424, 1801472, 2391296, 2391552,
                                  2539008, 2539136, 2539264};
    const long FLAG_OFF = 2539280;
    const long CE = 2539296;
    int* flag = (int*)(wsb + FLAG_OFF);

    k_detect<<<1, 256, 0, stream>>>((const unsigned short*)d_in[0], 262144, flag);
    bf16* cw[15];
    for (int i = 0; i < 15; ++i) {
        cw[i] = (bf16*)(wsb + woff[i]);
        k_canon<<<(wsz[i] + 255) / 256, 256, 0, stream>>>(d_in[i + 1], cw[i], wsz[i], flag);
    }
    const void* x = d_in[0];
    bf16 *enc_w1 = cw[0], *enc_b1 = cw[1], *enc_w2 = cw[2], *enc_b2 = cw[3],
         *enc_w3 = cw[4], *enc_b3 = cw[5], *dw_w = cw[6], *pw_w = cw[7],
         *pw_b = cw[8], *dec_w1 = cw[9], *dec_b1 = cw[10], *dec_w2 = cw[11],
         *dec_b2 = cw[12], *dec_w3 = cw[13], *dec_b3 = cw[14];

    bf16*  feats  = (bf16*)(wsb + CE);                  // 28,901,376
    bf16*  hs0    = (bf16*)(wsb + CE + 28901376);       //  1,806,336
    float* hbuf   = (float*)(wsb + CE + 30707712);      //  3,612,672
    float* cbuf   = (float*)(wsb + CE + 34320384);      //  3,612,672
    float* dwout  = (float*)(wsb + CE + 37933056);      //  7,225,344 (LSTM)
    bf16*  d1c    = (bf16*)(wsb + CE + 37933056);       // 14,450,688 (decode)
    bf16*  p1c    = (bf16*)(wsb + CE + 37933056);       //  7,225,344 (encode)
    bf16*  p2c    = (bf16*)(wsb + CE + 45158400);       //  3,612,672 (encode)
    float* outacc = (float*)(wsb + CE + 52383744);      //    903,168 (decode)

    for (int f0 = 0; f0 < 128; f0 += 32) {
        k_conv1_pool<<<dim3(36, 32), 256, 0, stream>>>(x, enc_w1, enc_b1, p1c, f0, flag);
        k_conv2_pool<<<dim3(7, 4, 32), 256, 0, stream>>>(p1c, enc_w2, enc_b2, p2c);
        k_conv3<<<dim3(4, 8, 32), 256, 0, stream>>>(p2c, enc_w3, enc_b3, feats, f0);
    }
    hipMemsetAsync(hbuf, 0, 2 * 3612672, stream);
    for (int t = 0; t < 16; ++t) {
        bf16* hst = (t == 0) ? hs0 : (feats + (long)(t - 1) * 8 * 112896);
        k_dw<<<7056, 256, 0, stream>>>(feats, hbuf, dw_w, dwout, t);
        k_pw_gate<<<dim3(7, 8, 8), 256, 0, stream>>>(dwout, pw_w, pw_b, hbuf, cbuf, hst);
    }
    k_out_hc<<<3528, 256, 0, stream>>>(hbuf, cbuf, d_out, flag);
    for (int c0f = 0; c0f < 128; c0f += 32) {
        k_dec1<<<dim3(4, 4, 32), 256, 0, stream>>>(feats, hs0, dec_w1, dec_b1, d1c, c0f);
        hipMemsetAsync(outacc, 0, 903168, stream);
        k_dec2f<<<dim3(16, 2, 32), 256, 0, stream>>>(d1c, dec_w2, dec_b2, dec_w3, outacc);
        k_outfin<<<882, 256, 0, stream>>>(outacc, dec_b3, d_out, c0f, flag);
    }
}

// Round 8
// 5245.115 us; speedup vs baseline: 2.3346x; 1.4131x over previous
//
#include <hip/hip_runtime.h>
#include <hip/hip_bf16.h>

typedef __hip_bfloat16 bf16;
typedef __attribute__((ext_vector_type(8))) short bf16x8;   // 8 bf16 (4 VGPRs)
typedef __attribute__((ext_vector_type(4))) float f32x4;    // 4 fp32 acc
#define DEV static __device__ __forceinline__

DEV float b2f(bf16 v) { return __bfloat162float(v); }
DEV bf16  f2b(float v) { return __float2bfloat16(v); }
DEV float sigf(float x) { return 1.0f / (1.0f + __expf(-x)); }
DEV float tanhfast(float x) { return 2.0f / (1.0f + __expf(-2.0f * x)) - 1.0f; }

// ---------------------------------------------------------------------------
// fp32 I/O (proved r4). Round-8: decoder converted to bf16 MFMA.
// Parity form: up2+3x3 == 4 parity GEMMs with 2x2-combined weights.
//   dec1: D[128][441] = wc1[par][128][1024] . X   (K = 256ci x 4ab)
//   dec2: D[64][1764] = wc2[par][64][512]  . X, fused w3-reduce -> out
// MFMA 16x16x32 bf16; A[m=lane&15][k=quad*8+j], B[n=lane&15][k=quad*8+j],
// C/D col=lane&15, row=quad*4+reg (guide-verified mappings).
//
// ws: [0,2539296) canon weights+flag; wc1 @2,539,296 (1 MB);
//     wc2 @3,587,872 (256 KB); CE=3,850,016.
//     feats @CE (28.9M) | hs0 +28,901,376 | h +30,707,712 | c +34,320,384
//     dwout/d1c/p1c +37,933,056 | p2c +45,158,400. Peak 56.2 MB <= 63.9 MB.
// ---------------------------------------------------------------------------

__global__ void k_detect(const unsigned short* __restrict__ xb, int nscan, int* flag)
{
    __shared__ int cnt_s[256];
    int tid = threadIdx.x;
    int c = 0;
    for (int i = tid; i < nscan; i += 256) {
        unsigned int e = (xb[i] >> 7) & 0xFF;
        c += (e >= 0xC0);
    }
    cnt_s[tid] = c;
    __syncthreads();
    for (int off = 128; off > 0; off >>= 1) {
        if (tid < off) cnt_s[tid] += cnt_s[tid + off];
        __syncthreads();
    }
    if (tid == 0) *flag = (cnt_s[0] > 1000) ? 1 : 0;
}

__global__ __launch_bounds__(256) void k_canon(
    const void* __restrict__ src, bf16* __restrict__ dst, int n,
    const int* __restrict__ flag)
{
    int i = blockIdx.x * 256 + threadIdx.x;
    if (i >= n) return;
    if (*flag) dst[i] = f2b(((const float*)src)[i]);
    else       dst[i] = ((const bf16*)src)[i];
}

// combine dec_w1 -> wc1[par][oc=128][k=ci*4+a*2+b], K=1024
__global__ __launch_bounds__(256) void k_combine1(
    const bf16* __restrict__ w, bf16* __restrict__ wc1)
{
    int idx = blockIdx.x * 256 + threadIdx.x;
    if (idx >= 524288) return;
    int b = idx & 1, a = (idx >> 1) & 1, ci = (idx >> 2) & 255;
    int oc = (idx >> 10) & 127, par = idx >> 17;
    int py = par >> 1, px = par & 1;
    const bf16* wb = w + (oc * 256 + ci) * 9;
    float v = 0.f;
    #pragma unroll
    for (int ky = 0; ky < 3; ++ky) {
        bool rok = (py == 0) ? (a == 0 ? (ky == 0) : (ky >= 1))
                             : (a == 0 ? (ky <= 1) : (ky == 2));
        if (!rok) continue;
        #pragma unroll
        for (int kx = 0; kx < 3; ++kx) {
            bool cok = (px == 0) ? (b == 0 ? (kx == 0) : (kx >= 1))
                                 : (b == 0 ? (kx <= 1) : (kx == 2));
            if (cok) v += b2f(wb[ky * 3 + kx]);
        }
    }
    wc1[idx] = f2b(v);
}

// combine dec_w2 -> wc2[par][oc=64][k=ci*4+a*2+b], K=512
__global__ __launch_bounds__(256) void k_combine2(
    const bf16* __restrict__ w, bf16* __restrict__ wc2)
{
    int idx = blockIdx.x * 256 + threadIdx.x;
    if (idx >= 131072) return;
    int b = idx & 1, a = (idx >> 1) & 1, ci = (idx >> 2) & 127;
    int oc = (idx >> 9) & 63, par = idx >> 15;
    int py = par >> 1, px = par & 1;
    const bf16* wb = w + (oc * 128 + ci) * 9;
    float v = 0.f;
    #pragma unroll
    for (int ky = 0; ky < 3; ++ky) {
        bool rok = (py == 0) ? (a == 0 ? (ky == 0) : (ky >= 1))
                             : (a == 0 ? (ky <= 1) : (ky == 2));
        if (!rok) continue;
        #pragma unroll
        for (int kx = 0; kx < 3; ++kx) {
            bool cok = (px == 0) ? (b == 0 ? (kx == 0) : (kx >= 1))
                                 : (b == 0 ? (kx <= 1) : (kx == 2));
            if (cok) v += b2f(wb[ky * 3 + kx]);
        }
    }
    wc2[idx] = f2b(v);
}

// K1: conv 3->64 + relu + pool : x[f0+z] -> p1c[z,64,42,42]
__global__ __launch_bounds__(256) void k_conv1_pool(
    const void* __restrict__ xv, const bf16* __restrict__ w,
    const bf16* __restrict__ bias, bf16* __restrict__ p1c, int fbase,
    const int* __restrict__ flag)
{
    __shared__ __align__(16) float in_s[3][16][16];
    __shared__ __align__(16) float w_s[1728];
    __shared__ __align__(16) float b_s[64];
    const int z = blockIdx.y;
    const int n = fbase + z;
    const int ty = blockIdx.x / 6, tx = blockIdx.x % 6;
    const int tid = threadIdx.x;
    const int isf32 = *flag;
    for (int i = tid; i < 1728; i += 256) w_s[i] = b2f(w[i]);
    if (tid < 64) b_s[tid] = b2f(bias[tid]);
    const int iy0 = ty * 14 - 1, ix0 = tx * 14 - 1;
    for (int i = tid; i < 768; i += 256) {
        int ci = i >> 8, r = (i >> 4) & 15, col = i & 15;
        int gy = iy0 + r, gx = ix0 + col;
        float v = 0.f;
        if (gy >= 0 && gy < 84 && gx >= 0 && gx < 84) {
            int idx = (n * 3 + ci) * 7056 + gy * 84 + gx;
            v = isf32 ? ((const float*)xv)[idx] : b2f(((const bf16*)xv)[idx]);
        }
        in_s[ci][r][col] = v;
    }
    __syncthreads();
    for (int idx = tid; idx < 3136; idx += 256) {
        int oc = idx / 49, p = idx % 49;
        int py = p / 7, px = p % 7;
        float m = 0.f;
        #pragma unroll
        for (int pp = 0; pp < 4; ++pp) {
            int a = pp >> 1, bb = pp & 1;
            float sacc = b_s[oc];
            for (int ci = 0; ci < 3; ++ci)
                #pragma unroll
                for (int ky = 0; ky < 3; ++ky)
                    #pragma unroll
                    for (int kx = 0; kx < 3; ++kx)
                        sacc += w_s[(oc * 3 + ci) * 9 + ky * 3 + kx] *
                                in_s[ci][2 * py + a + ky][2 * px + bb + kx];
            m = fmaxf(m, sacc);
        }
        p1c[((z * 64 + oc) * 42 + ty * 7 + py) * 42 + tx * 7 + px] = f2b(m);
    }
}

// K2: conv 64->128 + relu + pool : p1c[z] -> p2c[z,128,21,21]
__global__ __launch_bounds__(256) void k_conv2_pool(
    const bf16* __restrict__ p1c, const bf16* __restrict__ w,
    const bf16* __restrict__ bias, bf16* __restrict__ p2c)
{
    __shared__ __align__(16) float in_s[16][8][44];
    __shared__ __align__(16) float w_s[16][9][32];
    const int z = blockIdx.z, rt = blockIdx.x, oq = blockIdx.y;
    const int tid = threadIdx.x;
    const int s = tid & 63, og = tid >> 6;
    const int pr = (s < 63) ? (s / 21) : 2, pc = s % 21;
    const bool act = (s < 63);
    const int r0 = rt * 3;
    const int iy0 = r0 * 2 - 1;
    float acc[32];
    #pragma unroll
    for (int i = 0; i < 32; ++i) acc[i] = 0.f;
    for (int cc = 0; cc < 4; ++cc) {
        const int c0 = cc * 16;
        __syncthreads();
        for (int i = tid; i < 5632; i += 256) {
            int ci = i / 352, rem = i % 352, r = rem / 44, col = rem % 44;
            int gy = iy0 + r, gx = col - 1;
            float v = 0.f;
            if (gy >= 0 && gy < 42 && gx >= 0 && gx < 42)
                v = b2f(p1c[((z * 64 + c0 + ci) * 42 + gy) * 42 + gx]);
            in_s[ci][r][col] = v;
        }
        for (int i = tid; i < 4608; i += 256) {
            int ci = i / 288, rem = i % 288, tap = rem / 32, ol = rem & 31;
            w_s[ci][tap][ol] = b2f(w[((oq * 32 + ol) * 64 + c0 + ci) * 9 + tap]);
        }
        __syncthreads();
        if (act) {
            #pragma unroll 1
            for (int ci = 0; ci < 16; ++ci) {
                float iv[4][4];
                #pragma unroll
                for (int r = 0; r < 4; ++r)
                    #pragma unroll
                    for (int col = 0; col < 4; ++col)
                        iv[r][col] = in_s[ci][2 * pr + r][2 * pc + col];
                #pragma unroll
                for (int tap = 0; tap < 9; ++tap) {
                    const int ky = tap / 3, kx = tap % 3;
                    const float4 w0 = *(const float4*)&w_s[ci][tap][og * 8];
                    const float4 w1 = *(const float4*)&w_s[ci][tap][og * 8 + 4];
                    const float wv[8] = {w0.x, w0.y, w0.z, w0.w, w1.x, w1.y, w1.z, w1.w};
                    #pragma unroll
                    for (int j = 0; j < 8; ++j)
                        #pragma unroll
                        for (int pp = 0; pp < 4; ++pp)
                            acc[j * 4 + pp] += wv[j] * iv[(pp >> 1) + ky][(pp & 1) + kx];
                }
            }
        }
    }
    if (act) {
        #pragma unroll
        for (int j = 0; j < 8; ++j) {
            const int oc = oq * 32 + og * 8 + j;
            const float bv = b2f(bias[oc]);
            float m = 0.f;
            #pragma unroll
            for (int pp = 0; pp < 4; ++pp) m = fmaxf(m, acc[j * 4 + pp] + bv);
            p2c[((z * 128 + oc) * 21 + r0 + pr) * 21 + pc] = f2b(m);
        }
    }
}

// K3: conv 128->256 + relu : p2c[z] -> feats slot (t*8+b), n = fbase+z
__global__ __launch_bounds__(256) void k_conv3(
    const bf16* __restrict__ p2c, const bf16* __restrict__ w,
    const bf16* __restrict__ bias, bf16* __restrict__ feats, int fbase)
{
    __shared__ __align__(16) float in_s[16][8][23];
    __shared__ __align__(16) float w_s[16][9][32];
    const int z = blockIdx.z, rt = blockIdx.x, oq = blockIdx.y;
    const int n = fbase + z;
    const int slot = (n & 15) * 8 + (n >> 4);
    const int tid = threadIdx.x;
    const int s = tid & 63, og = tid >> 6;
    const bool act = (s < 63);
    const int lr = (s < 63) ? (s / 21) : 2, col = s % 21;
    const int r0 = rt * 6;
    float acc[16];
    #pragma unroll
    for (int i = 0; i < 16; ++i) acc[i] = 0.f;
    for (int cc = 0; cc < 8; ++cc) {
        const int c0 = cc * 16;
        __syncthreads();
        for (int i = tid; i < 2944; i += 256) {
            int ci = i / 184, rem = i % 184, r = rem / 23, gcol = rem % 23;
            int gy = r0 - 1 + r, gx = gcol - 1;
            float v = 0.f;
            if (gy >= 0 && gy < 21 && gx >= 0 && gx < 21)
                v = b2f(p2c[((z * 128 + c0 + ci) * 21 + gy) * 21 + gx]);
            in_s[ci][r][gcol] = v;
        }
        for (int i = tid; i < 4608; i += 256) {
            int ci = i / 288, rem = i % 288, tap = rem / 32, ol = rem & 31;
            w_s[ci][tap][ol] = b2f(w[((oq * 32 + ol) * 128 + c0 + ci) * 9 + tap]);
        }
        __syncthreads();
        if (act) {
            #pragma unroll 1
            for (int ci = 0; ci < 16; ++ci) {
                float iv0[3][3], iv1[3][3];
                #pragma unroll
                for (int r = 0; r < 3; ++r)
                    #pragma unroll
                    for (int q = 0; q < 3; ++q) {
                        iv0[r][q] = in_s[ci][lr + r][col + q];
                        iv1[r][q] = in_s[ci][lr + 3 + r][col + q];
                    }
                #pragma unroll
                for (int tap = 0; tap < 9; ++tap) {
                    const int ky = tap / 3, kx = tap % 3;
                    const float4 w0 = *(const float4*)&w_s[ci][tap][og * 8];
                    const float4 w1 = *(const float4*)&w_s[ci][tap][og * 8 + 4];
                    const float wv[8] = {w0.x, w0.y, w0.z, w0.w, w1.x, w1.y, w1.z, w1.w};
                    #pragma unroll
                    for (int j = 0; j < 8; ++j) {
                        acc[j]     += wv[j] * iv0[ky][kx];
                        acc[j + 8] += wv[j] * iv1[ky][kx];
                    }
                }
            }
        }
    }
    if (act) {
        const int oy0 = r0 + lr, oy1 = oy0 + 3;
        #pragma unroll
        for (int j = 0; j < 8; ++j) {
            const int oc = oq * 32 + og * 8 + j;
            const float bv = b2f(bias[oc]);
            if (oy0 < 21)
                feats[((slot * 256 + oc) * 21 + oy0) * 21 + col] = f2b(fmaxf(acc[j] + bv, 0.f));
            if (oy1 < 21)
                feats[((slot * 256 + oc) * 21 + oy1) * 21 + col] = f2b(fmaxf(acc[j + 8] + bv, 0.f));
        }
    }
}

// K4: depthwise 3x3 on [feats slot t | h] -> dwout f32 [8,512,441]
__global__ __launch_bounds__(256) void k_dw(
    const bf16* __restrict__ feats, const float* __restrict__ h,
    const bf16* __restrict__ dww, float* __restrict__ dwout, int t)
{
    int idx = blockIdx.x * 256 + threadIdx.x;
    if (idx >= 8 * 512 * 441) return;
    const int p = idx % 441;
    const int ch = (idx / 441) & 511;
    const int b = idx / (441 * 512);
    const int y = p / 21, x = p % 21;
    float wv[9];
    #pragma unroll
    for (int k = 0; k < 9; ++k) wv[k] = b2f(dww[ch * 9 + k]);
    float s = 0.f;
    #pragma unroll
    for (int ky = 0; ky < 3; ++ky) {
        int iy = y + ky - 1;
        if (iy < 0 || iy >= 21) continue;
        #pragma unroll
        for (int kx = 0; kx < 3; ++kx) {
            int ix = x + kx - 1;
            if (ix < 0 || ix >= 21) continue;
            float v;
            if (ch < 256) v = b2f(feats[((t * 8 + b) * 256 + ch) * 441 + iy * 21 + ix]);
            else          v = h[(b * 256 + (ch - 256)) * 441 + iy * 21 + ix];
            s += wv[ky * 3 + kx] * v;
        }
    }
    dwout[idx] = s;
}

// K5: pointwise 512->1024 + gates (2 px/thread); grid (7,8,8)
__global__ __launch_bounds__(256) void k_pw_gate(
    const float* __restrict__ dwout, const bf16* __restrict__ pww,
    const bf16* __restrict__ pwb, float* __restrict__ h, float* __restrict__ c,
    bf16* __restrict__ hst)
{
    __shared__ __align__(16) float a_s[32][64];
    __shared__ __align__(16) float w_s[32][128];
    const int b = blockIdx.z, cq = blockIdx.y, pt = blockIdx.x;
    const int tid = threadIdx.x;
    const int s = tid & 31, cg = tid >> 5;
    const int p0 = pt * 64 + s, p1 = p0 + 32;
    float acc0[16], acc1[16];
    #pragma unroll
    for (int i = 0; i < 16; ++i) { acc0[i] = 0.f; acc1[i] = 0.f; }
    for (int kk = 0; kk < 512; kk += 32) {
        __syncthreads();
        for (int i = tid; i < 2048; i += 256) {
            int k = i >> 6, pix = i & 63;
            int gp = pt * 64 + pix;
            a_s[k][pix] = (gp < 441) ? dwout[(b * 512 + kk + k) * 441 + gp] : 0.f;
        }
        for (int i = tid; i < 4096; i += 256) {
            int k = i >> 7, j = i & 127;
            int cgl = j >> 4, ccl = (j >> 2) & 3, gate = j & 3;
            int oc = gate * 256 + cq * 32 + cgl * 4 + ccl;
            w_s[k][j] = b2f(pww[oc * 512 + kk + k]);
        }
        __syncthreads();
        #pragma unroll 4
        for (int k = 0; k < 32; ++k) {
            const float a0 = a_s[k][s], a1 = a_s[k][s + 32];
            const float4 q0 = *(const float4*)&w_s[k][cg * 16];
            const float4 q1 = *(const float4*)&w_s[k][cg * 16 + 4];
            const float4 q2 = *(const float4*)&w_s[k][cg * 16 + 8];
            const float4 q3 = *(const float4*)&w_s[k][cg * 16 + 12];
            const float wv[16] = {q0.x, q0.y, q0.z, q0.w, q1.x, q1.y, q1.z, q1.w,
                                  q2.x, q2.y, q2.z, q2.w, q3.x, q3.y, q3.z, q3.w};
            #pragma unroll
            for (int j = 0; j < 16; ++j) { acc0[j] += wv[j] * a0; acc1[j] += wv[j] * a1; }
        }
    }
    #pragma unroll
    for (int ccl = 0; ccl < 4; ++ccl) {
        const int ch = cq * 32 + cg * 4 + ccl;
        const float bi = b2f(pwb[ch]);
        const float bfg = b2f(pwb[256 + ch]);
        const float bo = b2f(pwb[512 + ch]);
        const float bg = b2f(pwb[768 + ch]);
        if (p0 < 441) {
            float ig = sigf(acc0[ccl * 4 + 0] + bi);
            float fg = sigf(acc0[ccl * 4 + 1] + bfg);
            float og = sigf(acc0[ccl * 4 + 2] + bo);
            float gg = tanhfast(acc0[ccl * 4 + 3] + bg);
            int ci2 = (b * 256 + ch) * 441 + p0;
            float c2 = fg * c[ci2] + ig * gg;
            float h2 = og * tanhfast(c2);
            c[ci2] = c2; h[ci2] = h2;
            hst[ci2] = f2b(h2);
        }
        if (p1 < 441) {
            float ig = sigf(acc1[ccl * 4 + 0] + bi);
            float fg = sigf(acc1[ccl * 4 + 1] + bfg);
            float og = sigf(acc1[ccl * 4 + 2] + bo);
            float gg = tanhfast(acc1[ccl * 4 + 3] + bg);
            int ci2 = (b * 256 + ch) * 441 + p1;
            float c2 = fg * c[ci2] + ig * gg;
            float h2 = og * tanhfast(c2);
            c[ci2] = c2; h[ci2] = h2;
            hst[ci2] = f2b(h2);
        }
    }
}

// K6: dec1 MFMA. grid (7 ntile, 4 par, 32 z). D[128][63] per block.
__global__ __launch_bounds__(256) void k_dec1_mfma(
    const bf16* __restrict__ feats, const bf16* __restrict__ hs0,
    const bf16* __restrict__ wc1, const bf16* __restrict__ bias,
    bf16* __restrict__ d1c, int c0f)
{
    __shared__ __align__(16) short W_s[128 * 72];   // [m][k] pad 72
    __shared__ __align__(16) short H_s[16 * 5 * 23];  // [ci][r][c] halo
    const int nt = blockIdx.x, par = blockIdx.y, z = blockIdx.z;
    const int py = par >> 1, px = par & 1;
    const int n = c0f + z, bb = n >> 4, tt = n & 15;
    const short* hsf = (const short*)((tt == 0) ? (hs0 + bb * 112896)
                                    : (feats + (((tt - 1) * 8 + bb) * 112896)));
    const int tid = threadIdx.x;
    const int wave = tid >> 6, lane = tid & 63;
    const int quad = lane >> 4, nl = lane & 15;
    const int nn = wave * 16 + nl;                 // 0..63, valid < 63
    const int np = (nn < 63) ? nn : 62;
    const int iyl = np / 21, ix = np % 21;
    const int r0 = nt * 3;
    f32x4 acc[8];
    #pragma unroll
    for (int f = 0; f < 8; ++f) acc[f] = (f32x4){0.f, 0.f, 0.f, 0.f};
    const int hbase = (py + iyl) * 23 + (px + ix);
    for (int cc = 0; cc < 16; ++cc) {
        __syncthreads();
        for (int i = tid; i < 1024; i += 256) {
            int m = i >> 3, k8 = (i & 7) * 8;
            uint4 v = *(const uint4*)&wc1[((par * 128 + m) << 10) + cc * 64 + k8];
            *(uint4*)&W_s[m * 72 + k8] = v;
        }
        for (int i = tid; i < 1840; i += 256) {
            int ci = i / 115, rem = i % 115, r = rem / 23, col = rem % 23;
            int gy = r0 + r - 1, gx = col - 1;
            short v = 0;
            if (gy >= 0 && gy < 21 && gx >= 0 && gx < 21)
                v = hsf[((cc * 16 + ci) * 21 + gy) * 21 + gx];
            H_s[(ci * 5 + r) * 23 + col] = v;
        }
        __syncthreads();
        #pragma unroll
        for (int s = 0; s < 2; ++s) {
            bf16x8 bfv;
            #pragma unroll
            for (int j = 0; j < 8; ++j) {
                int ci = s * 8 + quad * 2 + (j >> 2);
                int a = (j >> 1) & 1, b = j & 1;
                bfv[j] = H_s[ci * 115 + a * 23 + b + hbase];
            }
            #pragma unroll
            for (int f = 0; f < 8; ++f) {
                bf16x8 af = *(const bf16x8*)&W_s[(f * 16 + nl) * 72 + s * 32 + quad * 8];
                acc[f] = __builtin_amdgcn_mfma_f32_16x16x32_bf16(af, bfv, acc[f], 0, 0, 0);
            }
        }
    }
    if (nn < 63) {
        const int oy = 2 * (r0 + iyl) + py, ox = 2 * ix + px;
        #pragma unroll
        for (int f = 0; f < 8; ++f)
            #pragma unroll
            for (int reg = 0; reg < 4; ++reg) {
                const int oc = f * 16 + quad * 4 + reg;
                float v = acc[f][reg] + b2f(bias[oc]);
                d1c[(z * 128 + oc) * 1764 + oy * 42 + ox] = f2b(fmaxf(v, 0.f));
            }
    }
}

// K7: dec2 MFMA fused with 1x1 w3-reduce -> direct out. grid (28, 4, 32).
__global__ __launch_bounds__(256) void k_dec2f_mfma(
    const bf16* __restrict__ d1c, const bf16* __restrict__ wc2,
    const bf16* __restrict__ bias, const bf16* __restrict__ w3,
    const bf16* __restrict__ b3, void* __restrict__ out, int c0f,
    const int* __restrict__ flag)
{
    __shared__ __align__(16) short W_s[64 * 72];
    __shared__ __align__(16) short H_s[16 * 4 * 44];
    const int nt = blockIdx.x, par = blockIdx.y, z = blockIdx.z;
    const int py = par >> 1, px = par & 1;
    const int tid = threadIdx.x;
    const int wave = tid >> 6, lane = tid & 63;
    const int quad = lane >> 4, nl = lane & 15;
    const int nn = wave * 16 + nl;
    const int p0 = nt * 63;
    const int iy_lo = p0 / 42;
    const int p = p0 + ((nn < 63) ? nn : 62);
    const int iyl = p / 42 - iy_lo, ix = p % 42;
    f32x4 acc[4];
    #pragma unroll
    for (int f = 0; f < 4; ++f) acc[f] = (f32x4){0.f, 0.f, 0.f, 0.f};
    const int hbase = (py + iyl) * 44 + (px + ix);
    for (int cc = 0; cc < 8; ++cc) {
        __syncthreads();
        for (int i = tid; i < 512; i += 256) {
            int m = i >> 3, k8 = (i & 7) * 8;
            uint4 v = *(const uint4*)&wc2[((par * 64 + m) << 9) + cc * 64 + k8];
            *(uint4*)&W_s[m * 72 + k8] = v;
        }
        for (int i = tid; i < 2816; i += 256) {
            int ci = i / 176, rem = i % 176, r = rem / 44, col = rem % 44;
            int gy = iy_lo + r - 1, gx = col - 1;
            short v = 0;
            if (gy >= 0 && gy < 42 && gx >= 0 && gx < 42)
                v = ((const short*)d1c)[((z * 128 + cc * 16 + ci) * 42 + gy) * 42 + gx];
            H_s[(ci * 4 + r) * 44 + col] = v;
        }
        __syncthreads();
        #pragma unroll
        for (int s = 0; s < 2; ++s) {
            bf16x8 bfv;
            #pragma unroll
            for (int j = 0; j < 8; ++j) {
                int ci = s * 8 + quad * 2 + (j >> 2);
                int a = (j >> 1) & 1, b = j & 1;
                bfv[j] = H_s[ci * 176 + a * 44 + b + hbase];
            }
            #pragma unroll
            for (int f = 0; f < 4; ++f) {
                bf16x8 af = *(const bf16x8*)&W_s[(f * 16 + nl) * 72 + s * 32 + quad * 8];
                acc[f] = __builtin_amdgcn_mfma_f32_16x16x32_bf16(af, bfv, acc[f], 0, 0, 0);
            }
        }
    }
    // fused epilogue: relu + w3 reduce over this lane's 16 oc, then quad-reduce
    float part = 0.f;
    #pragma unroll
    for (int f = 0; f < 4; ++f)
        #pragma unroll
        for (int reg = 0; reg < 4; ++reg) {
            const int oc = f * 16 + quad * 4 + reg;
            part += b2f(w3[oc]) * fmaxf(acc[f][reg] + b2f(bias[oc]), 0.f);
        }
    part += __shfl_xor(part, 16);
    part += __shfl_xor(part, 32);
    if (quad == 0 && nn < 63) {
        const int oy = 2 * (iy_lo + iyl) + py, ox = 2 * ix + px;
        const float v = part + b2f(b3[0]);
        const long oi = (long)(c0f + z) * 7056 + oy * 84 + ox;
        if (*flag) ((float*)out)[oi] = v;
        else       ((bf16*)out)[oi]  = f2b(v);
    }
}

// K9: flush final h,c -> d_out
__global__ __launch_bounds__(256) void k_out_hc(
    const float* __restrict__ h, const float* __restrict__ c,
    void* __restrict__ out, const int* __restrict__ flag)
{
    int idx = blockIdx.x * 256 + threadIdx.x;
    if (idx >= 903168) return;
    if (*flag) {
        ((float*)out)[903168 + idx] = h[idx];
        ((float*)out)[1806336 + idx] = c[idx];
    } else {
        ((bf16*)out)[903168 + idx]  = f2b(h[idx]);
        ((bf16*)out)[1806336 + idx] = f2b(c[idx]);
    }
}

extern "C" void kernel_launch(void* const* d_in, const int* in_sizes, int n_in,
                              void* d_out, int out_size, void* d_ws, size_t ws_size,
                              hipStream_t stream)
{
    char* wsb = (char*)d_ws;
    static const int wsz[15] = {1728, 64, 73728, 128, 294912, 256, 4608, 524288,
                                1024, 294912, 128, 73728, 64, 64, 1};
    static const long woff[15] = {0, 3456, 3584, 151040, 151296, 741120, 741632,
                                  750848, 1799424, 1801472, 2391296, 2391552,
                                  2539008, 2539136, 2539264};
    const long FLAG_OFF = 2539280;
    const long WC1_OFF = 2539296;          // 1,048,576 B
    const long WC2_OFF = 3587872;          //   262,144 B
    const long CE = 3850016;
    int* flag = (int*)(wsb + FLAG_OFF);

    k_detect<<<1, 256, 0, stream>>>((const unsigned short*)d_in[0], 262144, flag);
    bf16* cw[15];
    for (int i = 0; i < 15; ++i) {
        cw[i] = (bf16*)(wsb + woff[i]);
        k_canon<<<(wsz[i] + 255) / 256, 256, 0, stream>>>(d_in[i + 1], cw[i], wsz[i], flag);
    }
    const void* x = d_in[0];
    bf16 *enc_w1 = cw[0], *enc_b1 = cw[1], *enc_w2 = cw[2], *enc_b2 = cw[3],
         *enc_w3 = cw[4], *enc_b3 = cw[5], *dw_w = cw[6], *pw_w = cw[7],
         *pw_b = cw[8], *dec_w1 = cw[9], *dec_b1 = cw[10], *dec_w2 = cw[11],
         *dec_b2 = cw[12], *dec_w3 = cw[13], *dec_b3 = cw[14];
    bf16* wc1 = (bf16*)(wsb + WC1_OFF);
    bf16* wc2 = (bf16*)(wsb + WC2_OFF);

    k_combine1<<<2048, 256, 0, stream>>>(dec_w1, wc1);
    k_combine2<<<512, 256, 0, stream>>>(dec_w2, wc2);

    bf16*  feats = (bf16*)(wsb + CE);                  // 28,901,376
    bf16*  hs0   = (bf16*)(wsb + CE + 28901376);       //  1,806,336
    float* hbuf  = (float*)(wsb + CE + 30707712);      //  3,612,672
    float* cbuf  = (float*)(wsb + CE + 34320384);      //  3,612,672
    float* dwout = (float*)(wsb + CE + 37933056);      //  7,225,344 (LSTM)
    bf16*  d1c   = (bf16*)(wsb + CE + 37933056);       // 14,450,688 (decode)
    bf16*  p1c   = (bf16*)(wsb + CE + 37933056);       //  7,225,344 (encode)
    bf16*  p2c   = (bf16*)(wsb + CE + 45158400);       //  3,612,672 (encode)

    for (int f0 = 0; f0 < 128; f0 += 32) {
        k_conv1_pool<<<dim3(36, 32), 256, 0, stream>>>(x, enc_w1, enc_b1, p1c, f0, flag);
        k_conv2_pool<<<dim3(7, 4, 32), 256, 0, stream>>>(p1c, enc_w2, enc_b2, p2c);
        k_conv3<<<dim3(4, 8, 32), 256, 0, stream>>>(p2c, enc_w3, enc_b3, feats, f0);
    }
    hipMemsetAsync(hbuf, 0, 2 * 3612672, stream);
    for (int t = 0; t < 16; ++t) {
        bf16* hst = (t == 0) ? hs0 : (feats + (long)(t - 1) * 8 * 112896);
        k_dw<<<7056, 256, 0, stream>>>(feats, hbuf, dw_w, dwout, t);
        k_pw_gate<<<dim3(7, 8, 8), 256, 0, stream>>>(dwout, pw_w, pw_b, hbuf, cbuf, hst);
    }
    k_out_hc<<<3528, 256, 0, stream>>>(hbuf, cbuf, d_out, flag);
    for (int c0f = 0; c0f < 128; c0f += 32) {
        k_dec1_mfma<<<dim3(7, 4, 32), 256, 0, stream>>>(feats, hs0, wc1, dec_b1, d1c, c0f);
        k_dec2f_mfma<<<dim3(28, 4, 32), 256, 0, stream>>>(d1c, wc2, dec_b2, dec_w3,
                                                          dec_b3, d_out, c0f, flag);
    }
}

// Round 9
// 3604.121 us; speedup vs baseline: 3.3975x; 1.4553x over previous
//
#include <hip/hip_runtime.h>
#include <hip/hip_bf16.h>

typedef __hip_bfloat16 bf16;
typedef __attribute__((ext_vector_type(8))) short bf16x8;   // 8 bf16 (4 VGPRs)
typedef __attribute__((ext_vector_type(4))) float f32x4;    // 4 fp32 acc
#define DEV static __device__ __forceinline__

DEV float b2f(bf16 v) { return __bfloat162float(v); }
DEV bf16  f2b(float v) { return __float2bfloat16(v); }
DEV float sigf(float x) { return 1.0f / (1.0f + __expf(-x)); }
DEV float tanhfast(float x) { return 2.0f / (1.0f + __expf(-2.0f * x)) - 1.0f; }

// ---------------------------------------------------------------------------
// fp32 I/O (proved r4). Round-9: conv3 and pw_gate moved to bf16 MFMA
// (same 16x16x32 pattern as the passing dec1/dec2 kernels).
//  - pw: wcp[m=ch*4+gate][k] so C rows (quad*4+reg) = 4 gates of one channel
//    -> LSTM epilogue fully in-register. dwout now bf16 (B operand).
//  - conv3: K=1152 tap-major wc3[oc][tap*128+ci]; halo staged once as
//    H_s[rc][ci] (pad 136) -> B-frag = single b128 at tap offset.
// ws: canon weights+flag | wc1 1MB | wc2 256KB | wcp 1MB | wc3 576KB |
//     CE=5,488,416: feats 28.9M | hs0 | h | c | dwout(bf16)/d1c/p1c | p2c.
//     Peak CE+52,383,744 = 57.9MB <= confirmed 63.95MB.
// ---------------------------------------------------------------------------

__global__ void k_detect(const unsigned short* __restrict__ xb, int nscan, int* flag)
{
    __shared__ int cnt_s[256];
    int tid = threadIdx.x;
    int c = 0;
    for (int i = tid; i < nscan; i += 256) {
        unsigned int e = (xb[i] >> 7) & 0xFF;
        c += (e >= 0xC0);
    }
    cnt_s[tid] = c;
    __syncthreads();
    for (int off = 128; off > 0; off >>= 1) {
        if (tid < off) cnt_s[tid] += cnt_s[tid + off];
        __syncthreads();
    }
    if (tid == 0) *flag = (cnt_s[0] > 1000) ? 1 : 0;
}

__global__ __launch_bounds__(256) void k_canon(
    const void* __restrict__ src, bf16* __restrict__ dst, int n,
    const int* __restrict__ flag)
{
    int i = blockIdx.x * 256 + threadIdx.x;
    if (i >= n) return;
    if (*flag) dst[i] = f2b(((const float*)src)[i]);
    else       dst[i] = ((const bf16*)src)[i];
}

// combine dec_w1 -> wc1[par][oc=128][k=ci*4+a*2+b], K=1024
__global__ __launch_bounds__(256) void k_combine1(
    const bf16* __restrict__ w, bf16* __restrict__ wc1)
{
    int idx = blockIdx.x * 256 + threadIdx.x;
    if (idx >= 524288) return;
    int b = idx & 1, a = (idx >> 1) & 1, ci = (idx >> 2) & 255;
    int oc = (idx >> 10) & 127, par = idx >> 17;
    int py = par >> 1, px = par & 1;
    const bf16* wb = w + (oc * 256 + ci) * 9;
    float v = 0.f;
    #pragma unroll
    for (int ky = 0; ky < 3; ++ky) {
        bool rok = (py == 0) ? (a == 0 ? (ky == 0) : (ky >= 1))
                             : (a == 0 ? (ky <= 1) : (ky == 2));
        if (!rok) continue;
        #pragma unroll
        for (int kx = 0; kx < 3; ++kx) {
            bool cok = (px == 0) ? (b == 0 ? (kx == 0) : (kx >= 1))
                                 : (b == 0 ? (kx <= 1) : (kx == 2));
            if (cok) v += b2f(wb[ky * 3 + kx]);
        }
    }
    wc1[idx] = f2b(v);
}

// combine dec_w2 -> wc2[par][oc=64][k=ci*4+a*2+b], K=512
__global__ __launch_bounds__(256) void k_combine2(
    const bf16* __restrict__ w, bf16* __restrict__ wc2)
{
    int idx = blockIdx.x * 256 + threadIdx.x;
    if (idx >= 131072) return;
    int b = idx & 1, a = (idx >> 1) & 1, ci = (idx >> 2) & 127;
    int oc = (idx >> 9) & 63, par = idx >> 15;
    int py = par >> 1, px = par & 1;
    const bf16* wb = w + (oc * 128 + ci) * 9;
    float v = 0.f;
    #pragma unroll
    for (int ky = 0; ky < 3; ++ky) {
        bool rok = (py == 0) ? (a == 0 ? (ky == 0) : (ky >= 1))
                             : (a == 0 ? (ky <= 1) : (ky == 2));
        if (!rok) continue;
        #pragma unroll
        for (int kx = 0; kx < 3; ++kx) {
            bool cok = (px == 0) ? (b == 0 ? (kx == 0) : (kx >= 1))
                                 : (b == 0 ? (kx <= 1) : (kx == 2));
            if (cok) v += b2f(wb[ky * 3 + kx]);
        }
    }
    wc2[idx] = f2b(v);
}

// rearrange pw_w -> wcp[m=ch*4+gate][k=512]
__global__ __launch_bounds__(256) void k_prep_pw(
    const bf16* __restrict__ pww, bf16* __restrict__ wcp)
{
    int idx = blockIdx.x * 256 + threadIdx.x;
    if (idx >= 524288) return;
    int k = idx & 511, m = idx >> 9;
    int ch = m >> 2, gate = m & 3;
    wcp[idx] = pww[(gate * 256 + ch) * 512 + k];
}

// rearrange enc_w3 -> wc3[oc][tap*128+ci]
__global__ __launch_bounds__(256) void k_prep_w3(
    const bf16* __restrict__ w, bf16* __restrict__ wc3)
{
    int idx = blockIdx.x * 256 + threadIdx.x;
    if (idx >= 294912) return;
    int oc = idx / 1152, rem = idx % 1152;
    int tap = rem >> 7, ci = rem & 127;
    wc3[idx] = w[(oc * 128 + ci) * 9 + tap];
}

// K1: conv 3->64 + relu + pool : x[f0+z] -> p1c[z,64,42,42]
__global__ __launch_bounds__(256) void k_conv1_pool(
    const void* __restrict__ xv, const bf16* __restrict__ w,
    const bf16* __restrict__ bias, bf16* __restrict__ p1c, int fbase,
    const int* __restrict__ flag)
{
    __shared__ __align__(16) float in_s[3][16][16];
    __shared__ __align__(16) float w_s[1728];
    __shared__ __align__(16) float b_s[64];
    const int z = blockIdx.y;
    const int n = fbase + z;
    const int ty = blockIdx.x / 6, tx = blockIdx.x % 6;
    const int tid = threadIdx.x;
    const int isf32 = *flag;
    for (int i = tid; i < 1728; i += 256) w_s[i] = b2f(w[i]);
    if (tid < 64) b_s[tid] = b2f(bias[tid]);
    const int iy0 = ty * 14 - 1, ix0 = tx * 14 - 1;
    for (int i = tid; i < 768; i += 256) {
        int ci = i >> 8, r = (i >> 4) & 15, col = i & 15;
        int gy = iy0 + r, gx = ix0 + col;
        float v = 0.f;
        if (gy >= 0 && gy < 84 && gx >= 0 && gx < 84) {
            int idx = (n * 3 + ci) * 7056 + gy * 84 + gx;
            v = isf32 ? ((const float*)xv)[idx] : b2f(((const bf16*)xv)[idx]);
        }
        in_s[ci][r][col] = v;
    }
    __syncthreads();
    for (int idx = tid; idx < 3136; idx += 256) {
        int oc = idx / 49, p = idx % 49;
        int py = p / 7, px = p % 7;
        float m = 0.f;
        #pragma unroll
        for (int pp = 0; pp < 4; ++pp) {
            int a = pp >> 1, bb = pp & 1;
            float sacc = b_s[oc];
            for (int ci = 0; ci < 3; ++ci)
                #pragma unroll
                for (int ky = 0; ky < 3; ++ky)
                    #pragma unroll
                    for (int kx = 0; kx < 3; ++kx)
                        sacc += w_s[(oc * 3 + ci) * 9 + ky * 3 + kx] *
                                in_s[ci][2 * py + a + ky][2 * px + bb + kx];
            m = fmaxf(m, sacc);
        }
        p1c[((z * 64 + oc) * 42 + ty * 7 + py) * 42 + tx * 7 + px] = f2b(m);
    }
}

// K2: conv 64->128 + relu + pool : p1c[z] -> p2c[z,128,21,21]
__global__ __launch_bounds__(256) void k_conv2_pool(
    const bf16* __restrict__ p1c, const bf16* __restrict__ w,
    const bf16* __restrict__ bias, bf16* __restrict__ p2c)
{
    __shared__ __align__(16) float in_s[16][8][44];
    __shared__ __align__(16) float w_s[16][9][32];
    const int z = blockIdx.z, rt = blockIdx.x, oq = blockIdx.y;
    const int tid = threadIdx.x;
    const int s = tid & 63, og = tid >> 6;
    const int pr = (s < 63) ? (s / 21) : 2, pc = s % 21;
    const bool act = (s < 63);
    const int r0 = rt * 3;
    const int iy0 = r0 * 2 - 1;
    float acc[32];
    #pragma unroll
    for (int i = 0; i < 32; ++i) acc[i] = 0.f;
    for (int cc = 0; cc < 4; ++cc) {
        const int c0 = cc * 16;
        __syncthreads();
        for (int i = tid; i < 5632; i += 256) {
            int ci = i / 352, rem = i % 352, r = rem / 44, col = rem % 44;
            int gy = iy0 + r, gx = col - 1;
            float v = 0.f;
            if (gy >= 0 && gy < 42 && gx >= 0 && gx < 42)
                v = b2f(p1c[((z * 64 + c0 + ci) * 42 + gy) * 42 + gx]);
            in_s[ci][r][col] = v;
        }
        for (int i = tid; i < 4608; i += 256) {
            int ci = i / 288, rem = i % 288, tap = rem / 32, ol = rem & 31;
            w_s[ci][tap][ol] = b2f(w[((oq * 32 + ol) * 64 + c0 + ci) * 9 + tap]);
        }
        __syncthreads();
        if (act) {
            #pragma unroll 1
            for (int ci = 0; ci < 16; ++ci) {
                float iv[4][4];
                #pragma unroll
                for (int r = 0; r < 4; ++r)
                    #pragma unroll
                    for (int col = 0; col < 4; ++col)
                        iv[r][col] = in_s[ci][2 * pr + r][2 * pc + col];
                #pragma unroll
                for (int tap = 0; tap < 9; ++tap) {
                    const int ky = tap / 3, kx = tap % 3;
                    const float4 w0 = *(const float4*)&w_s[ci][tap][og * 8];
                    const float4 w1 = *(const float4*)&w_s[ci][tap][og * 8 + 4];
                    const float wv[8] = {w0.x, w0.y, w0.z, w0.w, w1.x, w1.y, w1.z, w1.w};
                    #pragma unroll
                    for (int j = 0; j < 8; ++j)
                        #pragma unroll
                        for (int pp = 0; pp < 4; ++pp)
                            acc[j * 4 + pp] += wv[j] * iv[(pp >> 1) + ky][(pp & 1) + kx];
                }
            }
        }
    }
    if (act) {
        #pragma unroll
        for (int j = 0; j < 8; ++j) {
            const int oc = oq * 32 + og * 8 + j;
            const float bv = b2f(bias[oc]);
            float m = 0.f;
            #pragma unroll
            for (int pp = 0; pp < 4; ++pp) m = fmaxf(m, acc[j * 4 + pp] + bv);
            p2c[((z * 128 + oc) * 21 + r0 + pr) * 21 + pc] = f2b(m);
        }
    }
}

// K3: conv 128->256 + relu via MFMA : p2c[z] -> feats slot (t*8+b)
// grid (7 nt, 2 oq, 32 z). M=128, N=63 (3 rows x 21), K=1152 tap-major.
__global__ __launch_bounds__(256) void k_conv3_mfma(
    const bf16* __restrict__ p2c, const bf16* __restrict__ wc3,
    const bf16* __restrict__ bias, bf16* __restrict__ feats, int fbase)
{
    __shared__ __align__(16) short H_s[115 * 136];  // [rc=5x23][ci pad136]
    __shared__ __align__(16) short W_s[128 * 40];   // [m][32 k pad40]
    const int nt = blockIdx.x, oq = blockIdx.y, z = blockIdx.z;
    const int n = fbase + z;
    const int slot = (n & 15) * 8 + (n >> 4);
    const int tid = threadIdx.x;
    const int wave = tid >> 6, lane = tid & 63;
    const int quad = lane >> 4, nl = lane & 15;
    const int nn = wave * 16 + nl;
    const int np = (nn < 63) ? nn : 62;
    const int iyl = np / 21, ox = np % 21;
    const int r0 = nt * 3;
    // stage halo once: rows r0-1..r0+3, cols -1..21, all 128 ci
    for (int i = tid; i < 14720; i += 256) {
        int ci = i / 115, rc = i % 115, r = rc / 23, col = rc % 23;
        int gy = r0 + r - 1, gx = col - 1;
        short v = 0;
        if (gy >= 0 && gy < 21 && gx >= 0 && gx < 21)
            v = ((const short*)p2c)[((z * 128 + ci) * 21 + gy) * 21 + gx];
        H_s[rc * 136 + ci] = v;
    }
    f32x4 acc[8];
    #pragma unroll
    for (int f = 0; f < 8; ++f) acc[f] = (f32x4){0.f, 0.f, 0.f, 0.f};
    const int hb = iyl * 23 + ox;
    for (int tap = 0; tap < 9; ++tap) {
        const int dy = tap / 3, dx = tap % 3;
        const int hofs = (hb + dy * 23 + dx) * 136;
        for (int cc = 0; cc < 4; ++cc) {
            __syncthreads();
            for (int i = tid; i < 512; i += 256) {
                int m = i >> 2, k8 = (i & 3) * 8;
                *(uint4*)&W_s[m * 40 + k8] =
                    *(const uint4*)&wc3[(oq * 128 + m) * 1152 + tap * 128 + cc * 32 + k8];
            }
            __syncthreads();
            const bf16x8 bv = *(const bf16x8*)&H_s[hofs + cc * 32 + quad * 8];
            #pragma unroll
            for (int f = 0; f < 8; ++f) {
                bf16x8 af = *(const bf16x8*)&W_s[(f * 16 + nl) * 40 + quad * 8];
                acc[f] = __builtin_amdgcn_mfma_f32_16x16x32_bf16(af, bv, acc[f], 0, 0, 0);
            }
        }
    }
    if (nn < 63) {
        const int oy = r0 + iyl;
        #pragma unroll
        for (int f = 0; f < 8; ++f)
            #pragma unroll
            for (int reg = 0; reg < 4; ++reg) {
                const int oc = oq * 128 + f * 16 + quad * 4 + reg;
                float v = acc[f][reg] + b2f(bias[oc]);
                feats[(slot * 256 + oc) * 441 + oy * 21 + ox] = f2b(fmaxf(v, 0.f));
            }
    }
}

// K4: depthwise 3x3 on [feats slot t | h] -> dwout bf16 [8,512,441]
__global__ __launch_bounds__(256) void k_dw(
    const bf16* __restrict__ feats, const float* __restrict__ h,
    const bf16* __restrict__ dww, bf16* __restrict__ dwout, int t)
{
    int idx = blockIdx.x * 256 + threadIdx.x;
    if (idx >= 8 * 512 * 441) return;
    const int p = idx % 441;
    const int ch = (idx / 441) & 511;
    const int b = idx / (441 * 512);
    const int y = p / 21, x = p % 21;
    float wv[9];
    #pragma unroll
    for (int k = 0; k < 9; ++k) wv[k] = b2f(dww[ch * 9 + k]);
    float s = 0.f;
    #pragma unroll
    for (int ky = 0; ky < 3; ++ky) {
        int iy = y + ky - 1;
        if (iy < 0 || iy >= 21) continue;
        #pragma unroll
        for (int kx = 0; kx < 3; ++kx) {
            int ix = x + kx - 1;
            if (ix < 0 || ix >= 21) continue;
            float v;
            if (ch < 256) v = b2f(feats[((t * 8 + b) * 256 + ch) * 441 + iy * 21 + ix]);
            else          v = h[(b * 256 + (ch - 256)) * 441 + iy * 21 + ix];
            s += wv[ky * 3 + kx] * v;
        }
    }
    dwout[idx] = f2b(s);
}

// K5: pointwise + gates via MFMA. grid (7 nt, 8 mq, 8 b).
// M=128 (m=ch*4+gate), N=63, K=512. Gate math fully in-register.
__global__ __launch_bounds__(256) void k_pw_mfma(
    const bf16* __restrict__ dwout, const bf16* __restrict__ wcp,
    const bf16* __restrict__ pwb, float* __restrict__ h, float* __restrict__ c,
    bf16* __restrict__ hst)
{
    __shared__ __align__(16) short W_s[128 * 72];
    __shared__ __align__(16) short X_s[64 * 72];
    __shared__ bf16 pb_s[1024];
    const int nt = blockIdx.x, mq = blockIdx.y, b = blockIdx.z;
    const int tid = threadIdx.x;
    const int wave = tid >> 6, lane = tid & 63;
    const int quad = lane >> 4, nl = lane & 15;
    const int nn = wave * 16 + nl;
    for (int i = tid; i < 1024; i += 256) pb_s[i] = pwb[i];
    f32x4 acc[8];
    #pragma unroll
    for (int f = 0; f < 8; ++f) acc[f] = (f32x4){0.f, 0.f, 0.f, 0.f};
    for (int cc = 0; cc < 8; ++cc) {
        __syncthreads();
        for (int i = tid; i < 1024; i += 256) {
            int m = i >> 3, k8 = (i & 7) * 8;
            *(uint4*)&W_s[m * 72 + k8] =
                *(const uint4*)&wcp[(mq * 128 + m) * 512 + cc * 64 + k8];
        }
        for (int i = tid; i < 4096; i += 256) {
            int k = i >> 6, p = i & 63;
            short v = 0;
            if (p < 63)
                v = ((const short*)dwout)[(b * 512 + cc * 64 + k) * 441 + nt * 63 + p];
            X_s[p * 72 + k] = v;
        }
        __syncthreads();
        #pragma unroll
        for (int s = 0; s < 2; ++s) {
            const bf16x8 bv = *(const bf16x8*)&X_s[nn * 72 + s * 32 + quad * 8];
            #pragma unroll
            for (int f = 0; f < 8; ++f) {
                bf16x8 af = *(const bf16x8*)&W_s[(f * 16 + nl) * 72 + s * 32 + quad * 8];
                acc[f] = __builtin_amdgcn_mfma_f32_16x16x32_bf16(af, bv, acc[f], 0, 0, 0);
            }
        }
    }
    if (nn < 63) {
        const int p = nt * 63 + nn;
        #pragma unroll
        for (int f = 0; f < 8; ++f) {
            const int ch = mq * 32 + f * 4 + quad;
            float ig = sigf(acc[f][0] + b2f(pb_s[ch]));
            float fg = sigf(acc[f][1] + b2f(pb_s[256 + ch]));
            float og = sigf(acc[f][2] + b2f(pb_s[512 + ch]));
            float gg = tanhfast(acc[f][3] + b2f(pb_s[768 + ch]));
            const int ci2 = (b * 256 + ch) * 441 + p;
            float c2 = fg * c[ci2] + ig * gg;
            float h2 = og * tanhfast(c2);
            c[ci2] = c2; h[ci2] = h2;
            hst[ci2] = f2b(h2);
        }
    }
}

// K6: dec1 MFMA. grid (7 ntile, 4 par, 32 z). D[128][63] per block.
__global__ __launch_bounds__(256) void k_dec1_mfma(
    const bf16* __restrict__ feats, const bf16* __restrict__ hs0,
    const bf16* __restrict__ wc1, const bf16* __restrict__ bias,
    bf16* __restrict__ d1c, int c0f)
{
    __shared__ __align__(16) short W_s[128 * 72];   // [m][k] pad 72
    __shared__ __align__(16) short H_s[16 * 5 * 23];  // [ci][r][c] halo
    const int nt = blockIdx.x, par = blockIdx.y, z = blockIdx.z;
    const int py = par >> 1, px = par & 1;
    const int n = c0f + z, bb = n >> 4, tt = n & 15;
    const short* hsf = (const short*)((tt == 0) ? (hs0 + bb * 112896)
                                    : (feats + (((tt - 1) * 8 + bb) * 112896)));
    const int tid = threadIdx.x;
    const int wave = tid >> 6, lane = tid & 63;
    const int quad = lane >> 4, nl = lane & 15;
    const int nn = wave * 16 + nl;                 // 0..63, valid < 63
    const int np = (nn < 63) ? nn : 62;
    const int iyl = np / 21, ix = np % 21;
    const int r0 = nt * 3;
    f32x4 acc[8];
    #pragma unroll
    for (int f = 0; f < 8; ++f) acc[f] = (f32x4){0.f, 0.f, 0.f, 0.f};
    const int hbase = (py + iyl) * 23 + (px + ix);
    for (int cc = 0; cc < 16; ++cc) {
        __syncthreads();
        for (int i = tid; i < 1024; i += 256) {
            int m = i >> 3, k8 = (i & 7) * 8;
            uint4 v = *(const uint4*)&wc1[((par * 128 + m) << 10) + cc * 64 + k8];
            *(uint4*)&W_s[m * 72 + k8] = v;
        }
        for (int i = tid; i < 1840; i += 256) {
            int ci = i / 115, rem = i % 115, r = rem / 23, col = rem % 23;
            int gy = r0 + r - 1, gx = col - 1;
            short v = 0;
            if (gy >= 0 && gy < 21 && gx >= 0 && gx < 21)
                v = hsf[((cc * 16 + ci) * 21 + gy) * 21 + gx];
            H_s[(ci * 5 + r) * 23 + col] = v;
        }
        __syncthreads();
        #pragma unroll
        for (int s = 0; s < 2; ++s) {
            bf16x8 bfv;
            #pragma unroll
            for (int j = 0; j < 8; ++j) {
                int ci = s * 8 + quad * 2 + (j >> 2);
                int a = (j >> 1) & 1, b = j & 1;
                bfv[j] = H_s[ci * 115 + a * 23 + b + hbase];
            }
            #pragma unroll
            for (int f = 0; f < 8; ++f) {
                bf16x8 af = *(const bf16x8*)&W_s[(f * 16 + nl) * 72 + s * 32 + quad * 8];
                acc[f] = __builtin_amdgcn_mfma_f32_16x16x32_bf16(af, bfv, acc[f], 0, 0, 0);
            }
        }
    }
    if (nn < 63) {
        const int oy = 2 * (r0 + iyl) + py, ox = 2 * ix + px;
        #pragma unroll
        for (int f = 0; f < 8; ++f)
            #pragma unroll
            for (int reg = 0; reg < 4; ++reg) {
                const int oc = f * 16 + quad * 4 + reg;
                float v = acc[f][reg] + b2f(bias[oc]);
                d1c[(z * 128 + oc) * 1764 + oy * 42 + ox] = f2b(fmaxf(v, 0.f));
            }
    }
}

// K7: dec2 MFMA fused with 1x1 w3-reduce -> direct out. grid (28, 4, 32).
__global__ __launch_bounds__(256) void k_dec2f_mfma(
    const bf16* __restrict__ d1c, const bf16* __restrict__ wc2,
    const bf16* __restrict__ bias, const bf16* __restrict__ w3,
    const bf16* __restrict__ b3, void* __restrict__ out, int c0f,
    const int* __restrict__ flag)
{
    __shared__ __align__(16) short W_s[64 * 72];
    __shared__ __align__(16) short H_s[16 * 4 * 44];
    const int nt = blockIdx.x, par = blockIdx.y, z = blockIdx.z;
    const int py = par >> 1, px = par & 1;
    const int tid = threadIdx.x;
    const int wave = tid >> 6, lane = tid & 63;
    const int quad = lane >> 4, nl = lane & 15;
    const int nn = wave * 16 + nl;
    const int p0 = nt * 63;
    const int iy_lo = p0 / 42;
    const int p = p0 + ((nn < 63) ? nn : 62);
    const int iyl = p / 42 - iy_lo, ix = p % 42;
    f32x4 acc[4];
    #pragma unroll
    for (int f = 0; f < 4; ++f) acc[f] = (f32x4){0.f, 0.f, 0.f, 0.f};
    const int hbase = (py + iyl) * 44 + (px + ix);
    for (int cc = 0; cc < 8; ++cc) {
        __syncthreads();
        for (int i = tid; i < 512; i += 256) {
            int m = i >> 3, k8 = (i & 7) * 8;
            uint4 v = *(const uint4*)&wc2[((par * 64 + m) << 9) + cc * 64 + k8];
            *(uint4*)&W_s[m * 72 + k8] = v;
        }
        for (int i = tid; i < 2816; i += 256) {
            int ci = i / 176, rem = i % 176, r = rem / 44, col = rem % 44;
            int gy = iy_lo + r - 1, gx = col - 1;
            short v = 0;
            if (gy >= 0 && gy < 42 && gx >= 0 && gx < 42)
                v = ((const short*)d1c)[((z * 128 + cc * 16 + ci) * 42 + gy) * 42 + gx];
            H_s[(ci * 4 + r) * 44 + col] = v;
        }
        __syncthreads();
        #pragma unroll
        for (int s = 0; s < 2; ++s) {
            bf16x8 bfv;
            #pragma unroll
            for (int j = 0; j < 8; ++j) {
                int ci = s * 8 + quad * 2 + (j >> 2);
                int a = (j >> 1) & 1, b = j & 1;
                bfv[j] = H_s[ci * 176 + a * 44 + b + hbase];
            }
            #pragma unroll
            for (int f = 0; f < 4; ++f) {
                bf16x8 af = *(const bf16x8*)&W_s[(f * 16 + nl) * 72 + s * 32 + quad * 8];
                acc[f] = __builtin_amdgcn_mfma_f32_16x16x32_bf16(af, bfv, acc[f], 0, 0, 0);
            }
        }
    }
    float part = 0.f;
    #pragma unroll
    for (int f = 0; f < 4; ++f)
        #pragma unroll
        for (int reg = 0; reg < 4; ++reg) {
            const int oc = f * 16 + quad * 4 + reg;
            part += b2f(w3[oc]) * fmaxf(acc[f][reg] + b2f(bias[oc]), 0.f);
        }
    part += __shfl_xor(part, 16);
    part += __shfl_xor(part, 32);
    if (quad == 0 && nn < 63) {
        const int oy = 2 * (iy_lo + iyl) + py, ox = 2 * ix + px;
        const float v = part + b2f(b3[0]);
        const long oi = (long)(c0f + z) * 7056 + oy * 84 + ox;
        if (*flag) ((float*)out)[oi] = v;
        else       ((bf16*)out)[oi]  = f2b(v);
    }
}

// K9: flush final h,c -> d_out
__global__ __launch_bounds__(256) void k_out_hc(
    const float* __restrict__ h, const float* __restrict__ c,
    void* __restrict__ out, const int* __restrict__ flag)
{
    int idx = blockIdx.x * 256 + threadIdx.x;
    if (idx >= 903168) return;
    if (*flag) {
        ((float*)out)[903168 + idx] = h[idx];
        ((float*)out)[1806336 + idx] = c[idx];
    } else {
        ((bf16*)out)[903168 + idx]  = f2b(h[idx]);
        ((bf16*)out)[1806336 + idx] = f2b(c[idx]);
    }
}

extern "C" void kernel_launch(void* const* d_in, const int* in_sizes, int n_in,
                              void* d_out, int out_size, void* d_ws, size_t ws_size,
                              hipStream_t stream)
{
    char* wsb = (char*)d_ws;
    static const int wsz[15] = {1728, 64, 73728, 128, 294912, 256, 4608, 524288,
                                1024, 294912, 128, 73728, 64, 64, 1};
    static const long woff[15] = {0, 3456, 3584, 151040, 151296, 741120, 741632,
                                  750848, 1799424, 1801472, 2391296, 2391552,
                                  2539008, 2539136, 2539264};
    const long FLAG_OFF = 2539280;
    const long WC1_OFF = 2539296;          // 1,048,576 B
    const long WC2_OFF = 3587872;          //   262,144 B
    const long WCP_OFF = 3850016;          // 1,048,576 B
    const long WC3_OFF = 4898592;          //   589,824 B
    const long CE = 5488416;
    int* flag = (int*)(wsb + FLAG_OFF);

    k_detect<<<1, 256, 0, stream>>>((const unsigned short*)d_in[0], 262144, flag);
    bf16* cw[15];
    for (int i = 0; i < 15; ++i) {
        cw[i] = (bf16*)(wsb + woff[i]);
        k_canon<<<(wsz[i] + 255) / 256, 256, 0, stream>>>(d_in[i + 1], cw[i], wsz[i], flag);
    }
    const void* x = d_in[0];
    bf16 *enc_w1 = cw[0], *enc_b1 = cw[1], *enc_w2 = cw[2], *enc_b2 = cw[3],
         *enc_w3 = cw[4], *enc_b3 = cw[5], *dw_w = cw[6], *pw_w = cw[7],
         *pw_b = cw[8], *dec_w1 = cw[9], *dec_b1 = cw[10], *dec_w2 = cw[11],
         *dec_b2 = cw[12], *dec_w3 = cw[13], *dec_b3 = cw[14];
    bf16* wc1 = (bf16*)(wsb + WC1_OFF);
    bf16* wc2 = (bf16*)(wsb + WC2_OFF);
    bf16* wcp = (bf16*)(wsb + WCP_OFF);
    bf16* wc3 = (bf16*)(wsb + WC3_OFF);

    k_combine1<<<2048, 256, 0, stream>>>(dec_w1, wc1);
    k_combine2<<<512, 256, 0, stream>>>(dec_w2, wc2);
    k_prep_pw<<<2048, 256, 0, stream>>>(pw_w, wcp);
    k_prep_w3<<<1152, 256, 0, stream>>>(enc_w3, wc3);

    bf16*  feats = (bf16*)(wsb + CE);                  // 28,901,376
    bf16*  hs0   = (bf16*)(wsb + CE + 28901376);       //  1,806,336
    float* hbuf  = (float*)(wsb + CE + 30707712);      //  3,612,672
    float* cbuf  = (float*)(wsb + CE + 34320384);      //  3,612,672
    bf16*  dwout = (bf16*)(wsb + CE + 37933056);       //  1,806,336 (LSTM, bf16)
    bf16*  d1c   = (bf16*)(wsb + CE + 37933056);       // 14,450,688 (decode)
    bf16*  p1c   = (bf16*)(wsb + CE + 37933056);       //  7,225,344 (encode)
    bf16*  p2c   = (bf16*)(wsb + CE + 45158400);       //  3,612,672 (encode)

    for (int f0 = 0; f0 < 128; f0 += 32) {
        k_conv1_pool<<<dim3(36, 32), 256, 0, stream>>>(x, enc_w1, enc_b1, p1c, f0, flag);
        k_conv2_pool<<<dim3(7, 4, 32), 256, 0, stream>>>(p1c, enc_w2, enc_b2, p2c);
        k_conv3_mfma<<<dim3(7, 2, 32), 256, 0, stream>>>(p2c, wc3, enc_b3, feats, f0);
    }
    hipMemsetAsync(hbuf, 0, 2 * 3612672, stream);
    for (int t = 0; t < 16; ++t) {
        bf16* hst = (t == 0) ? hs0 : (feats + (long)(t - 1) * 8 * 112896);
        k_dw<<<7056, 256, 0, stream>>>(feats, hbuf, dw_w, dwout, t);
        k_pw_mfma<<<dim3(7, 8, 8), 256, 0, stream>>>(dwout, wcp, pw_b, hbuf, cbuf, hst);
    }
    k_out_hc<<<3528, 256, 0, stream>>>(hbuf, cbuf, d_out, flag);
    for (int c0f = 0; c0f < 128; c0f += 32) {
        k_dec1_mfma<<<dim3(7, 4, 32), 256, 0, stream>>>(feats, hs0, wc1, dec_b1, d1c, c0f);
        k_dec2f_mfma<<<dim3(28, 4, 32), 256, 0, stream>>>(d1c, wc2, dec_b2, dec_w3,
                                                          dec_b3, d_out, c0f, flag);
    }
}

// Round 10
// 2898.975 us; speedup vs baseline: 4.2239x; 1.2432x over previous
//
#include <hip/hip_runtime.h>
#include <hip/hip_bf16.h>

typedef __hip_bfloat16 bf16;
typedef __attribute__((ext_vector_type(8))) short bf16x8;   // 8 bf16 (4 VGPRs)
typedef __attribute__((ext_vector_type(4))) float f32x4;    // 4 fp32 acc
#define DEV static __device__ __forceinline__

DEV float b2f(bf16 v) { return __bfloat162float(v); }
DEV bf16  f2b(float v) { return __float2bfloat16(v); }
DEV float sigf(float x) { return 1.0f / (1.0f + __expf(-x)); }
DEV float tanhfast(float x) { return 2.0f / (1.0f + __expf(-2.0f * x)) - 1.0f; }

// ---------------------------------------------------------------------------
// fp32 I/O (proved r4). Round-10: conv2 -> MFMA with fused maxpool (pool of
// relu == relu of max over 4 conv parities; per-block acc[4][8] then max).
// K=576 tap-major, W shared across parities. Encoder chunk 64 frames so
// conv2 grid = 448 blocks. k_detect nscan 262144->8192. canon merged to 1.
//
// ws: canon weights+flag | wc1 1MB | wc2 256KB | wcp 1MB | wc3 576KB |
//     wc2e 144KB | CE=5,635,872.
//  feats @CE 28.9M (t-major slots) | hs0 +28,901,376 | h +30,707,712 |
//  c +34,320,384 | dwout(bf16)/d1c/p1c +37,933,056 | p2c(encode) +28,901,376
//  (aliases hs0/h/c, dead during encode). Peak ~58 MB <= confirmed 63.95 MB.
// ---------------------------------------------------------------------------

__global__ void k_detect(const unsigned short* __restrict__ xb, int nscan, int* flag)
{
    __shared__ int cnt_s[256];
    int tid = threadIdx.x;
    int c = 0;
    for (int i = tid; i < nscan; i += 256) {
        unsigned int e = (xb[i] >> 7) & 0xFF;
        c += (e >= 0xC0);
    }
    cnt_s[tid] = c;
    __syncthreads();
    for (int off = 128; off > 0; off >>= 1) {
        if (tid < off) cnt_s[tid] += cnt_s[tid + off];
        __syncthreads();
    }
    if (tid == 0) *flag = (cnt_s[0] > 256) ? 1 : 0;
}

struct CanonSrc { const void* s[15]; };

// single-launch canonicalization of all 15 weight tensors
__global__ __launch_bounds__(256) void k_canon_all(
    CanonSrc cs, char* __restrict__ wsb, int total, const int* __restrict__ flag)
{
    static const __device__ int off_d[16] = {0, 1728, 1792, 75520, 75648, 370560,
        370816, 375424, 899712, 900736, 1195648, 1195776, 1269504, 1269568,
        1269632, 1269633};
    static const __device__ long woff_d[15] = {0, 3456, 3584, 151040, 151296,
        741120, 741632, 750848, 1799424, 1801472, 2391296, 2391552, 2539008,
        2539136, 2539264};
    int i = blockIdx.x * 256 + threadIdx.x;
    if (i >= total) return;
    int t = 0;
    while (t < 14 && i >= off_d[t + 1]) ++t;
    int j = i - off_d[t];
    bf16* dst = (bf16*)(wsb + woff_d[t]);
    if (*flag) dst[j] = f2b(((const float*)cs.s[t])[j]);
    else       dst[j] = ((const bf16*)cs.s[t])[j];
}

// combine dec_w1 -> wc1[par][oc=128][k=ci*4+a*2+b], K=1024
__global__ __launch_bounds__(256) void k_combine1(
    const bf16* __restrict__ w, bf16* __restrict__ wc1)
{
    int idx = blockIdx.x * 256 + threadIdx.x;
    if (idx >= 524288) return;
    int b = idx & 1, a = (idx >> 1) & 1, ci = (idx >> 2) & 255;
    int oc = (idx >> 10) & 127, par = idx >> 17;
    int py = par >> 1, px = par & 1;
    const bf16* wb = w + (oc * 256 + ci) * 9;
    float v = 0.f;
    #pragma unroll
    for (int ky = 0; ky < 3; ++ky) {
        bool rok = (py == 0) ? (a == 0 ? (ky == 0) : (ky >= 1))
                             : (a == 0 ? (ky <= 1) : (ky == 2));
        if (!rok) continue;
        #pragma unroll
        for (int kx = 0; kx < 3; ++kx) {
            bool cok = (px == 0) ? (b == 0 ? (kx == 0) : (kx >= 1))
                                 : (b == 0 ? (kx <= 1) : (kx == 2));
            if (cok) v += b2f(wb[ky * 3 + kx]);
        }
    }
    wc1[idx] = f2b(v);
}

// combine dec_w2 -> wc2[par][oc=64][k=ci*4+a*2+b], K=512
__global__ __launch_bounds__(256) void k_combine2(
    const bf16* __restrict__ w, bf16* __restrict__ wc2)
{
    int idx = blockIdx.x * 256 + threadIdx.x;
    if (idx >= 131072) return;
    int b = idx & 1, a = (idx >> 1) & 1, ci = (idx >> 2) & 127;
    int oc = (idx >> 9) & 63, par = idx >> 15;
    int py = par >> 1, px = par & 1;
    const bf16* wb = w + (oc * 128 + ci) * 9;
    float v = 0.f;
    #pragma unroll
    for (int ky = 0; ky < 3; ++ky) {
        bool rok = (py == 0) ? (a == 0 ? (ky == 0) : (ky >= 1))
                             : (a == 0 ? (ky <= 1) : (ky == 2));
        if (!rok) continue;
        #pragma unroll
        for (int kx = 0; kx < 3; ++kx) {
            bool cok = (px == 0) ? (b == 0 ? (kx == 0) : (kx >= 1))
                                 : (b == 0 ? (kx <= 1) : (kx == 2));
            if (cok) v += b2f(wb[ky * 3 + kx]);
        }
    }
    wc2[idx] = f2b(v);
}

// rearrange pw_w -> wcp[m=ch*4+gate][k=512]
__global__ __launch_bounds__(256) void k_prep_pw(
    const bf16* __restrict__ pww, bf16* __restrict__ wcp)
{
    int idx = blockIdx.x * 256 + threadIdx.x;
    if (idx >= 524288) return;
    int k = idx & 511, m = idx >> 9;
    int ch = m >> 2, gate = m & 3;
    wcp[idx] = pww[(gate * 256 + ch) * 512 + k];
}

// rearrange enc_w3 -> wc3[oc][tap*128+ci]
__global__ __launch_bounds__(256) void k_prep_w3(
    const bf16* __restrict__ w, bf16* __restrict__ wc3)
{
    int idx = blockIdx.x * 256 + threadIdx.x;
    if (idx >= 294912) return;
    int oc = idx / 1152, rem = idx % 1152;
    int tap = rem >> 7, ci = rem & 127;
    wc3[idx] = w[(oc * 128 + ci) * 9 + tap];
}

// rearrange enc_w2 -> wc2e[oc][tap*64+ci], K=576
__global__ __launch_bounds__(256) void k_prep_w2(
    const bf16* __restrict__ w, bf16* __restrict__ wc2e)
{
    int idx = blockIdx.x * 256 + threadIdx.x;
    if (idx >= 73728) return;
    int oc = idx / 576, rem = idx % 576;
    int tap = rem >> 6, ci = rem & 63;
    wc2e[idx] = w[(oc * 64 + ci) * 9 + tap];
}

// K1: conv 3->64 + relu + pool : x[f0+z] -> p1c[z,64,42,42]
__global__ __launch_bounds__(256) void k_conv1_pool(
    const void* __restrict__ xv, const bf16* __restrict__ w,
    const bf16* __restrict__ bias, bf16* __restrict__ p1c, int fbase,
    const int* __restrict__ flag)
{
    __shared__ __align__(16) float in_s[3][16][16];
    __shared__ __align__(16) float w_s[1728];
    __shared__ __align__(16) float b_s[64];
    const int z = blockIdx.y;
    const int n = fbase + z;
    const int ty = blockIdx.x / 6, tx = blockIdx.x % 6;
    const int tid = threadIdx.x;
    const int isf32 = *flag;
    for (int i = tid; i < 1728; i += 256) w_s[i] = b2f(w[i]);
    if (tid < 64) b_s[tid] = b2f(bias[tid]);
    const int iy0 = ty * 14 - 1, ix0 = tx * 14 - 1;
    for (int i = tid; i < 768; i += 256) {
        int ci = i >> 8, r = (i >> 4) & 15, col = i & 15;
        int gy = iy0 + r, gx = ix0 + col;
        float v = 0.f;
        if (gy >= 0 && gy < 84 && gx >= 0 && gx < 84) {
            int idx = (n * 3 + ci) * 7056 + gy * 84 + gx;
            v = isf32 ? ((const float*)xv)[idx] : b2f(((const bf16*)xv)[idx]);
        }
        in_s[ci][r][col] = v;
    }
    __syncthreads();
    for (int idx = tid; idx < 3136; idx += 256) {
        int oc = idx / 49, p = idx % 49;
        int py = p / 7, px = p % 7;
        float m = 0.f;
        #pragma unroll
        for (int pp = 0; pp < 4; ++pp) {
            int a = pp >> 1, bb = pp & 1;
            float sacc = b_s[oc];
            for (int ci = 0; ci < 3; ++ci)
                #pragma unroll
                for (int ky = 0; ky < 3; ++ky)
                    #pragma unroll
                    for (int kx = 0; kx < 3; ++kx)
                        sacc += w_s[(oc * 3 + ci) * 9 + ky * 3 + kx] *
                                in_s[ci][2 * py + a + ky][2 * px + bb + kx];
            m = fmaxf(m, sacc);
        }
        p1c[((z * 64 + oc) * 42 + ty * 7 + py) * 42 + tx * 7 + px] = f2b(m);
    }
}

// K2: conv 64->128 + relu + maxpool via MFMA, parity-fused.
// grid (7 nt, 1, 64 z). M=128 oc, N=63 pooled px (3 rows x 21), K=576.
__global__ __launch_bounds__(256) void k_conv2_mfma(
    const bf16* __restrict__ p1c, const bf16* __restrict__ wc2e,
    const bf16* __restrict__ bias, bf16* __restrict__ p2c)
{
    __shared__ __align__(16) short H_s[352 * 72];   // [hy*44+hx][ci pad72]
    __shared__ __align__(16) short W_s[128 * 40];   // [m][32k pad40]
    const int nt = blockIdx.x, z = blockIdx.z;
    const int tid = threadIdx.x;
    const int wave = tid >> 6, lane = tid & 63;
    const int quad = lane >> 4, nl = lane & 15;
    const int nn = wave * 16 + nl;
    const int np = (nn < 63) ? nn : 62;
    const int iyl = np / 21, ix = np % 21;
    const int r0 = nt * 3;
    // stage halo once: input rows 2r0-1..2r0+6, cols -1..42, 64 ci
    for (int i = tid; i < 22528; i += 256) {
        int ci = i / 352, rc = i % 352;
        int gy = 2 * r0 - 1 + rc / 44, gx = (rc % 44) - 1;
        short v = 0;
        if (gy >= 0 && gy < 42 && gx >= 0 && gx < 42)
            v = ((const short*)p1c)[((z * 64 + ci) * 42 + gy) * 42 + gx];
        H_s[rc * 72 + ci] = v;
    }
    f32x4 acc[4][8];
    #pragma unroll
    for (int p = 0; p < 4; ++p)
        #pragma unroll
        for (int f = 0; f < 8; ++f) acc[p][f] = (f32x4){0.f, 0.f, 0.f, 0.f};
    for (int tap = 0; tap < 9; ++tap) {
        const int dy = tap / 3, dx = tap % 3;
        for (int cc = 0; cc < 2; ++cc) {
            __syncthreads();
            for (int i = tid; i < 512; i += 256) {
                int m = i >> 2, k8 = (i & 3) * 8;
                *(uint4*)&W_s[m * 40 + k8] =
                    *(const uint4*)&wc2e[m * 576 + tap * 64 + cc * 32 + k8];
            }
            __syncthreads();
            bf16x8 af[8];
            #pragma unroll
            for (int f = 0; f < 8; ++f)
                af[f] = *(const bf16x8*)&W_s[(f * 16 + nl) * 40 + quad * 8];
            #pragma unroll
            for (int par = 0; par < 4; ++par) {
                const int pa = par >> 1, pb = par & 1;
                const int hy = 2 * iyl + pa + dy;       // 0..7
                const int hx = 2 * ix + pb + dx;        // 0..43
                const bf16x8 bv =
                    *(const bf16x8*)&H_s[(hy * 44 + hx) * 72 + cc * 32 + quad * 8];
                #pragma unroll
                for (int f = 0; f < 8; ++f)
                    acc[par][f] = __builtin_amdgcn_mfma_f32_16x16x32_bf16(
                        af[f], bv, acc[par][f], 0, 0, 0);
            }
        }
    }
    if (nn < 63) {
        #pragma unroll
        for (int f = 0; f < 8; ++f)
            #pragma unroll
            for (int reg = 0; reg < 4; ++reg) {
                const int oc = f * 16 + quad * 4 + reg;
                float m = fmaxf(fmaxf(acc[0][f][reg], acc[1][f][reg]),
                                fmaxf(acc[2][f][reg], acc[3][f][reg]));
                p2c[(z * 128 + oc) * 441 + (r0 + iyl) * 21 + ix] =
                    f2b(fmaxf(m + b2f(bias[oc]), 0.f));
            }
    }
}

// K3: conv 128->256 + relu via MFMA : p2c[z] -> feats slot (t*8+b)
__global__ __launch_bounds__(256) void k_conv3_mfma(
    const bf16* __restrict__ p2c, const bf16* __restrict__ wc3,
    const bf16* __restrict__ bias, bf16* __restrict__ feats, int fbase)
{
    __shared__ __align__(16) short H_s[115 * 136];  // [rc=5x23][ci pad136]
    __shared__ __align__(16) short W_s[128 * 40];   // [m][32 k pad40]
    const int nt = blockIdx.x, oq = blockIdx.y, z = blockIdx.z;
    const int n = fbase + z;
    const int slot = (n & 15) * 8 + (n >> 4);
    const int tid = threadIdx.x;
    const int wave = tid >> 6, lane = tid & 63;
    const int quad = lane >> 4, nl = lane & 15;
    const int nn = wave * 16 + nl;
    const int np = (nn < 63) ? nn : 62;
    const int iyl = np / 21, ox = np % 21;
    const int r0 = nt * 3;
    for (int i = tid; i < 14720; i += 256) {
        int ci = i / 115, rc = i % 115, r = rc / 23, col = rc % 23;
        int gy = r0 + r - 1, gx = col - 1;
        short v = 0;
        if (gy >= 0 && gy < 21 && gx >= 0 && gx < 21)
            v = ((const short*)p2c)[((z * 128 + ci) * 21 + gy) * 21 + gx];
        H_s[rc * 136 + ci] = v;
    }
    f32x4 acc[8];
    #pragma unroll
    for (int f = 0; f < 8; ++f) acc[f] = (f32x4){0.f, 0.f, 0.f, 0.f};
    const int hb = iyl * 23 + ox;
    for (int tap = 0; tap < 9; ++tap) {
        const int dy = tap / 3, dx = tap % 3;
        const int hofs = (hb + dy * 23 + dx) * 136;
        for (int cc = 0; cc < 4; ++cc) {
            __syncthreads();
            for (int i = tid; i < 512; i += 256) {
                int m = i >> 2, k8 = (i & 3) * 8;
                *(uint4*)&W_s[m * 40 + k8] =
                    *(const uint4*)&wc3[(oq * 128 + m) * 1152 + tap * 128 + cc * 32 + k8];
            }
            __syncthreads();
            const bf16x8 bv = *(const bf16x8*)&H_s[hofs + cc * 32 + quad * 8];
            #pragma unroll
            for (int f = 0; f < 8; ++f) {
                bf16x8 af = *(const bf16x8*)&W_s[(f * 16 + nl) * 40 + quad * 8];
                acc[f] = __builtin_amdgcn_mfma_f32_16x16x32_bf16(af, bv, acc[f], 0, 0, 0);
            }
        }
    }
    if (nn < 63) {
        const int oy = r0 + iyl;
        #pragma unroll
        for (int f = 0; f < 8; ++f)
            #pragma unroll
            for (int reg = 0; reg < 4; ++reg) {
                const int oc = oq * 128 + f * 16 + quad * 4 + reg;
                float v = acc[f][reg] + b2f(bias[oc]);
                feats[(slot * 256 + oc) * 441 + oy * 21 + ox] = f2b(fmaxf(v, 0.f));
            }
    }
}

// K4: depthwise 3x3 on [feats slot t | h] -> dwout bf16 [8,512,441]
__global__ __launch_bounds__(256) void k_dw(
    const bf16* __restrict__ feats, const float* __restrict__ h,
    const bf16* __restrict__ dww, bf16* __restrict__ dwout, int t)
{
    int idx = blockIdx.x * 256 + threadIdx.x;
    if (idx >= 8 * 512 * 441) return;
    const int p = idx % 441;
    const int ch = (idx / 441) & 511;
    const int b = idx / (441 * 512);
    const int y = p / 21, x = p % 21;
    float wv[9];
    #pragma unroll
    for (int k = 0; k < 9; ++k) wv[k] = b2f(dww[ch * 9 + k]);
    float s = 0.f;
    #pragma unroll
    for (int ky = 0; ky < 3; ++ky) {
        int iy = y + ky - 1;
        if (iy < 0 || iy >= 21) continue;
        #pragma unroll
        for (int kx = 0; kx < 3; ++kx) {
            int ix = x + kx - 1;
            if (ix < 0 || ix >= 21) continue;
            float v;
            if (ch < 256) v = b2f(feats[((t * 8 + b) * 256 + ch) * 441 + iy * 21 + ix]);
            else          v = h[(b * 256 + (ch - 256)) * 441 + iy * 21 + ix];
            s += wv[ky * 3 + kx] * v;
        }
    }
    dwout[idx] = f2b(s);
}

// K5: pointwise + gates via MFMA. grid (7 nt, 8 mq, 8 b).
__global__ __launch_bounds__(256) void k_pw_mfma(
    const bf16* __restrict__ dwout, const bf16* __restrict__ wcp,
    const bf16* __restrict__ pwb, float* __restrict__ h, float* __restrict__ c,
    bf16* __restrict__ hst)
{
    __shared__ __align__(16) short W_s[128 * 72];
    __shared__ __align__(16) short X_s[64 * 72];
    __shared__ bf16 pb_s[1024];
    const int nt = blockIdx.x, mq = blockIdx.y, b = blockIdx.z;
    const int tid = threadIdx.x;
    const int wave = tid >> 6, lane = tid & 63;
    const int quad = lane >> 4, nl = lane & 15;
    const int nn = wave * 16 + nl;
    for (int i = tid; i < 1024; i += 256) pb_s[i] = pwb[i];
    f32x4 acc[8];
    #pragma unroll
    for (int f = 0; f < 8; ++f) acc[f] = (f32x4){0.f, 0.f, 0.f, 0.f};
    for (int cc = 0; cc < 8; ++cc) {
        __syncthreads();
        for (int i = tid; i < 1024; i += 256) {
            int m = i >> 3, k8 = (i & 7) * 8;
            *(uint4*)&W_s[m * 72 + k8] =
                *(const uint4*)&wcp[(mq * 128 + m) * 512 + cc * 64 + k8];
        }
        for (int i = tid; i < 4096; i += 256) {
            int k = i >> 6, p = i & 63;
            short v = 0;
            if (p < 63)
                v = ((const short*)dwout)[(b * 512 + cc * 64 + k) * 441 + nt * 63 + p];
            X_s[p * 72 + k] = v;
        }
        __syncthreads();
        #pragma unroll
        for (int s = 0; s < 2; ++s) {
            const bf16x8 bv = *(const bf16x8*)&X_s[nn * 72 + s * 32 + quad * 8];
            #pragma unroll
            for (int f = 0; f < 8; ++f) {
                bf16x8 af = *(const bf16x8*)&W_s[(f * 16 + nl) * 72 + s * 32 + quad * 8];
                acc[f] = __builtin_amdgcn_mfma_f32_16x16x32_bf16(af, bv, acc[f], 0, 0, 0);
            }
        }
    }
    if (nn < 63) {
        const int p = nt * 63 + nn;
        #pragma unroll
        for (int f = 0; f < 8; ++f) {
            const int ch = mq * 32 + f * 4 + quad;
            float ig = sigf(acc[f][0] + b2f(pb_s[ch]));
            float fg = sigf(acc[f][1] + b2f(pb_s[256 + ch]));
            float og = sigf(acc[f][2] + b2f(pb_s[512 + ch]));
            float gg = tanhfast(acc[f][3] + b2f(pb_s[768 + ch]));
            const int ci2 = (b * 256 + ch) * 441 + p;
            float c2 = fg * c[ci2] + ig * gg;
            float h2 = og * tanhfast(c2);
            c[ci2] = c2; h[ci2] = h2;
            hst[ci2] = f2b(h2);
        }
    }
}

// K6: dec1 MFMA. grid (7 ntile, 4 par, 32 z). D[128][63] per block.
__global__ __launch_bounds__(256) void k_dec1_mfma(
    const bf16* __restrict__ feats, const bf16* __restrict__ hs0,
    const bf16* __restrict__ wc1, const bf16* __restrict__ bias,
    bf16* __restrict__ d1c, int c0f)
{
    __shared__ __align__(16) short W_s[128 * 72];
    __shared__ __align__(16) short H_s[16 * 5 * 23];
    const int nt = blockIdx.x, par = blockIdx.y, z = blockIdx.z;
    const int py = par >> 1, px = par & 1;
    const int n = c0f + z, bb = n >> 4, tt = n & 15;
    const short* hsf = (const short*)((tt == 0) ? (hs0 + bb * 112896)
                                    : (feats + (((tt - 1) * 8 + bb) * 112896)));
    const int tid = threadIdx.x;
    const int wave = tid >> 6, lane = tid & 63;
    const int quad = lane >> 4, nl = lane & 15;
    const int nn = wave * 16 + nl;
    const int np = (nn < 63) ? nn : 62;
    const int iyl = np / 21, ix = np % 21;
    const int r0 = nt * 3;
    f32x4 acc[8];
    #pragma unroll
    for (int f = 0; f < 8; ++f) acc[f] = (f32x4){0.f, 0.f, 0.f, 0.f};
    const int hbase = (py + iyl) * 23 + (px + ix);
    for (int cc = 0; cc < 16; ++cc) {
        __syncthreads();
        for (int i = tid; i < 1024; i += 256) {
            int m = i >> 3, k8 = (i & 7) * 8;
            uint4 v = *(const uint4*)&wc1[((par * 128 + m) << 10) + cc * 64 + k8];
            *(uint4*)&W_s[m * 72 + k8] = v;
        }
        for (int i = tid; i < 1840; i += 256) {
            int ci = i / 115, rem = i % 115, r = rem / 23, col = rem % 23;
            int gy = r0 + r - 1, gx = col - 1;
            short v = 0;
            if (gy >= 0 && gy < 21 && gx >= 0 && gx < 21)
                v = hsf[((cc * 16 + ci) * 21 + gy) * 21 + gx];
            H_s[(ci * 5 + r) * 23 + col] = v;
        }
        __syncthreads();
        #pragma unroll
        for (int s = 0; s < 2; ++s) {
            bf16x8 bfv;
            #pragma unroll
            for (int j = 0; j < 8; ++j) {
                int ci = s * 8 + quad * 2 + (j >> 2);
                int a = (j >> 1) & 1, b = j & 1;
                bfv[j] = H_s[ci * 115 + a * 23 + b + hbase];
            }
            #pragma unroll
            for (int f = 0; f < 8; ++f) {
                bf16x8 af = *(const bf16x8*)&W_s[(f * 16 + nl) * 72 + s * 32 + quad * 8];
                acc[f] = __builtin_amdgcn_mfma_f32_16x16x32_bf16(af, bfv, acc[f], 0, 0, 0);
            }
        }
    }
    if (nn < 63) {
        const int oy = 2 * (r0 + iyl) + py, ox = 2 * ix + px;
        #pragma unroll
        for (int f = 0; f < 8; ++f)
            #pragma unroll
            for (int reg = 0; reg < 4; ++reg) {
                const int oc = f * 16 + quad * 4 + reg;
                float v = acc[f][reg] + b2f(bias[oc]);
                d1c[(z * 128 + oc) * 1764 + oy * 42 + ox] = f2b(fmaxf(v, 0.f));
            }
    }
}

// K7: dec2 MFMA fused with 1x1 w3-reduce -> direct out. grid (28, 4, 32).
__global__ __launch_bounds__(256) void k_dec2f_mfma(
    const bf16* __restrict__ d1c, const bf16* __restrict__ wc2,
    const bf16* __restrict__ bias, const bf16* __restrict__ w3,
    const bf16* __restrict__ b3, void* __restrict__ out, int c0f,
    const int* __restrict__ flag)
{
    __shared__ __align__(16) short W_s[64 * 72];
    __shared__ __align__(16) short H_s[16 * 4 * 44];
    const int nt = blockIdx.x, par = blockIdx.y, z = blockIdx.z;
    const int py = par >> 1, px = par & 1;
    const int tid = threadIdx.x;
    const int wave = tid >> 6, lane = tid & 63;
    const int quad = lane >> 4, nl = lane & 15;
    const int nn = wave * 16 + nl;
    const int p0 = nt * 63;
    const int iy_lo = p0 / 42;
    const int p = p0 + ((nn < 63) ? nn : 62);
    const int iyl = p / 42 - iy_lo, ix = p % 42;
    f32x4 acc[4];
    #pragma unroll
    for (int f = 0; f < 4; ++f) acc[f] = (f32x4){0.f, 0.f, 0.f, 0.f};
    const int hbase = (py + iyl) * 44 + (px + ix);
    for (int cc = 0; cc < 8; ++cc) {
        __syncthreads();
        for (int i = tid; i < 512; i += 256) {
            int m = i >> 3, k8 = (i & 7) * 8;
            uint4 v = *(const uint4*)&wc2[((par * 64 + m) << 9) + cc * 64 + k8];
            *(uint4*)&W_s[m * 72 + k8] = v;
        }
        for (int i = tid; i < 2816; i += 256) {
            int ci = i / 176, rem = i % 176, r = rem / 44, col = rem % 44;
            int gy = iy_lo + r - 1, gx = col - 1;
            short v = 0;
            if (gy >= 0 && gy < 42 && gx >= 0 && gx < 42)
                v = ((const short*)d1c)[((z * 128 + cc * 16 + ci) * 42 + gy) * 42 + gx];
            H_s[(ci * 4 + r) * 44 + col] = v;
        }
        __syncthreads();
        #pragma unroll
        for (int s = 0; s < 2; ++s) {
            bf16x8 bfv;
            #pragma unroll
            for (int j = 0; j < 8; ++j) {
                int ci = s * 8 + quad * 2 + (j >> 2);
                int a = (j >> 1) & 1, b = j & 1;
                bfv[j] = H_s[ci * 176 + a * 44 + b + hbase];
            }
            #pragma unroll
            for (int f = 0; f < 4; ++f) {
                bf16x8 af = *(const bf16x8*)&W_s[(f * 16 + nl) * 72 + s * 32 + quad * 8];
                acc[f] = __builtin_amdgcn_mfma_f32_16x16x32_bf16(af, bfv, acc[f], 0, 0, 0);
            }
        }
    }
    float part = 0.f;
    #pragma unroll
    for (int f = 0; f < 4; ++f)
        #pragma unroll
        for (int reg = 0; reg < 4; ++reg) {
            const int oc = f * 16 + quad * 4 + reg;
            part += b2f(w3[oc]) * fmaxf(acc[f][reg] + b2f(bias[oc]), 0.f);
        }
    part += __shfl_xor(part, 16);
    part += __shfl_xor(part, 32);
    if (quad == 0 && nn < 63) {
        const int oy = 2 * (iy_lo + iyl) + py, ox = 2 * ix + px;
        const float v = part + b2f(b3[0]);
        const long oi = (long)(c0f + z) * 7056 + oy * 84 + ox;
        if (*flag) ((float*)out)[oi] = v;
        else       ((bf16*)out)[oi]  = f2b(v);
    }
}

// K9: flush final h,c -> d_out
__global__ __launch_bounds__(256) void k_out_hc(
    const float* __restrict__ h, const float* __restrict__ c,
    void* __restrict__ out, const int* __restrict__ flag)
{
    int idx = blockIdx.x * 256 + threadIdx.x;
    if (idx >= 903168) return;
    if (*flag) {
        ((float*)out)[903168 + idx] = h[idx];
        ((float*)out)[1806336 + idx] = c[idx];
    } else {
        ((bf16*)out)[903168 + idx]  = f2b(h[idx]);
        ((bf16*)out)[1806336 + idx] = f2b(c[idx]);
    }
}

extern "C" void kernel_launch(void* const* d_in, const int* in_sizes, int n_in,
                              void* d_out, int out_size, void* d_ws, size_t ws_size,
                              hipStream_t stream)
{
    char* wsb = (char*)d_ws;
    static const long woff[15] = {0, 3456, 3584, 151040, 151296, 741120, 741632,
                                  750848, 1799424, 1801472, 2391296, 2391552,
                                  2539008, 2539136, 2539264};
    const long FLAG_OFF = 2539280;
    const long WC1_OFF = 2539296;          // 1,048,576 B
    const long WC2_OFF = 3587872;          //   262,144 B
    const long WCP_OFF = 3850016;          // 1,048,576 B
    const long WC3_OFF = 4898592;          //   589,824 B
    const long WC2E_OFF = 5488416;         //   147,456 B
    const long CE = 5635872;
    int* flag = (int*)(wsb + FLAG_OFF);

    k_detect<<<1, 256, 0, stream>>>((const unsigned short*)d_in[0], 8192, flag);
    CanonSrc cs;
    for (int i = 0; i < 15; ++i) cs.s[i] = d_in[i + 1];
    k_canon_all<<<(1269633 + 255) / 256, 256, 0, stream>>>(cs, wsb, 1269633, flag);

    const void* x = d_in[0];
    bf16 *enc_w1 = (bf16*)(wsb + woff[0]), *enc_b1 = (bf16*)(wsb + woff[1]),
         *enc_w2 = (bf16*)(wsb + woff[2]), *enc_b2 = (bf16*)(wsb + woff[3]),
         *enc_w3 = (bf16*)(wsb + woff[4]), *enc_b3 = (bf16*)(wsb + woff[5]),
         *dw_w   = (bf16*)(wsb + woff[6]), *pw_w   = (bf16*)(wsb + woff[7]),
         *pw_b   = (bf16*)(wsb + woff[8]), *dec_w1 = (bf16*)(wsb + woff[9]),
         *dec_b1 = (bf16*)(wsb + woff[10]), *dec_w2 = (bf16*)(wsb + woff[11]),
         *dec_b2 = (bf16*)(wsb + woff[12]), *dec_w3 = (bf16*)(wsb + woff[13]),
         *dec_b3 = (bf16*)(wsb + woff[14]);
    bf16* wc1  = (bf16*)(wsb + WC1_OFF);
    bf16* wc2  = (bf16*)(wsb + WC2_OFF);
    bf16* wcp  = (bf16*)(wsb + WCP_OFF);
    bf16* wc3  = (bf16*)(wsb + WC3_OFF);
    bf16* wc2e = (bf16*)(wsb + WC2E_OFF);

    k_combine1<<<2048, 256, 0, stream>>>(dec_w1, wc1);
    k_combine2<<<512, 256, 0, stream>>>(dec_w2, wc2);
    k_prep_pw<<<2048, 256, 0, stream>>>(pw_w, wcp);
    k_prep_w3<<<1152, 256, 0, stream>>>(enc_w3, wc3);
    k_prep_w2<<<288, 256, 0, stream>>>(enc_w2, wc2e);

    bf16*  feats = (bf16*)(wsb + CE);                  // 28,901,376 (t-major)
    bf16*  hs0   = (bf16*)(wsb + CE + 28901376);       //  1,806,336
    float* hbuf  = (float*)(wsb + CE + 30707712);      //  3,612,672
    float* cbuf  = (float*)(wsb + CE + 34320384);      //  3,612,672
    bf16*  dwout = (bf16*)(wsb + CE + 37933056);       //  1,806,336 (LSTM)
    bf16*  d1c   = (bf16*)(wsb + CE + 37933056);       // 14,450,688 (decode)
    bf16*  p1c   = (bf16*)(wsb + CE + 37933056);       // 14,450,688 (encode, 64 fr)
    bf16*  p2c   = (bf16*)(wsb + CE + 28901376);       //  7,225,344 (encode; aliases
                                                       //  hs0/h/c, dead then)

    for (int f0 = 0; f0 < 128; f0 += 64) {
        k_conv1_pool<<<dim3(36, 64), 256, 0, stream>>>(x, enc_w1, enc_b1, p1c, f0, flag);
        k_conv2_mfma<<<dim3(7, 1, 64), 256, 0, stream>>>(p1c, wc2e, enc_b2, p2c);
        k_conv3_mfma<<<dim3(7, 2, 64), 256, 0, stream>>>(p2c, wc3, enc_b3, feats, f0);
    }
    hipMemsetAsync(hbuf, 0, 2 * 3612672, stream);
    for (int t = 0; t < 16; ++t) {
        bf16* hst = (t == 0) ? hs0 : (feats + (long)(t - 1) * 8 * 112896);
        k_dw<<<7056, 256, 0, stream>>>(feats, hbuf, dw_w, dwout, t);
        k_pw_mfma<<<dim3(7, 8, 8), 256, 0, stream>>>(dwout, wcp, pw_b, hbuf, cbuf, hst);
    }
    k_out_hc<<<3528, 256, 0, stream>>>(hbuf, cbuf, d_out, flag);
    for (int c0f = 0; c0f < 128; c0f += 32) {
        k_dec1_mfma<<<dim3(7, 4, 32), 256, 0, stream>>>(feats, hs0, wc1, dec_b1, d1c, c0f);
        k_dec2f_mfma<<<dim3(28, 4, 32), 256, 0, stream>>>(d1c, wc2, dec_b2, dec_w3,
                                                          dec_b3, d_out, c0f, flag);
    }
}

// Round 11
// 1635.982 us; speedup vs baseline: 7.4849x; 1.7720x over previous
//
#include <hip/hip_runtime.h>
#include <hip/hip_bf16.h>

typedef __hip_bfloat16 bf16;
typedef __attribute__((ext_vector_type(8))) short bf16x8;   // 8 bf16 (4 VGPRs)
typedef __attribute__((ext_vector_type(4))) float f32x4;    // 4 fp32 acc
#define DEV static __device__ __forceinline__

DEV float b2f(bf16 v) { return __bfloat162float(v); }
DEV bf16  f2b(float v) { return __float2bfloat16(v); }
DEV unsigned short f2u(float v) { bf16 t = f2b(v); return *(unsigned short*)&t; }
DEV float sigf(float x) { return 1.0f / (1.0f + __expf(-x)); }
DEV float tanhfast(float x) { return 2.0f / (1.0f + __expf(-2.0f * x)) - 1.0f; }

// ---------------------------------------------------------------------------
// fp32 I/O (proved r4). Round-11: NHWC (channel-fast) activations everywhere +
// tap-major decode K (k = tap*C + ci) -> every MFMA B-frag is one b128, all
// halo staging is vectorized b128, epilogues pack 4 oc per store.
// Layouts: p1c_t[z][1764][64], p2c_t[z][441][128], feats_t[slot][441][256]
// (slot=t*8+b), hs0_t[b][441][256], h_t/c_t f32 [b][441][256],
// dwout_t[b][441][512], d1c_t[z][1764][128].
// ws offsets unchanged from round 10 (peak ~58 MB <= 63.95 MB confirmed).
// ---------------------------------------------------------------------------

__global__ void k_detect(const unsigned short* __restrict__ xb, int nscan, int* flag)
{
    __shared__ int cnt_s[256];
    int tid = threadIdx.x;
    int c = 0;
    for (int i = tid; i < nscan; i += 256) {
        unsigned int e = (xb[i] >> 7) & 0xFF;
        c += (e >= 0xC0);
    }
    cnt_s[tid] = c;
    __syncthreads();
    for (int off = 128; off > 0; off >>= 1) {
        if (tid < off) cnt_s[tid] += cnt_s[tid + off];
        __syncthreads();
    }
    if (tid == 0) *flag = (cnt_s[0] > 256) ? 1 : 0;
}

struct CanonSrc { const void* s[15]; };

__global__ __launch_bounds__(256) void k_canon_all(
    CanonSrc cs, char* __restrict__ wsb, int total, const int* __restrict__ flag)
{
    static const __device__ int off_d[16] = {0, 1728, 1792, 75520, 75648, 370560,
        370816, 375424, 899712, 900736, 1195648, 1195776, 1269504, 1269568,
        1269632, 1269633};
    static const __device__ long woff_d[15] = {0, 3456, 3584, 151040, 151296,
        741120, 741632, 750848, 1799424, 1801472, 2391296, 2391552, 2539008,
        2539136, 2539264};
    int i = blockIdx.x * 256 + threadIdx.x;
    if (i >= total) return;
    int t = 0;
    while (t < 14 && i >= off_d[t + 1]) ++t;
    int j = i - off_d[t];
    bf16* dst = (bf16*)(wsb + woff_d[t]);
    if (*flag) dst[j] = f2b(((const float*)cs.s[t])[j]);
    else       dst[j] = ((const bf16*)cs.s[t])[j];
}

// combine dec_w1 -> wc1t[par][oc=128][k = tap*256 + ci], K=1024
__global__ __launch_bounds__(256) void k_combine1(
    const bf16* __restrict__ w, bf16* __restrict__ wc1)
{
    int idx = blockIdx.x * 256 + threadIdx.x;
    if (idx >= 524288) return;
    int ci = idx & 255, tap = (idx >> 8) & 3;
    int oc = (idx >> 10) & 127, par = idx >> 17;
    int a = tap >> 1, b = tap & 1;
    int py = par >> 1, px = par & 1;
    const bf16* wb = w + (oc * 256 + ci) * 9;
    float v = 0.f;
    #pragma unroll
    for (int ky = 0; ky < 3; ++ky) {
        bool rok = (py == 0) ? (a == 0 ? (ky == 0) : (ky >= 1))
                             : (a == 0 ? (ky <= 1) : (ky == 2));
        if (!rok) continue;
        #pragma unroll
        for (int kx = 0; kx < 3; ++kx) {
            bool cok = (px == 0) ? (b == 0 ? (kx == 0) : (kx >= 1))
                                 : (b == 0 ? (kx <= 1) : (kx == 2));
            if (cok) v += b2f(wb[ky * 3 + kx]);
        }
    }
    wc1[idx] = f2b(v);
}

// combine dec_w2 -> wc2t[par][oc=64][k = tap*128 + ci], K=512
__global__ __launch_bounds__(256) void k_combine2(
    const bf16* __restrict__ w, bf16* __restrict__ wc2)
{
    int idx = blockIdx.x * 256 + threadIdx.x;
    if (idx >= 131072) return;
    int ci = idx & 127, tap = (idx >> 7) & 3;
    int oc = (idx >> 9) & 63, par = idx >> 15;
    int a = tap >> 1, b = tap & 1;
    int py = par >> 1, px = par & 1;
    const bf16* wb = w + (oc * 128 + ci) * 9;
    float v = 0.f;
    #pragma unroll
    for (int ky = 0; ky < 3; ++ky) {
        bool rok = (py == 0) ? (a == 0 ? (ky == 0) : (ky >= 1))
                             : (a == 0 ? (ky <= 1) : (ky == 2));
        if (!rok) continue;
        #pragma unroll
        for (int kx = 0; kx < 3; ++kx) {
            bool cok = (px == 0) ? (b == 0 ? (kx == 0) : (kx >= 1))
                                 : (b == 0 ? (kx <= 1) : (kx == 2));
            if (cok) v += b2f(wb[ky * 3 + kx]);
        }
    }
    wc2[idx] = f2b(v);
}

// rearrange pw_w -> wcp[m=ch*4+gate][k=512]
__global__ __launch_bounds__(256) void k_prep_pw(
    const bf16* __restrict__ pww, bf16* __restrict__ wcp)
{
    int idx = blockIdx.x * 256 + threadIdx.x;
    if (idx >= 524288) return;
    int k = idx & 511, m = idx >> 9;
    int ch = m >> 2, gate = m & 3;
    wcp[idx] = pww[(gate * 256 + ch) * 512 + k];
}

// rearrange enc_w3 -> wc3[oc][tap*128+ci]
__global__ __launch_bounds__(256) void k_prep_w3(
    const bf16* __restrict__ w, bf16* __restrict__ wc3)
{
    int idx = blockIdx.x * 256 + threadIdx.x;
    if (idx >= 294912) return;
    int oc = idx / 1152, rem = idx % 1152;
    int tap = rem >> 7, ci = rem & 127;
    wc3[idx] = w[(oc * 128 + ci) * 9 + tap];
}

// rearrange enc_w2 -> wc2e[oc][tap*64+ci], K=576
__global__ __launch_bounds__(256) void k_prep_w2(
    const bf16* __restrict__ w, bf16* __restrict__ wc2e)
{
    int idx = blockIdx.x * 256 + threadIdx.x;
    if (idx >= 73728) return;
    int oc = idx / 576, rem = idx % 576;
    int tap = rem >> 6, ci = rem & 63;
    wc2e[idx] = w[(oc * 64 + ci) * 9 + tap];
}

// K1: conv 3->64 + relu + pool : x[f0+z] -> p1c_t[z][1764][64]
__global__ __launch_bounds__(256) void k_conv1_pool(
    const void* __restrict__ xv, const bf16* __restrict__ w,
    const bf16* __restrict__ bias, bf16* __restrict__ p1c, int fbase,
    const int* __restrict__ flag)
{
    __shared__ __align__(16) float in_s[3][16][16];
    __shared__ __align__(16) float w_s[1728];
    __shared__ __align__(16) float b_s[64];
    const int z = blockIdx.y;
    const int n = fbase + z;
    const int ty = blockIdx.x / 6, tx = blockIdx.x % 6;
    const int tid = threadIdx.x;
    const int isf32 = *flag;
    for (int i = tid; i < 1728; i += 256) w_s[i] = b2f(w[i]);
    if (tid < 64) b_s[tid] = b2f(bias[tid]);
    const int iy0 = ty * 14 - 1, ix0 = tx * 14 - 1;
    for (int i = tid; i < 768; i += 256) {
        int ci = i >> 8, r = (i >> 4) & 15, col = i & 15;
        int gy = iy0 + r, gx = ix0 + col;
        float v = 0.f;
        if (gy >= 0 && gy < 84 && gx >= 0 && gx < 84) {
            int idx = (n * 3 + ci) * 7056 + gy * 84 + gx;
            v = isf32 ? ((const float*)xv)[idx] : b2f(((const bf16*)xv)[idx]);
        }
        in_s[ci][r][col] = v;
    }
    __syncthreads();
    for (int idx = tid; idx < 3136; idx += 256) {
        int oc = idx / 49, p = idx % 49;
        int py = p / 7, px = p % 7;
        float m = 0.f;
        #pragma unroll
        for (int pp = 0; pp < 4; ++pp) {
            int a = pp >> 1, bb = pp & 1;
            float sacc = b_s[oc];
            for (int ci = 0; ci < 3; ++ci)
                #pragma unroll
                for (int ky = 0; ky < 3; ++ky)
                    #pragma unroll
                    for (int kx = 0; kx < 3; ++kx)
                        sacc += w_s[(oc * 3 + ci) * 9 + ky * 3 + kx] *
                                in_s[ci][2 * py + a + ky][2 * px + bb + kx];
            m = fmaxf(m, sacc);
        }
        p1c[(z * 1764 + (ty * 7 + py) * 42 + tx * 7 + px) * 64 + oc] = f2b(m);
    }
}

// K2: conv 64->128 + relu + maxpool via MFMA, parity-fused. NHWC.
// grid (7 nt, 1, 64 z). M=128 oc, N=63 pooled px, K=576 tap-major.
__global__ __launch_bounds__(256) void k_conv2_mfma(
    const bf16* __restrict__ p1c, const bf16* __restrict__ wc2e,
    const bf16* __restrict__ bias, bf16* __restrict__ p2c)
{
    __shared__ __align__(16) short H_s[352 * 72];   // [hy*44+hx][ci pad72]
    __shared__ __align__(16) short W_s[128 * 40];   // [m][32k pad40]
    const int nt = blockIdx.x, z = blockIdx.z;
    const int tid = threadIdx.x;
    const int wave = tid >> 6, lane = tid & 63;
    const int quad = lane >> 4, nl = lane & 15;
    const int nn = wave * 16 + nl;
    const int np = (nn < 63) ? nn : 62;
    const int iyl = np / 21, ix = np % 21;
    const int r0 = nt * 3;
    // vectorized halo staging: rows 2r0-1..2r0+6, cols -1..42, 64 ci
    for (int u = tid; u < 2816; u += 256) {
        int rc = u >> 3, c8 = u & 7;
        int gy = 2 * r0 - 1 + rc / 44, gx = (rc % 44) - 1;
        uint4 v = {0, 0, 0, 0};
        if (gy >= 0 && gy < 42 && gx >= 0 && gx < 42)
            v = *(const uint4*)&p1c[(z * 1764 + gy * 42 + gx) * 64 + c8 * 8];
        *(uint4*)&H_s[rc * 72 + c8 * 8] = v;
    }
    f32x4 acc[4][8];
    #pragma unroll
    for (int p = 0; p < 4; ++p)
        #pragma unroll
        for (int f = 0; f < 8; ++f) acc[p][f] = (f32x4){0.f, 0.f, 0.f, 0.f};
    for (int tap = 0; tap < 9; ++tap) {
        const int dy = tap / 3, dx = tap % 3;
        for (int cc = 0; cc < 2; ++cc) {
            __syncthreads();
            for (int i = tid; i < 512; i += 256) {
                int m = i >> 1, k8 = (i & 1) * 16;  // 512 shorts*? use uint4
            }
            for (int u = tid; u < 256; u += 256) {}
            for (int u = tid; u < 512; u += 256) {
                int m = u >> 2, k8 = (u & 3) * 8;
                *(uint4*)&W_s[m * 40 + k8] =
                    *(const uint4*)&wc2e[m * 576 + tap * 64 + cc * 32 + k8];
            }
            __syncthreads();
            bf16x8 af[8];
            #pragma unroll
            for (int f = 0; f < 8; ++f)
                af[f] = *(const bf16x8*)&W_s[(f * 16 + nl) * 40 + quad * 8];
            #pragma unroll
            for (int par = 0; par < 4; ++par) {
                const int pa = par >> 1, pb = par & 1;
                const int hy = 2 * iyl + pa + dy;
                const int hx = 2 * ix + pb + dx;
                const bf16x8 bv =
                    *(const bf16x8*)&H_s[(hy * 44 + hx) * 72 + cc * 32 + quad * 8];
                #pragma unroll
                for (int f = 0; f < 8; ++f)
                    acc[par][f] = __builtin_amdgcn_mfma_f32_16x16x32_bf16(
                        af[f], bv, acc[par][f], 0, 0, 0);
            }
        }
    }
    if (nn < 63) {
        #pragma unroll
        for (int f = 0; f < 8; ++f) {
            ushort4 o;
            unsigned short* op = (unsigned short*)&o;
            #pragma unroll
            for (int reg = 0; reg < 4; ++reg) {
                const int oc = f * 16 + quad * 4 + reg;
                float m = fmaxf(fmaxf(acc[0][f][reg], acc[1][f][reg]),
                                fmaxf(acc[2][f][reg], acc[3][f][reg]));
                op[reg] = f2u(fmaxf(m + b2f(bias[oc]), 0.f));
            }
            *(ushort4*)&p2c[(z * 441 + (r0 + iyl) * 21 + ix) * 128 +
                            f * 16 + quad * 4] = o;
        }
    }
}

// K3: conv 128->256 + relu via MFMA. NHWC. grid (7 nt, 2 oq, 64 z).
__global__ __launch_bounds__(256) void k_conv3_mfma(
    const bf16* __restrict__ p2c, const bf16* __restrict__ wc3,
    const bf16* __restrict__ bias, bf16* __restrict__ feats, int fbase)
{
    __shared__ __align__(16) short H_s[115 * 136];  // [rc=5x23][ci pad136]
    __shared__ __align__(16) short W_s[128 * 40];
    const int nt = blockIdx.x, oq = blockIdx.y, z = blockIdx.z;
    const int n = fbase + z;
    const int slot = (n & 15) * 8 + (n >> 4);
    const int tid = threadIdx.x;
    const int wave = tid >> 6, lane = tid & 63;
    const int quad = lane >> 4, nl = lane & 15;
    const int nn = wave * 16 + nl;
    const int np = (nn < 63) ? nn : 62;
    const int iyl = np / 21, ox = np % 21;
    const int r0 = nt * 3;
    for (int u = tid; u < 1840; u += 256) {
        int rc = u >> 4, c8 = u & 15;
        int gy = r0 + rc / 23 - 1, gx = (rc % 23) - 1;
        uint4 v = {0, 0, 0, 0};
        if (gy >= 0 && gy < 21 && gx >= 0 && gx < 21)
            v = *(const uint4*)&p2c[(z * 441 + gy * 21 + gx) * 128 + c8 * 8];
        *(uint4*)&H_s[rc * 136 + c8 * 8] = v;
    }
    f32x4 acc[8];
    #pragma unroll
    for (int f = 0; f < 8; ++f) acc[f] = (f32x4){0.f, 0.f, 0.f, 0.f};
    const int hb = iyl * 23 + ox;
    for (int tap = 0; tap < 9; ++tap) {
        const int dy = tap / 3, dx = tap % 3;
        const int hofs = (hb + dy * 23 + dx) * 136;
        for (int cc = 0; cc < 4; ++cc) {
            __syncthreads();
            for (int u = tid; u < 512; u += 256) {
                int m = u >> 2, k8 = (u & 3) * 8;
                *(uint4*)&W_s[m * 40 + k8] =
                    *(const uint4*)&wc3[(oq * 128 + m) * 1152 + tap * 128 + cc * 32 + k8];
            }
            __syncthreads();
            const bf16x8 bv = *(const bf16x8*)&H_s[hofs + cc * 32 + quad * 8];
            #pragma unroll
            for (int f = 0; f < 8; ++f) {
                bf16x8 af = *(const bf16x8*)&W_s[(f * 16 + nl) * 40 + quad * 8];
                acc[f] = __builtin_amdgcn_mfma_f32_16x16x32_bf16(af, bv, acc[f], 0, 0, 0);
            }
        }
    }
    if (nn < 63) {
        const int oy = r0 + iyl;
        #pragma unroll
        for (int f = 0; f < 8; ++f) {
            ushort4 o;
            unsigned short* op = (unsigned short*)&o;
            #pragma unroll
            for (int reg = 0; reg < 4; ++reg) {
                const int oc = oq * 128 + f * 16 + quad * 4 + reg;
                op[reg] = f2u(fmaxf(acc[f][reg] + b2f(bias[oc]), 0.f));
            }
            *(ushort4*)&feats[(slot * 441 + oy * 21 + ox) * 256 +
                              oq * 128 + f * 16 + quad * 4] = o;
        }
    }
}

// K4: depthwise 3x3 on [feats_t slot t | h_t] -> dwout_t[b][441][512], ch-fast
__global__ __launch_bounds__(256) void k_dw(
    const bf16* __restrict__ feats, const float* __restrict__ h,
    const bf16* __restrict__ dww, bf16* __restrict__ dwout, int t)
{
    int idx = blockIdx.x * 256 + threadIdx.x;
    if (idx >= 8 * 512 * 441) return;
    const int ch = idx & 511;
    const int p = (idx >> 9) % 441;
    const int b = idx / (512 * 441);
    const int y = p / 21, x = p % 21;
    float wv[9];
    #pragma unroll
    for (int k = 0; k < 9; ++k) wv[k] = b2f(dww[ch * 9 + k]);
    float s = 0.f;
    #pragma unroll
    for (int ky = 0; ky < 3; ++ky) {
        int iy = y + ky - 1;
        if (iy < 0 || iy >= 21) continue;
        #pragma unroll
        for (int kx = 0; kx < 3; ++kx) {
            int ix = x + kx - 1;
            if (ix < 0 || ix >= 21) continue;
            float v;
            if (ch < 256)
                v = b2f(feats[((t * 8 + b) * 441 + iy * 21 + ix) * 256 + ch]);
            else
                v = h[(b * 441 + iy * 21 + ix) * 256 + (ch - 256)];
            s += wv[ky * 3 + kx] * v;
        }
    }
    dwout[(b * 441 + p) * 512 + ch] = f2b(s);
}

// K5: pointwise + gates via MFMA. grid (7 nt, 8 mq, 8 b). NHWC.
__global__ __launch_bounds__(256) void k_pw_mfma(
    const bf16* __restrict__ dwout, const bf16* __restrict__ wcp,
    const bf16* __restrict__ pwb, float* __restrict__ h, float* __restrict__ c,
    bf16* __restrict__ hst)
{
    __shared__ __align__(16) short W_s[128 * 72];
    __shared__ __align__(16) short X_s[64 * 72];
    __shared__ bf16 pb_s[1024];
    const int nt = blockIdx.x, mq = blockIdx.y, b = blockIdx.z;
    const int tid = threadIdx.x;
    const int wave = tid >> 6, lane = tid & 63;
    const int quad = lane >> 4, nl = lane & 15;
    const int nn = wave * 16 + nl;
    for (int i = tid; i < 1024; i += 256) pb_s[i] = pwb[i];
    f32x4 acc[8];
    #pragma unroll
    for (int f = 0; f < 8; ++f) acc[f] = (f32x4){0.f, 0.f, 0.f, 0.f};
    for (int cc = 0; cc < 8; ++cc) {
        __syncthreads();
        for (int u = tid; u < 1024; u += 256) {
            int m = u >> 3, k8 = (u & 7) * 8;
            *(uint4*)&W_s[m * 72 + k8] =
                *(const uint4*)&wcp[(mq * 128 + m) * 512 + cc * 64 + k8];
        }
        for (int u = tid; u < 512; u += 256) {
            int p = u >> 3, k8 = (u & 7) * 8;
            int gp = nt * 63 + p;
            uint4 v = {0, 0, 0, 0};
            if (p < 63)
                v = *(const uint4*)&dwout[(b * 441 + gp) * 512 + cc * 64 + k8];
            *(uint4*)&X_s[p * 72 + k8] = v;
        }
        __syncthreads();
        #pragma unroll
        for (int s = 0; s < 2; ++s) {
            const bf16x8 bv = *(const bf16x8*)&X_s[nn * 72 + s * 32 + quad * 8];
            #pragma unroll
            for (int f = 0; f < 8; ++f) {
                bf16x8 af = *(const bf16x8*)&W_s[(f * 16 + nl) * 72 + s * 32 + quad * 8];
                acc[f] = __builtin_amdgcn_mfma_f32_16x16x32_bf16(af, bv, acc[f], 0, 0, 0);
            }
        }
    }
    if (nn < 63) {
        const int p = nt * 63 + nn;
        #pragma unroll
        for (int f = 0; f < 8; ++f) {
            const int ch = mq * 32 + f * 4 + quad;
            float ig = sigf(acc[f][0] + b2f(pb_s[ch]));
            float fg = sigf(acc[f][1] + b2f(pb_s[256 + ch]));
            float og = sigf(acc[f][2] + b2f(pb_s[512 + ch]));
            float gg = tanhfast(acc[f][3] + b2f(pb_s[768 + ch]));
            const int ci2 = (b * 441 + p) * 256 + ch;
            float c2 = fg * c[ci2] + ig * gg;
            float h2 = og * tanhfast(c2);
            c[ci2] = c2; h[ci2] = h2;
            hst[(long)b * 112896 + p * 256 + ch] = f2b(h2);
        }
    }
}

// K6: dec1 MFMA, tap-major NHWC, 2 B-frags/wave. grid (4 nt, 4 par, 32 z).
__global__ __launch_bounds__(256) void k_dec1_mfma(
    const bf16* __restrict__ feats, const bf16* __restrict__ hs0,
    const bf16* __restrict__ wc1, const bf16* __restrict__ bias,
    bf16* __restrict__ d1c, int c0f)
{
    __shared__ __align__(16) short H_s[184 * 72];   // [8r x 23c][64 ci pad72]
    __shared__ __align__(16) short W_s[128 * 72];   // [m][64 k pad72]
    const int nt = blockIdx.x, par = blockIdx.y, z = blockIdx.z;
    const int py = par >> 1, px = par & 1;
    const int n = c0f + z, bb = n >> 4, tt = n & 15;
    const short* hsf = (const short*)((tt == 0) ? (hs0 + (long)bb * 112896)
                        : (feats + (long)((tt - 1) * 8 + bb) * 112896));
    const int tid = threadIdx.x;
    const int wave = tid >> 6, lane = tid & 63;
    const int quad = lane >> 4, nl = lane & 15;
    int maxs = 440 - nt * 126; if (maxs > 125) maxs = 125;
    int hb[2], pv[2]; bool val[2];
    #pragma unroll
    for (int pg = 0; pg < 2; ++pg) {
        int slot = (wave * 2 + pg) * 16 + nl;
        val[pg] = (slot <= maxs);
        int sl = val[pg] ? slot : maxs;
        int p = nt * 126 + sl;
        pv[pg] = p;
        int y = p / 21, x = p % 21;
        hb[pg] = (y - nt * 6 + py) * 23 + (x + px);
    }
    f32x4 acc[2][8];
    #pragma unroll
    for (int pg = 0; pg < 2; ++pg)
        #pragma unroll
        for (int f = 0; f < 8; ++f) acc[pg][f] = (f32x4){0.f, 0.f, 0.f, 0.f};
    for (int cc = 0; cc < 4; ++cc) {
        __syncthreads();
        for (int u = tid; u < 1472; u += 256) {
            int rc = u >> 3, c8 = (u & 7) * 8;
            int gy = nt * 6 - 1 + rc / 23, gx = (rc % 23) - 1;
            uint4 v = {0, 0, 0, 0};
            if (gy >= 0 && gy < 21 && gx >= 0 && gx < 21)
                v = *(const uint4*)&hsf[(gy * 21 + gx) * 256 + cc * 64 + c8];
            *(uint4*)&H_s[rc * 72 + c8] = v;
        }
        for (int tap = 0; tap < 4; ++tap) {
            __syncthreads();
            for (int u = tid; u < 1024; u += 256) {
                int m = u >> 3, k8 = (u & 7) * 8;
                *(uint4*)&W_s[m * 72 + k8] =
                    *(const uint4*)&wc1[((par * 128 + m) << 10) + tap * 256 + cc * 64 + k8];
            }
            __syncthreads();
            const int a = tap >> 1, b = tap & 1;
            #pragma unroll
            for (int s = 0; s < 2; ++s) {
                bf16x8 bv0 = *(const bf16x8*)&H_s[(hb[0] + a * 23 + b) * 72 + s * 32 + quad * 8];
                bf16x8 bv1 = *(const bf16x8*)&H_s[(hb[1] + a * 23 + b) * 72 + s * 32 + quad * 8];
                #pragma unroll
                for (int f = 0; f < 8; ++f) {
                    bf16x8 af = *(const bf16x8*)&W_s[(f * 16 + nl) * 72 + s * 32 + quad * 8];
                    acc[0][f] = __builtin_amdgcn_mfma_f32_16x16x32_bf16(af, bv0, acc[0][f], 0, 0, 0);
                    acc[1][f] = __builtin_amdgcn_mfma_f32_16x16x32_bf16(af, bv1, acc[1][f], 0, 0, 0);
                }
            }
        }
    }
    #pragma unroll
    for (int pg = 0; pg < 2; ++pg) {
        if (!val[pg]) continue;
        const int p = pv[pg];
        const int oy = 2 * (p / 21) + py, ox = 2 * (p % 21) + px;
        #pragma unroll
        for (int f = 0; f < 8; ++f) {
            ushort4 o;
            unsigned short* op = (unsigned short*)&o;
            #pragma unroll
            for (int reg = 0; reg < 4; ++reg) {
                const int oc = f * 16 + quad * 4 + reg;
                op[reg] = f2u(fmaxf(acc[pg][f][reg] + b2f(bias[oc]), 0.f));
            }
            *(ushort4*)&d1c[((long)z * 1764 + oy * 42 + ox) * 128 +
                            f * 16 + quad * 4] = o;
        }
    }
}

// K7: dec2 MFMA fused w3-reduce, tap-major NHWC, 2 B-frags/wave.
// grid (14 nt, 4 par, 32 z).
__global__ __launch_bounds__(256) void k_dec2f_mfma(
    const bf16* __restrict__ d1c, const bf16* __restrict__ wc2,
    const bf16* __restrict__ bias, const bf16* __restrict__ w3,
    const bf16* __restrict__ b3, void* __restrict__ out, int c0f,
    const int* __restrict__ flag)
{
    __shared__ __align__(16) short H_s[220 * 72];   // [5r x 44c][64 ci pad72]
    __shared__ __align__(16) short W_s[64 * 72];
    const int nt = blockIdx.x, par = blockIdx.y, z = blockIdx.z;
    const int py = par >> 1, px = par & 1;
    const int tid = threadIdx.x;
    const int wave = tid >> 6, lane = tid & 63;
    const int quad = lane >> 4, nl = lane & 15;
    int hb[2], pv[2]; bool val[2];
    #pragma unroll
    for (int pg = 0; pg < 2; ++pg) {
        int slot = (wave * 2 + pg) * 16 + nl;
        val[pg] = (slot < 126);
        int sl = val[pg] ? slot : 125;
        int p = nt * 126 + sl;
        pv[pg] = p;
        int y = p / 42, x = p % 42;
        hb[pg] = (y - nt * 3 + py) * 44 + (x + px);
    }
    f32x4 acc[2][4];
    #pragma unroll
    for (int pg = 0; pg < 2; ++pg)
        #pragma unroll
        for (int f = 0; f < 4; ++f) acc[pg][f] = (f32x4){0.f, 0.f, 0.f, 0.f};
    for (int cc = 0; cc < 2; ++cc) {
        __syncthreads();
        for (int u = tid; u < 1760; u += 256) {
            int rc = u >> 3, c8 = (u & 7) * 8;
            int gy = nt * 3 - 1 + rc / 44, gx = (rc % 44) - 1;
            uint4 v = {0, 0, 0, 0};
            if (gy >= 0 && gy < 42 && gx >= 0 && gx < 42)
                v = *(const uint4*)&d1c[((long)z * 1764 + gy * 42 + gx) * 128 + cc * 64 + c8];
            *(uint4*)&H_s[rc * 72 + c8] = v;
        }
        for (int tap = 0; tap < 4; ++tap) {
            __syncthreads();
            for (int u = tid; u < 512; u += 256) {
                int m = u >> 3, k8 = (u & 7) * 8;
                *(uint4*)&W_s[m * 72 + k8] =
                    *(const uint4*)&wc2[((par * 64 + m) << 9) + tap * 128 + cc * 64 + k8];
            }
            __syncthreads();
            const int a = tap >> 1, b = tap & 1;
            #pragma unroll
            for (int s = 0; s < 2; ++s) {
                bf16x8 bv0 = *(const bf16x8*)&H_s[(hb[0] + a * 44 + b) * 72 + s * 32 + quad * 8];
                bf16x8 bv1 = *(const bf16x8*)&H_s[(hb[1] + a * 44 + b) * 72 + s * 32 + quad * 8];
                #pragma unroll
                for (int f = 0; f < 4; ++f) {
                    bf16x8 af = *(const bf16x8*)&W_s[(f * 16 + nl) * 72 + s * 32 + quad * 8];
                    acc[0][f] = __builtin_amdgcn_mfma_f32_16x16x32_bf16(af, bv0, acc[0][f], 0, 0, 0);
                    acc[1][f] = __builtin_amdgcn_mfma_f32_16x16x32_bf16(af, bv1, acc[1][f], 0, 0, 0);
                }
            }
        }
    }
    #pragma unroll
    for (int pg = 0; pg < 2; ++pg) {
        float part = 0.f;
        #pragma unroll
        for (int f = 0; f < 4; ++f)
            #pragma unroll
            for (int reg = 0; reg < 4; ++reg) {
                const int oc = f * 16 + quad * 4 + reg;
                part += b2f(w3[oc]) * fmaxf(acc[pg][f][reg] + b2f(bias[oc]), 0.f);
            }
        part += __shfl_xor(part, 16);
        part += __shfl_xor(part, 32);
        if (quad == 0 && val[pg]) {
            const int p = pv[pg];
            const int oy = 2 * (p / 42) + py, ox = 2 * (p % 42) + px;
            const float v = part + b2f(b3[0]);
            const long oi = (long)(c0f + z) * 7056 + oy * 84 + ox;
            if (*flag) ((float*)out)[oi] = v;
            else       ((bf16*)out)[oi]  = f2b(v);
        }
    }
}

// K9: flush final h,c (NHWC f32) -> d_out (NCHW)
__global__ __launch_bounds__(256) void k_out_hc(
    const float* __restrict__ h, const float* __restrict__ c,
    void* __restrict__ out, const int* __restrict__ flag)
{
    int idx = blockIdx.x * 256 + threadIdx.x;
    if (idx >= 903168) return;
    const int ch = idx & 255;
    const int r = idx >> 8;
    const int p = r % 441, b = r / 441;
    const long o = (long)(b * 256 + ch) * 441 + p;
    if (*flag) {
        ((float*)out)[903168 + o] = h[idx];
        ((float*)out)[1806336 + o] = c[idx];
    } else {
        ((bf16*)out)[903168 + o]  = f2b(h[idx]);
        ((bf16*)out)[1806336 + o] = f2b(c[idx]);
    }
}

extern "C" void kernel_launch(void* const* d_in, const int* in_sizes, int n_in,
                              void* d_out, int out_size, void* d_ws, size_t ws_size,
                              hipStream_t stream)
{
    char* wsb = (char*)d_ws;
    static const long woff[15] = {0, 3456, 3584, 151040, 151296, 741120, 741632,
                                  750848, 1799424, 1801472, 2391296, 2391552,
                                  2539008, 2539136, 2539264};
    const long FLAG_OFF = 2539280;
    const long WC1_OFF = 2539296;
    const long WC2_OFF = 3587872;
    const long WCP_OFF = 3850016;
    const long WC3_OFF = 4898592;
    const long WC2E_OFF = 5488416;
    const long CE = 5635872;
    int* flag = (int*)(wsb + FLAG_OFF);

    k_detect<<<1, 256, 0, stream>>>((const unsigned short*)d_in[0], 8192, flag);
    CanonSrc cs;
    for (int i = 0; i < 15; ++i) cs.s[i] = d_in[i + 1];
    k_canon_all<<<(1269633 + 255) / 256, 256, 0, stream>>>(cs, wsb, 1269633, flag);

    const void* x = d_in[0];
    bf16 *enc_w1 = (bf16*)(wsb + woff[0]), *enc_b1 = (bf16*)(wsb + woff[1]),
         *enc_w2 = (bf16*)(wsb + woff[2]), *enc_b2 = (bf16*)(wsb + woff[3]),
         *enc_w3 = (bf16*)(wsb + woff[4]), *enc_b3 = (bf16*)(wsb + woff[5]),
         *dw_w   = (bf16*)(wsb + woff[6]), *pw_w   = (bf16*)(wsb + woff[7]),
         *pw_b   = (bf16*)(wsb + woff[8]), *dec_w1 = (bf16*)(wsb + woff[9]),
         *dec_b1 = (bf16*)(wsb + woff[10]), *dec_w2 = (bf16*)(wsb + woff[11]),
         *dec_b2 = (bf16*)(wsb + woff[12]), *dec_w3 = (bf16*)(wsb + woff[13]),
         *dec_b3 = (bf16*)(wsb + woff[14]);
    bf16* wc1  = (bf16*)(wsb + WC1_OFF);
    bf16* wc2  = (bf16*)(wsb + WC2_OFF);
    bf16* wcp  = (bf16*)(wsb + WCP_OFF);
    bf16* wc3  = (bf16*)(wsb + WC3_OFF);
    bf16* wc2e = (bf16*)(wsb + WC2E_OFF);

    k_combine1<<<2048, 256, 0, stream>>>(dec_w1, wc1);
    k_combine2<<<512, 256, 0, stream>>>(dec_w2, wc2);
    k_prep_pw<<<2048, 256, 0, stream>>>(pw_w, wcp);
    k_prep_w3<<<1152, 256, 0, stream>>>(enc_w3, wc3);
    k_prep_w2<<<288, 256, 0, stream>>>(enc_w2, wc2e);

    bf16*  feats = (bf16*)(wsb + CE);                  // 28,901,376 (t-major)
    bf16*  hs0   = (bf16*)(wsb + CE + 28901376);       //  1,806,336
    float* hbuf  = (float*)(wsb + CE + 30707712);      //  3,612,672
    float* cbuf  = (float*)(wsb + CE + 34320384);      //  3,612,672
    bf16*  dwout = (bf16*)(wsb + CE + 37933056);       //  1,806,336 (LSTM)
    bf16*  d1c   = (bf16*)(wsb + CE + 37933056);       // 14,450,688 (decode)
    bf16*  p1c   = (bf16*)(wsb + CE + 37933056);       // 14,450,688 (encode, 64 fr)
    bf16*  p2c   = (bf16*)(wsb + CE + 28901376);       //  7,225,344 (encode alias)

    for (int f0 = 0; f0 < 128; f0 += 64) {
        k_conv1_pool<<<dim3(36, 64), 256, 0, stream>>>(x, enc_w1, enc_b1, p1c, f0, flag);
        k_conv2_mfma<<<dim3(7, 1, 64), 256, 0, stream>>>(p1c, wc2e, enc_b2, p2c);
        k_conv3_mfma<<<dim3(7, 2, 64), 256, 0, stream>>>(p2c, wc3, enc_b3, feats, f0);
    }
    hipMemsetAsync(hbuf, 0, 2 * 3612672, stream);
    for (int t = 0; t < 16; ++t) {
        bf16* hst = (t == 0) ? hs0 : (feats + (long)(t - 1) * 8 * 112896);
        k_dw<<<7056, 256, 0, stream>>>(feats, hbuf, dw_w, dwout, t);
        k_pw_mfma<<<dim3(7, 8, 8), 256, 0, stream>>>(dwout, wcp, pw_b, hbuf, cbuf, hst);
    }
    k_out_hc<<<3528, 256, 0, stream>>>(hbuf, cbuf, d_out, flag);
    for (int c0f = 0; c0f < 128; c0f += 32) {
        k_dec1_mfma<<<dim3(4, 4, 32), 256, 0, stream>>>(feats, hs0, wc1, dec_b1, d1c, c0f);
        k_dec2f_mfma<<<dim3(14, 4, 32), 256, 0, stream>>>(d1c, wc2, dec_b2, dec_w3,
                                                          dec_b3, d_out, c0f, flag);
    }
}